// Round 1
// baseline (3632.530 us; speedup 1.0000x reference)
//
#include <hip/hip_runtime.h>

#define CH    64
#define NTOK  2049
#define MROWS 4098
#define DMODEL 128
#define AHDIM 512
#define NHEAD 8

// workspace offsets (floats)
#define OFF_X     0u
#define OFF_RT    524544u
#define OFF_RC    1049088u
#define OFF_XN    1573632u
#define OFF_QKV   2098176u
#define OFF_KT    8392704u
#define OFF_KC    10490880u
#define OFF_QN    12589056u
#define OFF_KSUM  14687232u
#define OFF_VN    16785408u
#define OFF_COLB  18883584u

__device__ __forceinline__ float wave_allreduce_sum(float v) {
    #pragma unroll
    for (int m = 1; m < 64; m <<= 1) v += __shfl_xor(v, m);
    return v;
}

// ---------------- embed: conv patches + cls + positional embeddings ----------------
__global__ __launch_bounds__(128) void embed_kernel(
    const float* __restrict__ eeg, const float* __restrict__ est, const int* __restrict__ cvi,
    const float* __restrict__ cw, const float* __restrict__ cb,
    const float* __restrict__ cls, const float* __restrict__ clsp,
    float* __restrict__ x, float* __restrict__ rt, float* __restrict__ rc)
{
    int id = blockIdx.x;
    int d = threadIdx.x;
    if (id >= 4096) {  // cls rows
        int b = id - 4096;
        size_t base = (size_t)b * NTOK * 128 + d;
        x[base]  = cls[d];
        rt[base] = clsp[d];
        rc[base] = clsp[d];
        return;
    }
    int b = id >> 11, rem = id & 2047, c = rem >> 5, w = rem & 31;
    __shared__ float xs[25];
    if (d < 25) xs[d] = eeg[((size_t)(b * CH + c)) * 800 + w * 25 + d];
    __syncthreads();
    float acc = cb[d];
    #pragma unroll
    for (int p = 0; p < 25; ++p) acc += xs[p] * cw[d * 25 + p];
    int i = 1 + c * 32 + w;
    size_t base = ((size_t)b * NTOK + i) * 128 + d;
    x[base] = acc;
    int k = d & 63;
    float invk = __expf(-0.14391156831f * (float)k);   // log(10000)/64
    float pt = floorf(est[b] / 0.1f) + (float)w;
    float at = pt * invk;
    rt[base] = (d < 64) ? sinf(at) : cosf(at);
    float pc = (float)cvi[b * CH + c];
    float ac = pc * invk;
    rc[base] = (d < 64) ? sinf(ac) : cosf(ac);
}

// ---------------- layernorm over D=128, 4 rows per block (one per wave) ----------------
__global__ __launch_bounds__(256) void ln_kernel(
    const float* __restrict__ x, const float* __restrict__ g, const float* __restrict__ bb,
    float* __restrict__ out, int rows)
{
    int w = threadIdx.x >> 6, lane = threadIdx.x & 63;
    int row = blockIdx.x * 4 + w;
    if (row >= rows) return;
    const float* xr = x + (size_t)row * 128;
    float v0 = xr[lane], v1 = xr[lane + 64];
    float mean = wave_allreduce_sum(v0 + v1) * (1.0f / 128.0f);
    float d0 = v0 - mean, d1 = v1 - mean;
    float var = wave_allreduce_sum(d0 * d0 + d1 * d1) * (1.0f / 128.0f);
    float inv = rsqrtf(var + 1e-5f);
    out[(size_t)row * 128 + lane]      = d0 * inv * g[lane]      + bb[lane];
    out[(size_t)row * 128 + lane + 64] = d1 * inv * g[lane + 64] + bb[lane + 64];
}

// ---------------- generic tiled f32 GEMM: C = A[MxK] * W[KxN] (+bias)(+res|gelu) ----------------
// mode: 0 = none, 1 = +bias +res, 2 = gelu(+bias)
__global__ __launch_bounds__(256) void gemm_kernel(
    const float* __restrict__ A, const float* __restrict__ W, float* __restrict__ Cc,
    const float* __restrict__ bias, const float* __restrict__ res,
    int M, int K, int N, int mode)
{
    __shared__ float As[64][68];
    __shared__ float Bs[64][64];
    int t = threadIdx.x;
    int tx = t & 15, ty = t >> 4;
    int n0 = blockIdx.x * 64, m0 = blockIdx.y * 64;
    float acc[4][4];
    #pragma unroll
    for (int i = 0; i < 4; ++i)
        #pragma unroll
        for (int j = 0; j < 4; ++j) acc[i][j] = 0.0f;

    for (int kb = 0; kb < K; kb += 64) {
        #pragma unroll
        for (int it = 0; it < 4; ++it) {
            int r = ty + it * 16, c = tx * 4;
            int m = m0 + r; m = (m < M) ? m : (M - 1);
            float4 av = *(const float4*)&A[(size_t)m * K + kb + c];
            *(float4*)&As[r][c] = av;
        }
        #pragma unroll
        for (int it = 0; it < 4; ++it) {
            int k = ty + it * 16, c = tx * 4;
            float4 bv = *(const float4*)&W[(size_t)(kb + k) * N + n0 + c];
            *(float4*)&Bs[k][c] = bv;
        }
        __syncthreads();
        #pragma unroll 8
        for (int k = 0; k < 64; ++k) {
            float4 bv = *(float4*)&Bs[k][tx * 4];
            float a0 = As[ty * 4 + 0][k], a1 = As[ty * 4 + 1][k];
            float a2 = As[ty * 4 + 2][k], a3 = As[ty * 4 + 3][k];
            acc[0][0] += a0 * bv.x; acc[0][1] += a0 * bv.y; acc[0][2] += a0 * bv.z; acc[0][3] += a0 * bv.w;
            acc[1][0] += a1 * bv.x; acc[1][1] += a1 * bv.y; acc[1][2] += a1 * bv.z; acc[1][3] += a1 * bv.w;
            acc[2][0] += a2 * bv.x; acc[2][1] += a2 * bv.y; acc[2][2] += a2 * bv.z; acc[2][3] += a2 * bv.w;
            acc[3][0] += a3 * bv.x; acc[3][1] += a3 * bv.y; acc[3][2] += a3 * bv.z; acc[3][3] += a3 * bv.w;
        }
        __syncthreads();
    }
    #pragma unroll
    for (int i = 0; i < 4; ++i) {
        int m = m0 + ty * 4 + i;
        if (m >= M) continue;
        #pragma unroll
        for (int j = 0; j < 4; ++j) {
            int n = n0 + tx * 4 + j;
            float v = acc[i][j];
            if (mode == 1) v += bias[n] + res[(size_t)m * N + n];
            else if (mode == 2) { v += bias[n]; v = 0.5f * v * (1.0f + erff(v * 0.70710678118f)); }
            Cc[(size_t)m * N + n] = v;
        }
    }
}

// ---------------- remap qkv / kt / kc into "new space", build ksum & column bias ----------------
__global__ __launch_bounds__(512) void remap_kernel(
    const float* __restrict__ qkv, const float* __restrict__ kt, const float* __restrict__ kc,
    const float* __restrict__ bte, const float* __restrict__ btr,
    const float* __restrict__ bcr, const float* __restrict__ bce,
    float* __restrict__ qn, float* __restrict__ ksum, float* __restrict__ vn, float* __restrict__ colb)
{
    int id = blockIdx.x;            // b2*NTOK + i2
    int b2 = id / NTOK, i2 = id - b2 * NTOK;
    int t = threadIdx.x;
    int h2 = t >> 6, d2 = t & 63;
    int G = i2 * 16 + b2 * 8 + h2;
    int bhA = G / 2049, iA = G - bhA * 2049;
    int bA = bhA >> 3, hA = bhA & 7;
    size_t qbase = ((size_t)(bA * NTOK + iA)) * 1536 + hA * 64 + d2;
    float qv = qkv[qbase], kv = qkv[qbase + 512], vv = qkv[qbase + 1024];
    int bB = G / 16392, remB = G - bB * 16392;
    int iB = remB >> 3, hB = remB & 7;
    size_t tbase = ((size_t)(bB * NTOK + iB)) * 512 + hB * 64 + d2;
    float ktv = kt[tbase], kcv = kc[tbase];
    size_t ob = (size_t)id * 512 + t;
    qn[ob] = qv;
    ksum[ob] = kv + ktv + kcv;
    vn[ob] = vv;
    float cb = (bte[t] + bce[t]) * kv + (btr[t] + bcr[t]) * (ktv + kcv);
    cb = wave_allreduce_sum(cb);
    if (d2 == 0) colb[(size_t)id * 8 + h2] = cb;
}

// ---------------- fused attention (softmax over HEADS per (i,j)) ----------------
// grid (129, B), 256 threads: 16 i-rows/block, thread = (i_local, s), s = 16 d-slices of 32
__global__ __launch_bounds__(256) void attn_kernel(
    const float* __restrict__ qn, const float* __restrict__ ksum, const float* __restrict__ vn,
    const float* __restrict__ colb, float* __restrict__ o)
{
    __shared__ float kls[16][520];
    __shared__ float vls[16][520];
    __shared__ float cbl[16][8];
    int bb = blockIdx.y;
    int i0 = blockIdx.x * 16;
    int t = threadIdx.x;
    int il = t >> 4, s = t & 15, s7 = s & 7, h = s >> 1;
    int i = i0 + il;
    bool valid = (i < NTOK);
    float q[32], O[32];
    #pragma unroll
    for (int g = 0; g < 8; ++g) {
        float4 qv = make_float4(0.f, 0.f, 0.f, 0.f);
        if (valid) qv = *(const float4*)&qn[((size_t)bb * NTOK + i) * 512 + s * 32 + g * 4];
        q[4 * g + 0] = qv.x; q[4 * g + 1] = qv.y; q[4 * g + 2] = qv.z; q[4 * g + 3] = qv.w;
        O[4 * g + 0] = 0.f; O[4 * g + 1] = 0.f; O[4 * g + 2] = 0.f; O[4 * g + 3] = 0.f;
    }
    int offc[8];
    #pragma unroll
    for (int g = 0; g < 8; ++g) offc[g] = s * 32 + (((g ^ s7) & 7) << 2);

    for (int jt = 0; jt < NTOK; jt += 16) {
        __syncthreads();
        #pragma unroll
        for (int p = 0; p < 8; ++p) {
            int e4 = t + p * 256;
            int jj = e4 >> 7, gg = e4 & 127, d = gg * 4;
            int col = (d & ~31) | (((((d >> 2) ^ (d >> 5)) & 7) << 2));
            int j = jt + jj;
            float4 kv = make_float4(0.f, 0.f, 0.f, 0.f), vv = make_float4(0.f, 0.f, 0.f, 0.f);
            if (j < NTOK) {
                size_t base = ((size_t)bb * NTOK + j) * 512 + d;
                kv = *(const float4*)&ksum[base];
                vv = *(const float4*)&vn[base];
            }
            *(float4*)&kls[jj][col] = kv;
            *(float4*)&vls[jj][col] = vv;
        }
        if (t < 128) {
            int jj = t >> 3, hh = t & 7, j = jt + jj;
            cbl[jj][hh] = (j < NTOK) ? colb[((size_t)bb * NTOK + j) * 8 + hh] : 0.0f;
        }
        __syncthreads();
        #pragma unroll 4
        for (int jj = 0; jj < 16; ++jj) {
            float4 kf[8];
            #pragma unroll
            for (int g = 0; g < 8; ++g) kf[g] = *(float4*)&kls[jj][offc[g]];
            float part = 0.f;
            #pragma unroll
            for (int g = 0; g < 8; ++g) {
                part += q[4 * g + 0] * kf[g].x + q[4 * g + 1] * kf[g].y
                      + q[4 * g + 2] * kf[g].z + q[4 * g + 3] * kf[g].w;
            }
            float sc = part + __shfl_xor(part, 1);
            sc = (sc + cbl[jj][h]) * 0.125f;      // SCALE = DH^-0.5
            float mx = sc;
            mx = fmaxf(mx, __shfl_xor(mx, 2));
            mx = fmaxf(mx, __shfl_xor(mx, 4));
            mx = fmaxf(mx, __shfl_xor(mx, 8));
            float p = __expf(sc - mx);
            float sm = p;
            sm += __shfl_xor(sm, 2); sm += __shfl_xor(sm, 4); sm += __shfl_xor(sm, 8);
            float att = p * __builtin_amdgcn_rcpf(sm);
            #pragma unroll
            for (int g = 0; g < 8; ++g) {
                float4 vv = *(float4*)&vls[jj][offc[g]];
                O[4 * g + 0] += att * vv.x; O[4 * g + 1] += att * vv.y;
                O[4 * g + 2] += att * vv.z; O[4 * g + 3] += att * vv.w;
            }
        }
    }
    if (valid) {
        #pragma unroll
        for (int g = 0; g < 8; ++g) {
            float4 ov = make_float4(O[4 * g], O[4 * g + 1], O[4 * g + 2], O[4 * g + 3]);
            *(float4*)&o[((size_t)bb * NTOK + i) * 512 + s * 32 + g * 4] = ov;
        }
    }
}

// ---------------- head: LN(cls) @ head_w + head_b -> (2,4) ----------------
__global__ void head_kernel(
    const float* __restrict__ x, const float* __restrict__ g, const float* __restrict__ b,
    const float* __restrict__ w, const float* __restrict__ hb, float* __restrict__ out)
{
    int lane = threadIdx.x & 63;
    for (int bi = 0; bi < 2; ++bi) {
        const float* xr = x + (size_t)bi * NTOK * 128;
        float v0 = xr[lane], v1 = xr[lane + 64];
        float mean = wave_allreduce_sum(v0 + v1) * (1.0f / 128.0f);
        float d0 = v0 - mean, d1 = v1 - mean;
        float var = wave_allreduce_sum(d0 * d0 + d1 * d1) * (1.0f / 128.0f);
        float inv = rsqrtf(var + 1e-5f);
        float y0 = d0 * inv * g[lane] + b[lane];
        float y1 = d1 * inv * g[lane + 64] + b[lane + 64];
        for (int c = 0; c < 4; ++c) {
            float pt = y0 * w[lane * 4 + c] + y1 * w[(lane + 64) * 4 + c];
            pt = wave_allreduce_sum(pt);
            if (lane == 0) out[bi * 4 + c] = pt + hb[c];
        }
    }
}

extern "C" void kernel_launch(void* const* d_in, const int* in_sizes, int n_in,
                              void* d_out, int out_size, void* d_ws, size_t ws_size,
                              hipStream_t stream) {
    const float* eeg   = (const float*)d_in[0];
    const float* est   = (const float*)d_in[1];
    const int*   cvi   = (const int*)d_in[2];
    const float* convw = (const float*)d_in[3];
    const float* convb = (const float*)d_in[4];
    const float* cls   = (const float*)d_in[5];
    const float* clsp  = (const float*)d_in[6];
    const float* bte   = (const float*)d_in[7];
    const float* btr   = (const float*)d_in[8];
    const float* bcr   = (const float*)d_in[9];
    const float* bce   = (const float*)d_in[10];
    const float* ln1g  = (const float*)d_in[11];
    const float* ln1b  = (const float*)d_in[12];
    const float* wqkv  = (const float*)d_in[13];
    const float* wkt   = (const float*)d_in[14];
    const float* wkc   = (const float*)d_in[15];
    const float* wo    = (const float*)d_in[16];
    const float* bo    = (const float*)d_in[17];
    const float* ln2g  = (const float*)d_in[18];
    const float* ln2b  = (const float*)d_in[19];
    const float* w1    = (const float*)d_in[20];
    const float* b1    = (const float*)d_in[21];
    const float* w2    = (const float*)d_in[22];
    const float* b2    = (const float*)d_in[23];
    const float* hlng  = (const float*)d_in[24];
    const float* hlnb  = (const float*)d_in[25];
    const float* hw    = (const float*)d_in[26];
    const float* hb    = (const float*)d_in[27];

    float* ws   = (float*)d_ws;
    float* x_   = ws + OFF_X;
    float* rt_  = ws + OFF_RT;
    float* rc_  = ws + OFF_RC;
    float* xn_  = ws + OFF_XN;
    float* qkv_ = ws + OFF_QKV;
    float* kt_  = ws + OFF_KT;
    float* kc_  = ws + OFF_KC;
    float* qn_  = ws + OFF_QN;
    float* ksum_= ws + OFF_KSUM;
    float* vn_  = ws + OFF_VN;
    float* colb_= ws + OFF_COLB;
    float* attno_ = kt_;   // reuse (kt consumed by remap)
    float* ffnh_  = kc_;   // reuse (kc consumed by remap)

    embed_kernel<<<4098, 128, 0, stream>>>(eeg, est, cvi, convw, convb, cls, clsp, x_, rt_, rc_);

    for (int l = 0; l < 2; ++l) {
        ln_kernel<<<1025, 256, 0, stream>>>(x_, ln1g + l * 128, ln1b + l * 128, xn_, MROWS);
        gemm_kernel<<<dim3(24, 65), 256, 0, stream>>>(xn_, wqkv + (size_t)l * 128 * 1536, qkv_,
                                                      nullptr, nullptr, MROWS, 128, 1536, 0);
        gemm_kernel<<<dim3(8, 65), 256, 0, stream>>>(rt_, wkt + (size_t)l * 128 * 512, kt_,
                                                     nullptr, nullptr, MROWS, 128, 512, 0);
        gemm_kernel<<<dim3(8, 65), 256, 0, stream>>>(rc_, wkc + (size_t)l * 128 * 512, kc_,
                                                     nullptr, nullptr, MROWS, 128, 512, 0);
        remap_kernel<<<MROWS, 512, 0, stream>>>(qkv_, kt_, kc_, bte, btr, bcr, bce,
                                                qn_, ksum_, vn_, colb_);
        attn_kernel<<<dim3(129, 2), 256, 0, stream>>>(qn_, ksum_, vn_, colb_, attno_);
        gemm_kernel<<<dim3(2, 65), 256, 0, stream>>>(attno_, wo + (size_t)l * 512 * 128, x_,
                                                     bo + l * 128, x_, MROWS, 512, 128, 1);
        ln_kernel<<<1025, 256, 0, stream>>>(x_, ln2g + l * 128, ln2b + l * 128, xn_, MROWS);
        gemm_kernel<<<dim3(8, 65), 256, 0, stream>>>(xn_, w1 + (size_t)l * 128 * 512, ffnh_,
                                                     b1 + l * 512, nullptr, MROWS, 128, 512, 2);
        gemm_kernel<<<dim3(2, 65), 256, 0, stream>>>(ffnh_, w2 + (size_t)l * 512 * 128, x_,
                                                     b2 + l * 128, x_, MROWS, 512, 128, 1);
    }
    head_kernel<<<1, 64, 0, stream>>>(x_, hlng, hlnb, hw, hb, (float*)d_out);
}

// Round 3
// 947.011 us; speedup vs baseline: 3.8358x; 3.8358x over previous
//
#include <hip/hip_runtime.h>

#define CH    64
#define NTOK  2049
#define MROWS 4098

typedef __attribute__((ext_vector_type(8))) short bf16x8;
typedef __attribute__((ext_vector_type(4))) float f32x4;

// workspace offsets (float units)
#define OFF_X     0u
#define OFF_RT    524544u
#define OFF_RC    1049088u
#define OFF_XN    1573632u
#define OFF_QKV   2098176u
#define OFF_KT    8392704u
#define OFF_KC    10490880u
#define OFF_QNB   12589056u
#define OFF_KSB   13638144u
#define OFF_VNB   14687232u
#define OFF_VTB   15736320u
#define OFF_COLB  16801280u
// Op (bf16 partials, 4*2*2080*512 ushort) overlays QKV region; attno = KT region.

__device__ __forceinline__ float wave_allreduce_sum(float v) {
    #pragma unroll
    for (int m = 1; m < 64; m <<= 1) v += __shfl_xor(v, m);
    return v;
}

__device__ __forceinline__ ushort bf16rnd(float x) {
    unsigned u = __builtin_bit_cast(unsigned, x);
    u += 0x7FFF + ((u >> 16) & 1);
    return (ushort)(u >> 16);
}

__device__ __forceinline__ float bf16tof(ushort u) {
    return __builtin_bit_cast(float, ((unsigned)u) << 16);
}

// ---------------- embed: conv patches + cls + positional embeddings ----------------
__global__ __launch_bounds__(128) void embed_kernel(
    const float* __restrict__ eeg, const float* __restrict__ est, const int* __restrict__ cvi,
    const float* __restrict__ cw, const float* __restrict__ cb,
    const float* __restrict__ cls, const float* __restrict__ clsp,
    float* __restrict__ x, float* __restrict__ rt, float* __restrict__ rc)
{
    int id = blockIdx.x;
    int d = threadIdx.x;
    if (id >= 4096) {  // cls rows
        int b = id - 4096;
        size_t base = (size_t)b * NTOK * 128 + d;
        x[base]  = cls[d];
        rt[base] = clsp[d];
        rc[base] = clsp[d];
        return;
    }
    int b = id >> 11, rem = id & 2047, c = rem >> 5, w = rem & 31;
    __shared__ float xs[25];
    if (d < 25) xs[d] = eeg[((size_t)(b * CH + c)) * 800 + w * 25 + d];
    __syncthreads();
    float acc = cb[d];
    #pragma unroll
    for (int p = 0; p < 25; ++p) acc += xs[p] * cw[d * 25 + p];
    int i = 1 + c * 32 + w;
    size_t base = ((size_t)b * NTOK + i) * 128 + d;
    x[base] = acc;
    int k = d & 63;
    float invk = __expf(-0.14391156831f * (float)k);   // log(10000)/64
    float pt = floorf(est[b] / 0.1f) + (float)w;
    float at = pt * invk;
    rt[base] = (d < 64) ? sinf(at) : cosf(at);
    float pc = (float)cvi[b * CH + c];
    float ac = pc * invk;
    rc[base] = (d < 64) ? sinf(ac) : cosf(ac);
}

// ---------------- layernorm over D=128 ----------------
__global__ __launch_bounds__(256) void ln_kernel(
    const float* __restrict__ x, const float* __restrict__ g, const float* __restrict__ bb,
    float* __restrict__ out, int rows)
{
    int w = threadIdx.x >> 6, lane = threadIdx.x & 63;
    int row = blockIdx.x * 4 + w;
    if (row >= rows) return;
    const float* xr = x + (size_t)row * 128;
    float v0 = xr[lane], v1 = xr[lane + 64];
    float mean = wave_allreduce_sum(v0 + v1) * (1.0f / 128.0f);
    float d0 = v0 - mean, d1 = v1 - mean;
    float var = wave_allreduce_sum(d0 * d0 + d1 * d1) * (1.0f / 128.0f);
    float inv = rsqrtf(var + 1e-5f);
    out[(size_t)row * 128 + lane]      = d0 * inv * g[lane]      + bb[lane];
    out[(size_t)row * 128 + lane + 64] = d1 * inv * g[lane + 64] + bb[lane + 64];
}

// ---------------- generic tiled f32 GEMM ----------------
__global__ __launch_bounds__(256) void gemm_kernel(
    const float* __restrict__ A, const float* __restrict__ W, float* __restrict__ Cc,
    const float* __restrict__ bias, const float* __restrict__ res,
    int M, int K, int N, int mode)
{
    __shared__ float As[64][68];
    __shared__ float Bs[64][64];
    int t = threadIdx.x;
    int tx = t & 15, ty = t >> 4;
    int n0 = blockIdx.x * 64, m0 = blockIdx.y * 64;
    float acc[4][4];
    #pragma unroll
    for (int i = 0; i < 4; ++i)
        #pragma unroll
        for (int j = 0; j < 4; ++j) acc[i][j] = 0.0f;

    for (int kb = 0; kb < K; kb += 64) {
        #pragma unroll
        for (int it = 0; it < 4; ++it) {
            int r = ty + it * 16, c = tx * 4;
            int m = m0 + r; m = (m < M) ? m : (M - 1);
            float4 av = *(const float4*)&A[(size_t)m * K + kb + c];
            *(float4*)&As[r][c] = av;
        }
        #pragma unroll
        for (int it = 0; it < 4; ++it) {
            int k = ty + it * 16, c = tx * 4;
            float4 bv = *(const float4*)&W[(size_t)(kb + k) * N + n0 + c];
            *(float4*)&Bs[k][c] = bv;
        }
        __syncthreads();
        #pragma unroll 8
        for (int k = 0; k < 64; ++k) {
            float4 bv = *(float4*)&Bs[k][tx * 4];
            float a0 = As[ty * 4 + 0][k], a1 = As[ty * 4 + 1][k];
            float a2 = As[ty * 4 + 2][k], a3 = As[ty * 4 + 3][k];
            acc[0][0] += a0 * bv.x; acc[0][1] += a0 * bv.y; acc[0][2] += a0 * bv.z; acc[0][3] += a0 * bv.w;
            acc[1][0] += a1 * bv.x; acc[1][1] += a1 * bv.y; acc[1][2] += a1 * bv.z; acc[1][3] += a1 * bv.w;
            acc[2][0] += a2 * bv.x; acc[2][1] += a2 * bv.y; acc[2][2] += a2 * bv.z; acc[2][3] += a2 * bv.w;
            acc[3][0] += a3 * bv.x; acc[3][1] += a3 * bv.y; acc[3][2] += a3 * bv.z; acc[3][3] += a3 * bv.w;
        }
        __syncthreads();
    }
    #pragma unroll
    for (int i = 0; i < 4; ++i) {
        int m = m0 + ty * 4 + i;
        if (m >= M) continue;
        #pragma unroll
        for (int j = 0; j < 4; ++j) {
            int n = n0 + tx * 4 + j;
            float v = acc[i][j];
            if (mode == 1) v += bias[n] + res[(size_t)m * N + n];
            else if (mode == 2) { v += bias[n]; v = 0.5f * v * (1.0f + erff(v * 0.70710678118f)); }
            Cc[(size_t)m * N + n] = v;
        }
    }
}

// ---------------- remap qkv / kt / kc into "new space" (bf16), build ksum & column bias ----------------
__global__ __launch_bounds__(512) void remap_kernel(
    const float* __restrict__ qkv, const float* __restrict__ kt, const float* __restrict__ kc,
    const float* __restrict__ bte, const float* __restrict__ btr,
    const float* __restrict__ bcr, const float* __restrict__ bce,
    ushort* __restrict__ qn, ushort* __restrict__ ksum, ushort* __restrict__ vn,
    float* __restrict__ colb)
{
    int id = blockIdx.x;            // b2*NTOK + i2
    int b2 = id / NTOK, i2 = id - b2 * NTOK;
    int t = threadIdx.x;
    int h2 = t >> 6, d2 = t & 63;
    int G = i2 * 16 + b2 * 8 + h2;
    int bhA = G / 2049, iA = G - bhA * 2049;
    int bA = bhA >> 3, hA = bhA & 7;
    size_t qbase = ((size_t)(bA * NTOK + iA)) * 1536 + hA * 64 + d2;
    float qv = qkv[qbase], kv = qkv[qbase + 512], vv = qkv[qbase + 1024];
    int bB = G / 16392, remB = G - bB * 16392;
    int iB = remB >> 3, hB = remB & 7;
    size_t tbase = ((size_t)(bB * NTOK + iB)) * 512 + hB * 64 + d2;
    float ktv = kt[tbase], kcv = kc[tbase];
    size_t ob = (size_t)id * 512 + t;
    qn[ob] = bf16rnd(qv);
    ksum[ob] = bf16rnd(kv + ktv + kcv);
    vn[ob] = bf16rnd(vv);
    float cb = (bte[t] + bce[t]) * kv + (btr[t] + bcr[t]) * (ktv + kcv);
    cb = wave_allreduce_sum(cb);
    if (d2 == 0) colb[(size_t)id * 8 + h2] = cb;
}

// ---------------- transpose V: vn[b][j 2049][d 512] -> vt[b][d 512][j 2080] ----------------
__global__ __launch_bounds__(256) void vtrans_kernel(
    const ushort* __restrict__ vn, ushort* __restrict__ vt)
{
    __shared__ ushort tile[32][36];
    int jt = blockIdx.x, dt = blockIdx.y, b = blockIdx.z;
    int t = threadIdx.x;
    {
        int jj = t >> 3, dq = t & 7;
        int j = jt * 32 + jj; if (j > 2048) j = 2048;
        const ushort* src = vn + ((size_t)(b * NTOK + j)) * 512 + dt * 32 + dq * 4;
        *(ushort4*)&tile[jj][dq * 4] = *(const ushort4*)src;
    }
    __syncthreads();
    {
        int dd = t >> 3, jq = t & 7;
        ushort4 w;
        w.x = tile[jq * 4 + 0][dd];
        w.y = tile[jq * 4 + 1][dd];
        w.z = tile[jq * 4 + 2][dd];
        w.w = tile[jq * 4 + 3][dd];
        *(ushort4*)(vt + ((size_t)b * 512 + dt * 32 + dd) * 2080 + jt * 32 + jq * 4) = w;
    }
}

// ---------------- fused MFMA attention (softmax over heads) ----------------
__global__ __launch_bounds__(256, 2) void attn2_kernel(
    const ushort* __restrict__ qn, const ushort* __restrict__ ks,
    const ushort* __restrict__ vt, const float* __restrict__ colb,
    ushort* __restrict__ Op)
{
    __shared__ __align__(16) char smem[32768 + 16384 + 1152];
    float* cb_sh = (float*)(smem + 32768 + 16384);

    const int tid = threadIdx.x;
    const int lane = tid & 63;
    const int wave = tid >> 6;
    const int wi = wave >> 1, ws = wave & 1;
    const int g = lane >> 4, li = lane & 15;
    const int ib = blockIdx.x * 32 + wi * 16;
    const int nc = blockIdx.y, b = blockIdx.z;

    // Q fragments (8 heads x 2 ksub), k-slot map: d = d0 + 8*g + e
    bf16x8 qf[8][2];
    {
        int iq = ib + li; if (iq > 2048) iq = 2048;
        const ushort* qrow = qn + ((size_t)(b * NTOK + iq)) * 512;
        #pragma unroll
        for (int h = 0; h < 8; ++h)
            #pragma unroll
            for (int k2 = 0; k2 < 2; ++k2)
                qf[h][k2] = *(const bf16x8*)(qrow + h * 64 + k2 * 32 + 8 * g);
    }
    f32x4 o[4][4];
    #pragma unroll
    for (int a = 0; a < 4; ++a)
        #pragma unroll
        for (int m = 0; m < 4; ++m) o[a][m] = (f32x4){0.f, 0.f, 0.f, 0.f};

    const int jt0 = (nc * 65) / 4, jt1 = ((nc + 1) * 65) / 4;
    const int jcol = li + 16 * ws;

    for (int jt = jt0; jt < jt1; ++jt) {
        const int j0 = jt * 32;
        __syncthreads();   // previous tile fully consumed
        // ---- stage K tile (32 j x 512 d, 16B granules, XOR-swizzled) ----
        #pragma unroll
        for (int t = 0; t < 8; ++t) {
            int n = tid + t * 256;
            int j = n & 31, db = n >> 5;
            int jg = j0 + j; if (jg > 2048) jg = 2048;
            int4 v = *(const int4*)(ks + ((size_t)(b * NTOK + jg)) * 512 + db * 8);
            unsigned L = (unsigned)n * 16u;
            unsigned A = L ^ ((L >> 1) & 0x40u);
            *(int4*)(smem + A) = v;
        }
        // colb tile (scaled by 0.125), -inf for invalid j
        {
            int j = tid >> 3, h = tid & 7;
            int jg = j0 + j;
            float v = (jg <= 2048) ? colb[((size_t)(b * NTOK + jg)) * 8 + h] * 0.125f : -1e30f;
            cb_sh[j * 9 + h] = v;
        }
        __syncthreads();
        // ---- QK: all 8 heads, j-half = ws ----
        f32x4 s[8];
        #pragma unroll
        for (int h = 0; h < 8; ++h) {
            s[h] = (f32x4){0.f, 0.f, 0.f, 0.f};
            #pragma unroll
            for (int k2 = 0; k2 < 2; ++k2) {
                unsigned db = (unsigned)(h * 8 + k2 * 4 + g);
                unsigned L = (db * 32 + (unsigned)jcol) * 16u;
                unsigned A = L ^ ((L >> 1) & 0x40u);
                bf16x8 kf = *(const bf16x8*)(smem + A);
                s[h] = __builtin_amdgcn_mfma_f32_16x16x32_bf16(qf[h][k2], kf, s[h], 0, 0, 0);
            }
        }
        // ---- softmax over heads (in-lane), write att to swizzled LDS ----
        float cbv[8];
        #pragma unroll
        for (int h = 0; h < 8; ++h) cbv[h] = cb_sh[jcol * 9 + h];
        #pragma unroll
        for (int r = 0; r < 4; ++r) {
            float p[8]; float sum = 0.f;
            #pragma unroll
            for (int h = 0; h < 8; ++h) {
                p[h] = __expf(s[h][r] * 0.125f + cbv[h]);
                sum += p[h];
            }
            // NOTE: fmaxf(sum, 1e-20f) (NORMAL float) — rcp of a denormal arg
            // flushes to rcp(0)=inf and 0*inf=NaN poisoned round 2.
            float inv = __builtin_amdgcn_rcpf(fmaxf(sum, 1e-20f));
            #pragma unroll
            for (int h = 0; h < 8; ++h) {
                ushort ab = bf16rnd(p[h] * inv);
                unsigned L = ((unsigned)((wi * 8 + h) * 16 + 4 * g + r)) * 64u + (unsigned)jcol * 2u;
                unsigned A = L ^ ((L >> 3) & 0x70u);
                *(ushort*)(smem + 32768 + A) = ab;
            }
        }
        __syncthreads();
        // ---- PV: heads ws*4..+3, full j32; B(V) direct from global vt ----
        #pragma unroll
        for (int hh = 0; hh < 4; ++hh) {
            int h = ws * 4 + hh;
            unsigned Lr = ((unsigned)((wi * 8 + h) * 16 + li)) * 64u + 16u * (unsigned)g;
            unsigned Ar = Lr ^ ((Lr >> 3) & 0x70u);
            bf16x8 af = *(const bf16x8*)(smem + 32768 + Ar);
            const ushort* vrow = vt + ((size_t)b * 512 + h * 64 + li) * 2080 + j0 + 8 * g;
            #pragma unroll
            for (int m = 0; m < 4; ++m) {
                bf16x8 vf = *(const bf16x8*)(vrow + (size_t)m * 16 * 2080);
                o[hh][m] = __builtin_amdgcn_mfma_f32_16x16x32_bf16(af, vf, o[hh][m], 0, 0, 0);
            }
        }
    }
    // ---- store partial O (bf16): D row = i = 4g+r, col = d' ----
    {
        int irow0 = ib + 4 * g;
        #pragma unroll
        for (int hh = 0; hh < 4; ++hh) {
            int d0 = (ws * 4 + hh) * 64;
            #pragma unroll
            for (int m = 0; m < 4; ++m) {
                #pragma unroll
                for (int r = 0; r < 4; ++r) {
                    int irow = irow0 + r;
                    if (irow <= 2048) {
                        Op[(((size_t)(nc * 2 + b)) * 2080 + irow) * 512 + d0 + m * 16 + li] =
                            bf16rnd(o[hh][m][r]);
                    }
                }
            }
        }
    }
}

// ---------------- sum 4 bf16 partials -> f32 attno ----------------
__global__ __launch_bounds__(256) void osum_kernel(
    const ushort* __restrict__ Op, float* __restrict__ attno)
{
    int idx = blockIdx.x * 256 + threadIdx.x;
    if (idx >= MROWS * 64) return;
    int row = idx >> 6, dq = idx & 63;   // row = b*NTOK + i
    int b = row / NTOK, i = row - b * NTOK;
    float acc[8];
    #pragma unroll
    for (int e = 0; e < 8; ++e) acc[e] = 0.f;
    #pragma unroll
    for (int nc = 0; nc < 4; ++nc) {
        const ushort* src = Op + (((size_t)(nc * 2 + b)) * 2080 + i) * 512 + dq * 8;
        int4 v = *(const int4*)src;
        const ushort* up = (const ushort*)&v;
        #pragma unroll
        for (int e = 0; e < 8; ++e) acc[e] += bf16tof(up[e]);
    }
    float* dst = attno + (size_t)row * 512 + dq * 8;
    *(float4*)dst = make_float4(acc[0], acc[1], acc[2], acc[3]);
    *(float4*)(dst + 4) = make_float4(acc[4], acc[5], acc[6], acc[7]);
}

// ---------------- head ----------------
__global__ void head_kernel(
    const float* __restrict__ x, const float* __restrict__ g, const float* __restrict__ b,
    const float* __restrict__ w, const float* __restrict__ hb, float* __restrict__ out)
{
    int lane = threadIdx.x & 63;
    for (int bi = 0; bi < 2; ++bi) {
        const float* xr = x + (size_t)bi * NTOK * 128;
        float v0 = xr[lane], v1 = xr[lane + 64];
        float mean = wave_allreduce_sum(v0 + v1) * (1.0f / 128.0f);
        float d0 = v0 - mean, d1 = v1 - mean;
        float var = wave_allreduce_sum(d0 * d0 + d1 * d1) * (1.0f / 128.0f);
        float inv = rsqrtf(var + 1e-5f);
        float y0 = d0 * inv * g[lane] + b[lane];
        float y1 = d1 * inv * g[lane + 64] + b[lane + 64];
        for (int c = 0; c < 4; ++c) {
            float pt = y0 * w[lane * 4 + c] + y1 * w[(lane + 64) * 4 + c];
            pt = wave_allreduce_sum(pt);
            if (lane == 0) out[bi * 4 + c] = pt + hb[c];
        }
    }
}

extern "C" void kernel_launch(void* const* d_in, const int* in_sizes, int n_in,
                              void* d_out, int out_size, void* d_ws, size_t ws_size,
                              hipStream_t stream) {
    const float* eeg   = (const float*)d_in[0];
    const float* est   = (const float*)d_in[1];
    const int*   cvi   = (const int*)d_in[2];
    const float* convw = (const float*)d_in[3];
    const float* convb = (const float*)d_in[4];
    const float* cls   = (const float*)d_in[5];
    const float* clsp  = (const float*)d_in[6];
    const float* bte   = (const float*)d_in[7];
    const float* btr   = (const float*)d_in[8];
    const float* bcr   = (const float*)d_in[9];
    const float* bce   = (const float*)d_in[10];
    const float* ln1g  = (const float*)d_in[11];
    const float* ln1b  = (const float*)d_in[12];
    const float* wqkv  = (const float*)d_in[13];
    const float* wkt   = (const float*)d_in[14];
    const float* wkc   = (const float*)d_in[15];
    const float* wo    = (const float*)d_in[16];
    const float* bo    = (const float*)d_in[17];
    const float* ln2g  = (const float*)d_in[18];
    const float* ln2b  = (const float*)d_in[19];
    const float* w1    = (const float*)d_in[20];
    const float* b1    = (const float*)d_in[21];
    const float* w2    = (const float*)d_in[22];
    const float* b2    = (const float*)d_in[23];
    const float* hlng  = (const float*)d_in[24];
    const float* hlnb  = (const float*)d_in[25];
    const float* hw    = (const float*)d_in[26];
    const float* hb    = (const float*)d_in[27];

    float* ws   = (float*)d_ws;
    float* x_   = ws + OFF_X;
    float* rt_  = ws + OFF_RT;
    float* rc_  = ws + OFF_RC;
    float* xn_  = ws + OFF_XN;
    float* qkv_ = ws + OFF_QKV;
    float* kt_  = ws + OFF_KT;
    float* kc_  = ws + OFF_KC;
    ushort* qnb = (ushort*)(ws + OFF_QNB);
    ushort* ksb = (ushort*)(ws + OFF_KSB);
    ushort* vnb = (ushort*)(ws + OFF_VNB);
    ushort* vtb = (ushort*)(ws + OFF_VTB);
    float* colb_ = ws + OFF_COLB;
    ushort* opb  = (ushort*)(ws + OFF_QKV);   // Op overlays QKV (dead after remap)
    float* attno_ = kt_;                      // attno overlays KT (dead after remap)
    float* ffnh_  = kc_;                      // ffn hidden overlays KC (dead after remap)

    embed_kernel<<<4098, 128, 0, stream>>>(eeg, est, cvi, convw, convb, cls, clsp, x_, rt_, rc_);

    for (int l = 0; l < 2; ++l) {
        ln_kernel<<<1025, 256, 0, stream>>>(x_, ln1g + l * 128, ln1b + l * 128, xn_, MROWS);
        gemm_kernel<<<dim3(24, 65), 256, 0, stream>>>(xn_, wqkv + (size_t)l * 128 * 1536, qkv_,
                                                      nullptr, nullptr, MROWS, 128, 1536, 0);
        gemm_kernel<<<dim3(8, 65), 256, 0, stream>>>(rt_, wkt + (size_t)l * 128 * 512, kt_,
                                                     nullptr, nullptr, MROWS, 128, 512, 0);
        gemm_kernel<<<dim3(8, 65), 256, 0, stream>>>(rc_, wkc + (size_t)l * 128 * 512, kc_,
                                                     nullptr, nullptr, MROWS, 128, 512, 0);
        remap_kernel<<<MROWS, 512, 0, stream>>>(qkv_, kt_, kc_, bte, btr, bcr, bce,
                                                qnb, ksb, vnb, colb_);
        vtrans_kernel<<<dim3(65, 16, 2), 256, 0, stream>>>(vnb, vtb);
        attn2_kernel<<<dim3(65, 4, 2), 256, 0, stream>>>(qnb, ksb, vtb, colb_, opb);
        osum_kernel<<<1025, 256, 0, stream>>>(opb, attno_);
        gemm_kernel<<<dim3(2, 65), 256, 0, stream>>>(attno_, wo + (size_t)l * 512 * 128, x_,
                                                     bo + l * 128, x_, MROWS, 512, 128, 1);
        ln_kernel<<<1025, 256, 0, stream>>>(x_, ln2g + l * 128, ln2b + l * 128, xn_, MROWS);
        gemm_kernel<<<dim3(8, 65), 256, 0, stream>>>(xn_, w1 + (size_t)l * 128 * 512, ffnh_,
                                                     b1 + l * 512, nullptr, MROWS, 128, 512, 2);
        gemm_kernel<<<dim3(2, 65), 256, 0, stream>>>(ffnh_, w2 + (size_t)l * 512 * 128, x_,
                                                     b2 + l * 128, x_, MROWS, 512, 128, 1);
    }
    head_kernel<<<1, 64, 0, stream>>>(x_, hlng, hlnb, hw, hb, (float*)d_out);
}

// Round 4
// 764.894 us; speedup vs baseline: 4.7491x; 1.2381x over previous
//
#include <hip/hip_runtime.h>

#define CH    64
#define NTOK  2049
#define MROWS 4098

typedef __attribute__((ext_vector_type(8))) short bf16x8;
typedef __attribute__((ext_vector_type(4))) float f32x4;

// workspace offsets (float units)
#define OFF_X     0u
#define OFF_XNB   524544u
#define OFF_RTB   786816u
#define OFF_RCB   1049088u
#define OFF_QKV   1311360u
#define OFF_KT    7605888u
#define OFF_KC    9704064u
#define OFF_QNB   11802240u
#define OFF_KSB   12851328u
#define OFF_VNB   13900416u
#define OFF_VTB   14949504u
#define OFF_COLB  16014464u
#define OFF_WT    16047248u
// Op (bf16 partials, 8*2*2080*512 ushort) overlays QKV+KT+KC region.
// attnob overlays VNB (dead after vtrans); ffnhb overlays QNB (dead after attn3).

__device__ __forceinline__ float wave_allreduce_sum(float v) {
    #pragma unroll
    for (int m = 1; m < 64; m <<= 1) v += __shfl_xor(v, m);
    return v;
}

__device__ __forceinline__ ushort bf16rnd(float x) {
    unsigned u = __builtin_bit_cast(unsigned, x);
    u += 0x7FFF + ((u >> 16) & 1);
    return (ushort)(u >> 16);
}

__device__ __forceinline__ float bf16tof(ushort u) {
    return __builtin_bit_cast(float, ((unsigned)u) << 16);
}

// ---------------- weight prep: f32 [K][N] -> bf16 Wt [N][K], per layer/matrix ----------------
__global__ __launch_bounds__(256) void wprep_kernel(
    const float* __restrict__ wqkv, const float* __restrict__ wkt, const float* __restrict__ wkc,
    const float* __restrict__ wo, const float* __restrict__ w1, const float* __restrict__ w2,
    ushort* __restrict__ wT)
{
    int l = blockIdx.z, mat = blockIdx.y;
    int idx = blockIdx.x * 256 + threadIdx.x;
    const float* src; int K, N, off, lg;
    switch (mat) {
        case 0: src = wqkv + (size_t)l * 196608; K = 128; N = 1536; off = 0;      lg = 7; break;
        case 1: src = wkt  + (size_t)l * 65536;  K = 128; N = 512;  off = 196608; lg = 7; break;
        case 2: src = wkc  + (size_t)l * 65536;  K = 128; N = 512;  off = 262144; lg = 7; break;
        case 3: src = wo   + (size_t)l * 65536;  K = 512; N = 128;  off = 327680; lg = 9; break;
        case 4: src = w1   + (size_t)l * 65536;  K = 128; N = 512;  off = 393216; lg = 7; break;
        default: src = w2  + (size_t)l * 65536;  K = 512; N = 128;  off = 458752; lg = 9; break;
    }
    if (idx >= K * N) return;
    int k = idx & (K - 1), n = idx >> lg;
    wT[(size_t)l * 524288 + off + idx] = bf16rnd(src[(size_t)k * N + n]);
}

// ---------------- embed: conv patches + cls + positional embeddings ----------------
__global__ __launch_bounds__(128) void embed_kernel(
    const float* __restrict__ eeg, const float* __restrict__ est, const int* __restrict__ cvi,
    const float* __restrict__ cw, const float* __restrict__ cb,
    const float* __restrict__ cls, const float* __restrict__ clsp,
    float* __restrict__ x, ushort* __restrict__ rt, ushort* __restrict__ rc)
{
    int id = blockIdx.x;
    int d = threadIdx.x;
    if (id >= 4096) {  // cls rows
        int b = id - 4096;
        size_t base = (size_t)b * NTOK * 128 + d;
        x[base]  = cls[d];
        rt[base] = bf16rnd(clsp[d]);
        rc[base] = bf16rnd(clsp[d]);
        return;
    }
    int b = id >> 11, rem = id & 2047, c = rem >> 5, w = rem & 31;
    __shared__ float xs[25];
    if (d < 25) xs[d] = eeg[((size_t)(b * CH + c)) * 800 + w * 25 + d];
    __syncthreads();
    float acc = cb[d];
    #pragma unroll
    for (int p = 0; p < 25; ++p) acc += xs[p] * cw[d * 25 + p];
    int i = 1 + c * 32 + w;
    size_t base = ((size_t)b * NTOK + i) * 128 + d;
    x[base] = acc;
    int k = d & 63;
    float invk = __expf(-0.14391156831f * (float)k);   // log(10000)/64
    float pt = floorf(est[b] / 0.1f) + (float)w;
    float at = pt * invk;
    rt[base] = bf16rnd((d < 64) ? sinf(at) : cosf(at));
    float pc = (float)cvi[b * CH + c];
    float ac = pc * invk;
    rc[base] = bf16rnd((d < 64) ? sinf(ac) : cosf(ac));
}

// ---------------- layernorm over D=128, bf16 out ----------------
__global__ __launch_bounds__(256) void ln_kernel(
    const float* __restrict__ x, const float* __restrict__ g, const float* __restrict__ bb,
    ushort* __restrict__ out, int rows)
{
    int w = threadIdx.x >> 6, lane = threadIdx.x & 63;
    int row = blockIdx.x * 4 + w;
    if (row >= rows) return;
    const float* xr = x + (size_t)row * 128;
    float v0 = xr[lane], v1 = xr[lane + 64];
    float mean = wave_allreduce_sum(v0 + v1) * (1.0f / 128.0f);
    float d0 = v0 - mean, d1 = v1 - mean;
    float var = wave_allreduce_sum(d0 * d0 + d1 * d1) * (1.0f / 128.0f);
    float inv = rsqrtf(var + 1e-5f);
    out[(size_t)row * 128 + lane]      = bf16rnd(d0 * inv * g[lane]      + bb[lane]);
    out[(size_t)row * 128 + lane + 64] = bf16rnd(d1 * inv * g[lane + 64] + bb[lane + 64]);
}

// ---------------- bf16 MFMA GEMM: C[MxN] = A[MxK] (bf16) * Wt[NxK] (bf16) ----------------
// 128x128 tile, 4 waves (2x2), each wave 64x64 (4x4 frags of 16x16), K-step 32.
// mode: 0 -> outF; 1 -> outF = acc + bias + res; 2 -> outB = bf16(gelu(acc + bias))
__global__ __launch_bounds__(256) void mgemm_kernel(
    const ushort* __restrict__ A, const ushort* __restrict__ Wt,
    float* outF, ushort* outB, const float* bias, const float* res,
    int M, int K, int N, int mode)
{
    __shared__ ushort Alds[128 * 40];
    __shared__ ushort Blds[128 * 40];
    int tid = threadIdx.x;
    int lane = tid & 63, wv = tid >> 6;
    int wm = wv >> 1, wn = wv & 1;
    int li = lane & 15, g = lane >> 4;
    int m0 = blockIdx.y * 128, n0 = blockIdx.x * 128;
    f32x4 acc[4][4];
    #pragma unroll
    for (int a = 0; a < 4; ++a)
        #pragma unroll
        for (int c = 0; c < 4; ++c) acc[a][c] = (f32x4){0.f, 0.f, 0.f, 0.f};

    for (int kb = 0; kb < K; kb += 32) {
        #pragma unroll
        for (int it = 0; it < 2; ++it) {
            int gi = tid + it * 256;
            int row = gi >> 2, gc = gi & 3;
            int m = m0 + row; if (m >= M) m = M - 1;
            bf16x8 av = *(const bf16x8*)(A + (size_t)m * K + kb + gc * 8);
            *(bf16x8*)&Alds[row * 40 + ((gc ^ (row & 3)) << 3)] = av;
            int n = n0 + row;
            bf16x8 bv = *(const bf16x8*)(Wt + (size_t)n * K + kb + gc * 8);
            *(bf16x8*)&Blds[row * 40 + ((gc ^ (row & 3)) << 3)] = bv;
        }
        __syncthreads();
        bf16x8 af[4], bfr[4];
        #pragma unroll
        for (int xx = 0; xx < 4; ++xx) {
            af[xx]  = *(const bf16x8*)&Alds[(wm * 64 + xx * 16 + li) * 40 + ((g ^ (li & 3)) << 3)];
            bfr[xx] = *(const bf16x8*)&Blds[(wn * 64 + xx * 16 + li) * 40 + ((g ^ (li & 3)) << 3)];
        }
        #pragma unroll
        for (int mi = 0; mi < 4; ++mi)
            #pragma unroll
            for (int ni = 0; ni < 4; ++ni)
                acc[mi][ni] = __builtin_amdgcn_mfma_f32_16x16x32_bf16(af[mi], bfr[ni], acc[mi][ni], 0, 0, 0);
        __syncthreads();
    }
    #pragma unroll
    for (int mi = 0; mi < 4; ++mi) {
        #pragma unroll
        for (int r = 0; r < 4; ++r) {
            int m = m0 + wm * 64 + mi * 16 + 4 * g + r;
            if (m >= M) continue;
            #pragma unroll
            for (int ni = 0; ni < 4; ++ni) {
                int n = n0 + wn * 64 + ni * 16 + li;
                float v = acc[mi][ni][r];
                if (mode == 1) {
                    v += bias[n] + res[(size_t)m * N + n];
                    outF[(size_t)m * N + n] = v;
                } else if (mode == 2) {
                    v += bias[n];
                    v = 0.5f * v * (1.0f + erff(v * 0.70710678118f));
                    outB[(size_t)m * N + n] = bf16rnd(v);
                } else {
                    outF[(size_t)m * N + n] = v;
                }
            }
        }
    }
}

// ---------------- remap qkv / kt / kc into "new space" (bf16), build ksum & column bias ----------------
__global__ __launch_bounds__(512) void remap_kernel(
    const float* __restrict__ qkv, const float* __restrict__ kt, const float* __restrict__ kc,
    const float* __restrict__ bte, const float* __restrict__ btr,
    const float* __restrict__ bcr, const float* __restrict__ bce,
    ushort* __restrict__ qn, ushort* __restrict__ ksum, ushort* __restrict__ vn,
    float* __restrict__ colb)
{
    int id = blockIdx.x;            // b2*NTOK + i2
    int b2 = id / NTOK, i2 = id - b2 * NTOK;
    int t = threadIdx.x;
    int h2 = t >> 6, d2 = t & 63;
    int G = i2 * 16 + b2 * 8 + h2;
    int bhA = G / 2049, iA = G - bhA * 2049;
    int bA = bhA >> 3, hA = bhA & 7;
    size_t qbase = ((size_t)(bA * NTOK + iA)) * 1536 + hA * 64 + d2;
    float qv = qkv[qbase], kv = qkv[qbase + 512], vv = qkv[qbase + 1024];
    int bB = G / 16392, remB = G - bB * 16392;
    int iB = remB >> 3, hB = remB & 7;
    size_t tbase = ((size_t)(bB * NTOK + iB)) * 512 + hB * 64 + d2;
    float ktv = kt[tbase], kcv = kc[tbase];
    size_t ob = (size_t)id * 512 + t;
    qn[ob] = bf16rnd(qv);
    ksum[ob] = bf16rnd(kv + ktv + kcv);
    vn[ob] = bf16rnd(vv);
    float cbx = (bte[t] + bce[t]) * kv + (btr[t] + bcr[t]) * (ktv + kcv);
    cbx = wave_allreduce_sum(cbx);
    if (d2 == 0) colb[(size_t)id * 8 + h2] = cbx;
}

// ---------------- transpose V: vn[b][j 2049][d 512] -> vt[b][d 512][j 2080] ----------------
__global__ __launch_bounds__(256) void vtrans_kernel(
    const ushort* __restrict__ vn, ushort* __restrict__ vt)
{
    __shared__ ushort tile[32][36];
    int jt = blockIdx.x, dt = blockIdx.y, b = blockIdx.z;
    int t = threadIdx.x;
    {
        int jj = t >> 3, dq = t & 7;
        int j = jt * 32 + jj; if (j > 2048) j = 2048;
        const ushort* src = vn + ((size_t)(b * NTOK + j)) * 512 + dt * 32 + dq * 4;
        *(ushort4*)&tile[jj][dq * 4] = *(const ushort4*)src;
    }
    __syncthreads();
    {
        int dd = t >> 3, jq = t & 7;
        ushort4 w;
        w.x = tile[jq * 4 + 0][dd];
        w.y = tile[jq * 4 + 1][dd];
        w.z = tile[jq * 4 + 2][dd];
        w.w = tile[jq * 4 + 3][dd];
        *(ushort4*)(vt + ((size_t)b * 512 + dt * 32 + dd) * 2080 + jt * 32 + jq * 4) = w;
    }
}

// ---------------- fused MFMA attention (softmax over heads), latency-hidden ----------------
// grid (65, 8, 2), 256 thr = 4 waves (wi: i-16-subtile, ws: j-half for QK / head-half for PV).
// LDS: K tile 32KB | Q tile 32KB | att 16KB  (= 80KB, 2 blocks/CU)
// Prefetch: next K tile + this tile's V frags + colb into regs at top of each iter.
__global__ __launch_bounds__(256) void attn3_kernel(
    const ushort* __restrict__ qn, const ushort* __restrict__ ks,
    const ushort* __restrict__ vt, const float* __restrict__ colb,
    ushort* __restrict__ Op)
{
    __shared__ __align__(16) char smem[81920];
    const int tid = threadIdx.x;
    const int lane = tid & 63;
    const int wave = tid >> 6;
    const int wi = wave >> 1, ws = wave & 1;
    const int g = lane >> 4, li = lane & 15;
    const int nc = blockIdx.y, b = blockIdx.z;
    const int jt0 = (nc * 65) >> 3, jt1 = ((nc + 1) * 65) >> 3;
    const int jcol = li + 16 * ws;

    // ---- prologue: stage Q (block's 32 rows) and K tile jt0, swizzled [d-gran][row] ----
    #pragma unroll
    for (int t = 0; t < 8; ++t) {
        int n = tid + t * 256;
        int il = n & 31, db = n >> 5;
        int iq = blockIdx.x * 32 + il; if (iq > 2048) iq = 2048;
        int4 v = *(const int4*)(qn + ((size_t)(b * NTOK + iq)) * 512 + db * 8);
        unsigned L = (unsigned)n * 16u;
        *(int4*)(smem + 32768 + (L ^ ((L >> 1) & 0x40u))) = v;
    }
    {
        int j0 = jt0 * 32;
        #pragma unroll
        for (int t = 0; t < 8; ++t) {
            int n = tid + t * 256;
            int j = n & 31, db = n >> 5;
            int jg = j0 + j; if (jg > 2048) jg = 2048;
            int4 v = *(const int4*)(ks + ((size_t)(b * NTOK + jg)) * 512 + db * 8);
            unsigned L = (unsigned)n * 16u;
            *(int4*)(smem + (L ^ ((L >> 1) & 0x40u))) = v;
        }
    }
    f32x4 o[4][4];
    #pragma unroll
    for (int a = 0; a < 4; ++a)
        #pragma unroll
        for (int m = 0; m < 4; ++m) o[a][m] = (f32x4){0.f, 0.f, 0.f, 0.f};
    __syncthreads();

    for (int jt = jt0; jt < jt1; ++jt) {
        const int j0 = jt * 32;
        const bool hasNext = (jt + 1 < jt1);
        // ---- prefetch next K tile into regs (consumed after sync_A) ----
        int4 kpre[8];
        if (hasNext) {
            int j0n = j0 + 32;
            #pragma unroll
            for (int t = 0; t < 8; ++t) {
                int n = tid + t * 256;
                int j = n & 31, db = n >> 5;
                int jg = j0n + j; if (jg > 2048) jg = 2048;
                kpre[t] = *(const int4*)(ks + ((size_t)(b * NTOK + jg)) * 512 + db * 8);
            }
        }
        // ---- prefetch V fragments for THIS tile (consumed in PV) ----
        bf16x8 vf[4][4];
        #pragma unroll
        for (int hh = 0; hh < 4; ++hh) {
            const ushort* vrow = vt + ((size_t)b * 512 + (ws * 4 + hh) * 64 + li) * 2080 + j0 + 8 * g;
            #pragma unroll
            for (int m = 0; m < 4; ++m)
                vf[hh][m] = *(const bf16x8*)(vrow + (size_t)m * 16 * 2080);
        }
        // ---- colb for this tile's column (per-lane, 8 heads) ----
        float cbv[8];
        {
            int jg = j0 + jcol;
            int jc = jg > 2048 ? 2048 : jg;
            const float* cp = colb + ((size_t)(b * NTOK + jc)) * 8;
            float4 c0 = *(const float4*)cp;
            float4 c1 = *(const float4*)(cp + 4);
            cbv[0] = c0.x; cbv[1] = c0.y; cbv[2] = c0.z; cbv[3] = c0.w;
            cbv[4] = c1.x; cbv[5] = c1.y; cbv[6] = c1.z; cbv[7] = c1.w;
            #pragma unroll
            for (int h = 0; h < 8; ++h) cbv[h] = (jg > 2048) ? -1e30f : cbv[h] * 0.125f;
        }
        // ---- QK: all 8 heads, this wave's j-half; Q and K frags from LDS ----
        f32x4 s[8];
        #pragma unroll
        for (int h = 0; h < 8; ++h) {
            s[h] = (f32x4){0.f, 0.f, 0.f, 0.f};
            #pragma unroll
            for (int k2 = 0; k2 < 2; ++k2) {
                unsigned db = (unsigned)(h * 8 + k2 * 4 + g);
                unsigned Lq = (db * 32 + (unsigned)(wi * 16 + li)) * 16u;
                bf16x8 qf = *(const bf16x8*)(smem + 32768 + (Lq ^ ((Lq >> 1) & 0x40u)));
                unsigned Lk = (db * 32 + (unsigned)jcol) * 16u;
                bf16x8 kf = *(const bf16x8*)(smem + (Lk ^ ((Lk >> 1) & 0x40u)));
                s[h] = __builtin_amdgcn_mfma_f32_16x16x32_bf16(qf, kf, s[h], 0, 0, 0);
            }
        }
        // ---- softmax over heads (in-lane), att -> swizzled LDS ----
        #pragma unroll
        for (int r = 0; r < 4; ++r) {
            float p[8]; float sum = 0.f;
            #pragma unroll
            for (int h = 0; h < 8; ++h) {
                p[h] = __expf(s[h][r] * 0.125f + cbv[h]);
                sum += p[h];
            }
            float inv = __builtin_amdgcn_rcpf(fmaxf(sum, 1e-20f));  // NORMAL floor (denorm rcp -> inf!)
            #pragma unroll
            for (int h = 0; h < 8; ++h) {
                ushort ab = bf16rnd(p[h] * inv);
                unsigned L = ((unsigned)((wi * 8 + h) * 16 + 4 * g + r)) * 64u + (unsigned)jcol * 2u;
                *(ushort*)(smem + 65536 + (L ^ ((L >> 3) & 0x70u))) = ab;
            }
        }
        __syncthreads();   // A: att visible; K-LDS reads done
        if (hasNext) {
            #pragma unroll
            for (int t = 0; t < 8; ++t) {
                int n = tid + t * 256;
                unsigned L = (unsigned)n * 16u;
                *(int4*)(smem + (L ^ ((L >> 1) & 0x40u))) = kpre[t];
            }
        }
        // ---- PV: heads ws*4..+3, full j32; V from prefetched regs ----
        #pragma unroll
        for (int hh = 0; hh < 4; ++hh) {
            int h = ws * 4 + hh;
            unsigned Lr = ((unsigned)((wi * 8 + h) * 16 + li)) * 64u + 16u * (unsigned)g;
            bf16x8 af = *(const bf16x8*)(smem + 65536 + (Lr ^ ((Lr >> 3) & 0x70u)));
            #pragma unroll
            for (int m = 0; m < 4; ++m)
                o[hh][m] = __builtin_amdgcn_mfma_f32_16x16x32_bf16(af, vf[hh][m], o[hh][m], 0, 0, 0);
        }
        __syncthreads();   // B: K tile jt+1 ready; att reads done
    }
    // ---- store partial O (bf16) ----
    {
        int ib = blockIdx.x * 32 + wi * 16;
        int irow0 = ib + 4 * g;
        #pragma unroll
        for (int hh = 0; hh < 4; ++hh) {
            int d0 = (ws * 4 + hh) * 64;
            #pragma unroll
            for (int m = 0; m < 4; ++m) {
                #pragma unroll
                for (int r = 0; r < 4; ++r) {
                    int irow = irow0 + r;
                    if (irow <= 2048) {
                        Op[(((size_t)(nc * 2 + b)) * 2080 + irow) * 512 + d0 + m * 16 + li] =
                            bf16rnd(o[hh][m][r]);
                    }
                }
            }
        }
    }
}

// ---------------- sum 8 bf16 partials -> bf16 attno ----------------
__global__ __launch_bounds__(256) void osum_kernel(
    const ushort* __restrict__ Op, ushort* __restrict__ attno)
{
    int idx = blockIdx.x * 256 + threadIdx.x;
    if (idx >= MROWS * 64) return;
    int row = idx >> 6, dq = idx & 63;   // row = b*NTOK + i
    int b = row / NTOK, i = row - b * NTOK;
    float acc[8];
    #pragma unroll
    for (int e = 0; e < 8; ++e) acc[e] = 0.f;
    #pragma unroll
    for (int nc = 0; nc < 8; ++nc) {
        const ushort* src = Op + (((size_t)(nc * 2 + b)) * 2080 + i) * 512 + dq * 8;
        int4 v = *(const int4*)src;
        const ushort* up = (const ushort*)&v;
        #pragma unroll
        for (int e = 0; e < 8; ++e) acc[e] += bf16tof(up[e]);
    }
    ushort ov[8];
    #pragma unroll
    for (int e = 0; e < 8; ++e) ov[e] = bf16rnd(acc[e]);
    *(int4*)(attno + (size_t)row * 512 + dq * 8) = *(int4*)ov;
}

// ---------------- head ----------------
__global__ void head_kernel(
    const float* __restrict__ x, const float* __restrict__ g, const float* __restrict__ b,
    const float* __restrict__ w, const float* __restrict__ hb, float* __restrict__ out)
{
    int lane = threadIdx.x & 63;
    for (int bi = 0; bi < 2; ++bi) {
        const float* xr = x + (size_t)bi * NTOK * 128;
        float v0 = xr[lane], v1 = xr[lane + 64];
        float mean = wave_allreduce_sum(v0 + v1) * (1.0f / 128.0f);
        float d0 = v0 - mean, d1 = v1 - mean;
        float var = wave_allreduce_sum(d0 * d0 + d1 * d1) * (1.0f / 128.0f);
        float inv = rsqrtf(var + 1e-5f);
        float y0 = d0 * inv * g[lane] + b[lane];
        float y1 = d1 * inv * g[lane + 64] + b[lane + 64];
        for (int c = 0; c < 4; ++c) {
            float pt = y0 * w[lane * 4 + c] + y1 * w[(lane + 64) * 4 + c];
            pt = wave_allreduce_sum(pt);
            if (lane == 0) out[bi * 4 + c] = pt + hb[c];
        }
    }
}

extern "C" void kernel_launch(void* const* d_in, const int* in_sizes, int n_in,
                              void* d_out, int out_size, void* d_ws, size_t ws_size,
                              hipStream_t stream) {
    const float* eeg   = (const float*)d_in[0];
    const float* est   = (const float*)d_in[1];
    const int*   cvi   = (const int*)d_in[2];
    const float* convw = (const float*)d_in[3];
    const float* convb = (const float*)d_in[4];
    const float* cls   = (const float*)d_in[5];
    const float* clsp  = (const float*)d_in[6];
    const float* bte   = (const float*)d_in[7];
    const float* btr   = (const float*)d_in[8];
    const float* bcr   = (const float*)d_in[9];
    const float* bce   = (const float*)d_in[10];
    const float* ln1g  = (const float*)d_in[11];
    const float* ln1b  = (const float*)d_in[12];
    const float* wqkv  = (const float*)d_in[13];
    const float* wkt   = (const float*)d_in[14];
    const float* wkc   = (const float*)d_in[15];
    const float* wo    = (const float*)d_in[16];
    const float* bo    = (const float*)d_in[17];
    const float* ln2g  = (const float*)d_in[18];
    const float* ln2b  = (const float*)d_in[19];
    const float* w1    = (const float*)d_in[20];
    const float* b1    = (const float*)d_in[21];
    const float* w2    = (const float*)d_in[22];
    const float* b2    = (const float*)d_in[23];
    const float* hlng  = (const float*)d_in[24];
    const float* hlnb  = (const float*)d_in[25];
    const float* hw    = (const float*)d_in[26];
    const float* hb    = (const float*)d_in[27];

    float* ws    = (float*)d_ws;
    float* x_    = ws + OFF_X;
    ushort* xnb  = (ushort*)(ws + OFF_XNB);
    ushort* rtb  = (ushort*)(ws + OFF_RTB);
    ushort* rcb  = (ushort*)(ws + OFF_RCB);
    float* qkv_  = ws + OFF_QKV;
    float* kt_   = ws + OFF_KT;
    float* kc_   = ws + OFF_KC;
    ushort* qnb  = (ushort*)(ws + OFF_QNB);
    ushort* ksb  = (ushort*)(ws + OFF_KSB);
    ushort* vnb  = (ushort*)(ws + OFF_VNB);
    ushort* vtb  = (ushort*)(ws + OFF_VTB);
    float* colb_ = ws + OFF_COLB;
    ushort* wT   = (ushort*)(ws + OFF_WT);
    ushort* opb  = (ushort*)(ws + OFF_QKV);   // Op overlays QKV+KT+KC (dead after remap)
    ushort* attnob = vnb;                     // overlays VNB (dead after vtrans)
    ushort* ffnhb  = qnb;                     // overlays QNB (dead after attn3)

    wprep_kernel<<<dim3(768, 6, 2), 256, 0, stream>>>(wqkv, wkt, wkc, wo, w1, w2, wT);
    embed_kernel<<<4098, 128, 0, stream>>>(eeg, est, cvi, convw, convb, cls, clsp, x_, rtb, rcb);

    for (int l = 0; l < 2; ++l) {
        const ushort* wTl = wT + (size_t)l * 524288;
        ln_kernel<<<1025, 256, 0, stream>>>(x_, ln1g + l * 128, ln1b + l * 128, xnb, MROWS);
        mgemm_kernel<<<dim3(12, 33), 256, 0, stream>>>(xnb, wTl, qkv_, nullptr, nullptr, nullptr,
                                                       MROWS, 128, 1536, 0);
        mgemm_kernel<<<dim3(4, 33), 256, 0, stream>>>(rtb, wTl + 196608, kt_, nullptr, nullptr, nullptr,
                                                      MROWS, 128, 512, 0);
        mgemm_kernel<<<dim3(4, 33), 256, 0, stream>>>(rcb, wTl + 262144, kc_, nullptr, nullptr, nullptr,
                                                      MROWS, 128, 512, 0);
        remap_kernel<<<MROWS, 512, 0, stream>>>(qkv_, kt_, kc_, bte, btr, bcr, bce,
                                                qnb, ksb, vnb, colb_);
        vtrans_kernel<<<dim3(65, 16, 2), 256, 0, stream>>>(vnb, vtb);
        attn3_kernel<<<dim3(65, 8, 2), 256, 0, stream>>>(qnb, ksb, vtb, colb_, opb);
        osum_kernel<<<1025, 256, 0, stream>>>(opb, attnob);
        mgemm_kernel<<<dim3(1, 33), 256, 0, stream>>>(attnob, wTl + 327680, x_, nullptr,
                                                      bo + l * 128, x_, MROWS, 512, 128, 1);
        ln_kernel<<<1025, 256, 0, stream>>>(x_, ln2g + l * 128, ln2b + l * 128, xnb, MROWS);
        mgemm_kernel<<<dim3(4, 33), 256, 0, stream>>>(xnb, wTl + 393216, nullptr, ffnhb,
                                                      b1 + l * 512, nullptr, MROWS, 128, 512, 2);
        mgemm_kernel<<<dim3(1, 33), 256, 0, stream>>>(ffnhb, wTl + 458752, x_, nullptr,
                                                      b2 + l * 128, x_, MROWS, 512, 128, 1);
    }
    head_kernel<<<1, 64, 0, stream>>>(x_, hlng, hlnb, hw, hb, (float*)d_out);
}

// Round 5
// 636.885 us; speedup vs baseline: 5.7036x; 1.2010x over previous
//
#include <hip/hip_runtime.h>

#define CH    64
#define NTOK  2049
#define MROWS 4098
#define NCJ   3

typedef __attribute__((ext_vector_type(8))) short bf16x8;
typedef __attribute__((ext_vector_type(4))) float f32x4;

// workspace offsets (float units) — sequential, no overlays
#define OFF_X     0u
#define OFF_XNB   524544u
#define OFF_RTB   786816u
#define OFF_RCB   1049088u
#define OFF_QKVB  1311360u
#define OFF_KTCB  4458624u
#define OFF_QNB   5507712u
#define OFF_KSB   6556800u
#define OFF_VNB   7605888u
#define OFF_VTB   8654976u
#define OFF_COLB  9719936u
#define OFF_WT    9752720u
#define OFF_OP    10277008u
#define OFF_ATTNO 13424272u
#define OFF_FFNH  14473360u

__device__ __forceinline__ float wave_allreduce_sum(float v) {
    #pragma unroll
    for (int m = 1; m < 64; m <<= 1) v += __shfl_xor(v, m);
    return v;
}

__device__ __forceinline__ ushort bf16rnd(float x) {
    unsigned u = __builtin_bit_cast(unsigned, x);
    u += 0x7FFF + ((u >> 16) & 1);
    return (ushort)(u >> 16);
}

__device__ __forceinline__ float bf16tof(ushort u) {
    return __builtin_bit_cast(float, ((unsigned)u) << 16);
}

// ---------------- weight prep: f32 [K][N] -> bf16 Wt [N][K] (ktc concatenated) ----------------
__global__ __launch_bounds__(256) void wprep_kernel(
    const float* __restrict__ wqkv, const float* __restrict__ wkt, const float* __restrict__ wkc,
    const float* __restrict__ wo, const float* __restrict__ w1, const float* __restrict__ w2,
    ushort* __restrict__ wT)
{
    int l = blockIdx.z, mat = blockIdx.y;
    int idx = blockIdx.x * 256 + threadIdx.x;
    float v; int off;
    if (mat == 0) {            // qkv: N=1536 K=128
        if (idx >= 196608) return;
        int n = idx >> 7, k = idx & 127;
        v = wqkv[(size_t)l * 196608 + (size_t)k * 1536 + n]; off = 0;
    } else if (mat == 1) {     // ktc: N=512 K=256 (wkt | wkc)
        if (idx >= 131072) return;
        int n = idx >> 8, k = idx & 255;
        v = (k < 128) ? wkt[(size_t)l * 65536 + (size_t)k * 512 + n]
                      : wkc[(size_t)l * 65536 + (size_t)(k - 128) * 512 + n];
        off = 196608;
    } else if (mat == 2) {     // wo: N=128 K=512
        if (idx >= 65536) return;
        int n = idx >> 9, k = idx & 511;
        v = wo[(size_t)l * 65536 + (size_t)k * 128 + n]; off = 327680;
    } else if (mat == 3) {     // w1: N=512 K=128
        if (idx >= 65536) return;
        int n = idx >> 7, k = idx & 127;
        v = w1[(size_t)l * 65536 + (size_t)k * 512 + n]; off = 393216;
    } else {                   // w2: N=128 K=512
        if (idx >= 65536) return;
        int n = idx >> 9, k = idx & 511;
        v = w2[(size_t)l * 65536 + (size_t)k * 128 + n]; off = 458752;
    }
    wT[(size_t)l * 524288 + off + idx] = bf16rnd(v);
}

// ---------------- embed ----------------
__global__ __launch_bounds__(128) void embed_kernel(
    const float* __restrict__ eeg, const float* __restrict__ est, const int* __restrict__ cvi,
    const float* __restrict__ cw, const float* __restrict__ cb,
    const float* __restrict__ cls, const float* __restrict__ clsp,
    float* __restrict__ x, ushort* __restrict__ rt, ushort* __restrict__ rc)
{
    int id = blockIdx.x;
    int d = threadIdx.x;
    if (id >= 4096) {
        int b = id - 4096;
        size_t base = (size_t)b * NTOK * 128 + d;
        x[base]  = cls[d];
        rt[base] = bf16rnd(clsp[d]);
        rc[base] = bf16rnd(clsp[d]);
        return;
    }
    int b = id >> 11, rem = id & 2047, c = rem >> 5, w = rem & 31;
    __shared__ float xs[25];
    if (d < 25) xs[d] = eeg[((size_t)(b * CH + c)) * 800 + w * 25 + d];
    __syncthreads();
    float acc = cb[d];
    #pragma unroll
    for (int p = 0; p < 25; ++p) acc += xs[p] * cw[d * 25 + p];
    int i = 1 + c * 32 + w;
    size_t base = ((size_t)b * NTOK + i) * 128 + d;
    x[base] = acc;
    int k = d & 63;
    float invk = __expf(-0.14391156831f * (float)k);
    float pt = floorf(est[b] / 0.1f) + (float)w;
    float at = pt * invk;
    rt[base] = bf16rnd((d < 64) ? sinf(at) : cosf(at));
    float pc = (float)cvi[b * CH + c];
    float ac = pc * invk;
    rc[base] = bf16rnd((d < 64) ? sinf(ac) : cosf(ac));
}

// ---------------- layernorm, bf16 out ----------------
__global__ __launch_bounds__(256) void ln_kernel(
    const float* __restrict__ x, const float* __restrict__ g, const float* __restrict__ bb,
    ushort* __restrict__ out, int rows)
{
    int w = threadIdx.x >> 6, lane = threadIdx.x & 63;
    int row = blockIdx.x * 4 + w;
    if (row >= rows) return;
    const float* xr = x + (size_t)row * 128;
    float v0 = xr[lane], v1 = xr[lane + 64];
    float mean = wave_allreduce_sum(v0 + v1) * (1.0f / 128.0f);
    float d0 = v0 - mean, d1 = v1 - mean;
    float var = wave_allreduce_sum(d0 * d0 + d1 * d1) * (1.0f / 128.0f);
    float inv = rsqrtf(var + 1e-5f);
    out[(size_t)row * 128 + lane]      = bf16rnd(d0 * inv * g[lane]      + bb[lane]);
    out[(size_t)row * 128 + lane + 64] = bf16rnd(d1 * inv * g[lane + 64] + bb[lane + 64]);
}

// ---------------- bf16 MFMA GEMM: C = A[MxK] * Wt[NxK]; A may be [A | A2] concat on K ----------------
// mode: 0 -> outF f32; 1 -> outF = acc + bias + res; 2 -> outB = bf16(gelu(acc+bias)); 3 -> outB = bf16(acc)
__global__ __launch_bounds__(256, 3) void mgemm_kernel(
    const ushort* __restrict__ A, const ushort* __restrict__ A2, int K1,
    const ushort* __restrict__ Wt,
    float* outF, ushort* outB, const float* bias, const float* res,
    int M, int K, int N, int mode)
{
    __shared__ ushort Alds[128 * 72];
    __shared__ ushort Blds[128 * 72];
    int tid = threadIdx.x;
    int lane = tid & 63, wv = tid >> 6;
    int wm = wv >> 1, wn = wv & 1;
    int li = lane & 15, g = lane >> 4;
    int m0 = blockIdx.y * 128, n0 = blockIdx.x * 128;
    int K2s = K - K1;
    f32x4 acc[4][4];
    #pragma unroll
    for (int a = 0; a < 4; ++a)
        #pragma unroll
        for (int c = 0; c < 4; ++c) acc[a][c] = (f32x4){0.f, 0.f, 0.f, 0.f};

    for (int kb = 0; kb < K; kb += 64) {
        #pragma unroll
        for (int it = 0; it < 4; ++it) {
            int gi = tid + it * 256;
            int row = gi >> 3, gc = gi & 7;
            int m = m0 + row; if (m >= M) m = M - 1;
            int acol = kb + gc * 8;
            const ushort* asrc = (acol < K1) ? (A + (size_t)m * K1 + acol)
                                             : (A2 + (size_t)m * K2s + (acol - K1));
            bf16x8 av = *(const bf16x8*)asrc;
            *(bf16x8*)&Alds[row * 72 + ((gc ^ (row & 7)) << 3)] = av;
            int n = n0 + row;
            bf16x8 bv = *(const bf16x8*)(Wt + (size_t)n * K + acol);
            *(bf16x8*)&Blds[row * 72 + ((gc ^ (row & 7)) << 3)] = bv;
        }
        __syncthreads();
        #pragma unroll
        for (int k2 = 0; k2 < 2; ++k2) {
            bf16x8 af[4], bfr[4];
            #pragma unroll
            for (int xx = 0; xx < 4; ++xx) {
                int ra = wm * 64 + xx * 16 + li;
                int rb = wn * 64 + xx * 16 + li;
                af[xx]  = *(const bf16x8*)&Alds[ra * 72 + (((k2 * 4 + g) ^ (ra & 7)) << 3)];
                bfr[xx] = *(const bf16x8*)&Blds[rb * 72 + (((k2 * 4 + g) ^ (rb & 7)) << 3)];
            }
            #pragma unroll
            for (int mi = 0; mi < 4; ++mi)
                #pragma unroll
                for (int ni = 0; ni < 4; ++ni)
                    acc[mi][ni] = __builtin_amdgcn_mfma_f32_16x16x32_bf16(af[mi], bfr[ni], acc[mi][ni], 0, 0, 0);
        }
        __syncthreads();
    }
    #pragma unroll
    for (int mi = 0; mi < 4; ++mi) {
        #pragma unroll
        for (int r = 0; r < 4; ++r) {
            int m = m0 + wm * 64 + mi * 16 + 4 * g + r;
            if (m >= M) continue;
            #pragma unroll
            for (int ni = 0; ni < 4; ++ni) {
                int n = n0 + wn * 64 + ni * 16 + li;
                float v = acc[mi][ni][r];
                if (mode == 0) {
                    outF[(size_t)m * N + n] = v;
                } else if (mode == 1) {
                    v += bias[n] + res[(size_t)m * N + n];
                    outF[(size_t)m * N + n] = v;
                } else if (mode == 2) {
                    v += bias[n];
                    v = 0.5f * v * (1.0f + erff(v * 0.70710678118f));
                    outB[(size_t)m * N + n] = bf16rnd(v);
                } else {
                    outB[(size_t)m * N + n] = bf16rnd(v);
                }
            }
        }
    }
}

// ---------------- remap (bf16 inputs) -> qn/ksum/vn (new space) + colb ----------------
__global__ __launch_bounds__(512) void remap_kernel(
    const ushort* __restrict__ qkvb, const ushort* __restrict__ ktcb,
    const float* __restrict__ bte, const float* __restrict__ btr,
    const float* __restrict__ bcr, const float* __restrict__ bce,
    ushort* __restrict__ qn, ushort* __restrict__ ksum, ushort* __restrict__ vn,
    float* __restrict__ colb)
{
    int id = blockIdx.x;            // b2*NTOK + i2
    int b2 = id / NTOK, i2 = id - b2 * NTOK;
    int t = threadIdx.x;
    int h2 = t >> 6, d2 = t & 63;
    int G = i2 * 16 + b2 * 8 + h2;
    int bhA = G / 2049, iA = G - bhA * 2049;
    int bA = bhA >> 3, hA = bhA & 7;
    size_t qbase = ((size_t)(bA * NTOK + iA)) * 1536 + hA * 64 + d2;
    ushort qv = qkvb[qbase], kvu = qkvb[qbase + 512], vvu = qkvb[qbase + 1024];
    int bB = G / 16392, remB = G - bB * 16392;
    int iB = remB >> 3, hB = remB & 7;
    ushort ktcu = ktcb[((size_t)(bB * NTOK + iB)) * 512 + hB * 64 + d2];
    float kv = bf16tof(kvu), ktcv = bf16tof(ktcu);
    size_t ob = (size_t)id * 512 + t;
    qn[ob] = qv;
    ksum[ob] = bf16rnd(kv + ktcv);
    vn[ob] = vvu;
    float cbx = (bte[t] + bce[t]) * kv + (btr[t] + bcr[t]) * ktcv;
    cbx = wave_allreduce_sum(cbx);
    if (d2 == 0) colb[(size_t)id * 8 + h2] = cbx;
}

// ---------------- transpose V: vn[b][j][d] -> vt[b][d][j 2080] ----------------
__global__ __launch_bounds__(256) void vtrans_kernel(
    const ushort* __restrict__ vn, ushort* __restrict__ vt)
{
    __shared__ ushort tile[32][36];
    int jt = blockIdx.x, dt = blockIdx.y, b = blockIdx.z;
    int t = threadIdx.x;
    {
        int jj = t >> 3, dq = t & 7;
        int j = jt * 32 + jj; if (j > 2048) j = 2048;
        const ushort* src = vn + ((size_t)(b * NTOK + j)) * 512 + dt * 32 + dq * 4;
        *(ushort4*)&tile[jj][dq * 4] = *(const ushort4*)src;
    }
    __syncthreads();
    {
        int dd = t >> 3, jq = t & 7;
        ushort4 w;
        w.x = tile[jq * 4 + 0][dd];
        w.y = tile[jq * 4 + 1][dd];
        w.z = tile[jq * 4 + 2][dd];
        w.w = tile[jq * 4 + 3][dd];
        *(ushort4*)(vt + ((size_t)b * 512 + dt * 32 + dd) * 2080 + jt * 32 + jq * 4) = w;
    }
}

// ---------------- fused MFMA attention, spill-free + pipelined ----------------
// grid (65, NCJ=3, 2); 4 waves: wi = i-subtile, ws = j-half (QK) / head-half (PV).
// LDS: K dbuf 2x32KB @0 | att 16KB @65536 = 80KB -> 2 blocks/CU; VGPR cap 256 (no spill).
__global__ __launch_bounds__(256, 2) void attn4_kernel(
    const ushort* __restrict__ qn, const ushort* __restrict__ ks,
    const ushort* __restrict__ vt, const float* __restrict__ colb,
    ushort* __restrict__ Op)
{
    __shared__ __align__(16) char smem[81920];
    const int tid = threadIdx.x;
    const int lane = tid & 63;
    const int wave = tid >> 6;
    const int wi = wave >> 1, ws = wave & 1;
    const int g = lane >> 4, li = lane & 15;
    const int nc = blockIdx.y, b = blockIdx.z;
    const int jt0 = (nc * 65) / NCJ, jt1 = ((nc + 1) * 65) / NCJ;
    const int jcol = li + 16 * ws;

    // Q fragments in registers (k-slot map d = h*64 + k2*32 + 8g + e)
    bf16x8 qf[8][2];
    {
        int iq = blockIdx.x * 32 + wi * 16 + li; if (iq > 2048) iq = 2048;
        const ushort* qrow = qn + ((size_t)(b * NTOK + iq)) * 512;
        #pragma unroll
        for (int h = 0; h < 8; ++h)
            #pragma unroll
            for (int k2 = 0; k2 < 2; ++k2)
                qf[h][k2] = *(const bf16x8*)(qrow + h * 64 + k2 * 32 + 8 * g);
    }
    f32x4 o[4][4];
    #pragma unroll
    for (int a = 0; a < 4; ++a)
        #pragma unroll
        for (int m = 0; m < 4; ++m) o[a][m] = (f32x4){0.f, 0.f, 0.f, 0.f};

    // prologue: stage K(jt0) into buffer 0
    {
        int j0 = jt0 * 32;
        #pragma unroll
        for (int t = 0; t < 8; ++t) {
            int n = tid + t * 256;
            int j = n & 31, db = n >> 5;
            int jg = j0 + j; if (jg > 2048) jg = 2048;
            int4 v = *(const int4*)(ks + ((size_t)(b * NTOK + jg)) * 512 + db * 8);
            unsigned L = (unsigned)n * 16u;
            *(int4*)(smem + (L ^ ((L >> 1) & 0x40u))) = v;
        }
    }
    __syncthreads();
    unsigned curbase = 0;

    for (int jt = jt0; jt < jt1; ++jt) {
        const int j0 = jt * 32;
        const bool hasNext = (jt + 1 < jt1);
        // colb for this tile's column (consumed in softmax)
        float cbv[8];
        {
            int jg = j0 + jcol;
            int jc = jg > 2048 ? 2048 : jg;
            const float* cp = colb + ((size_t)(b * NTOK + jc)) * 8;
            float4 c0 = *(const float4*)cp;
            float4 c1 = *(const float4*)(cp + 4);
            cbv[0] = c0.x; cbv[1] = c0.y; cbv[2] = c0.z; cbv[3] = c0.w;
            cbv[4] = c1.x; cbv[5] = c1.y; cbv[6] = c1.z; cbv[7] = c1.w;
            #pragma unroll
            for (int h = 0; h < 8; ++h) cbv[h] = (jg > 2048) ? -1e30f : cbv[h] * 0.125f;
        }
        // issue next K tile loads (written to LDS at end of compute)
        int4 kreg[8];
        if (hasNext) {
            int j0n = j0 + 32;
            #pragma unroll
            for (int t = 0; t < 8; ++t) {
                int n = tid + t * 256;
                int j = n & 31, db = n >> 5;
                int jg = j0n + j; if (jg > 2048) jg = 2048;
                kreg[t] = *(const int4*)(ks + ((size_t)(b * NTOK + jg)) * 512 + db * 8);
            }
        }
        // QK: all 8 heads, this wave's j-half
        f32x4 s[8];
        const char* kb = smem + curbase;
        #pragma unroll
        for (int h = 0; h < 8; ++h) {
            s[h] = (f32x4){0.f, 0.f, 0.f, 0.f};
            #pragma unroll
            for (int k2 = 0; k2 < 2; ++k2) {
                unsigned db = (unsigned)(h * 8 + k2 * 4 + g);
                unsigned L = (db * 32 + (unsigned)jcol) * 16u;
                bf16x8 kf = *(const bf16x8*)(kb + (L ^ ((L >> 1) & 0x40u)));
                s[h] = __builtin_amdgcn_mfma_f32_16x16x32_bf16(qf[h][k2], kf, s[h], 0, 0, 0);
            }
        }
        // softmax over heads (in-lane) -> att LDS (swizzled)
        #pragma unroll
        for (int r = 0; r < 4; ++r) {
            float p[8]; float sum = 0.f;
            #pragma unroll
            for (int h = 0; h < 8; ++h) {
                p[h] = __expf(s[h][r] * 0.125f + cbv[h]);
                sum += p[h];
            }
            float inv = __builtin_amdgcn_rcpf(fmaxf(sum, 1e-20f));  // NORMAL floor (denorm rcp -> inf)
            #pragma unroll
            for (int h = 0; h < 8; ++h) {
                ushort ab = bf16rnd(p[h] * inv);
                unsigned L = ((unsigned)((wi * 8 + h) * 16 + 4 * g + r)) * 64u + (unsigned)jcol * 2u;
                *(ushort*)(smem + 65536 + (L ^ ((L >> 3) & 0x70u))) = ab;
            }
        }
        // V preload for first PV head-pair (hidden under att writes + barrier)
        bf16x8 vA[4];
        {
            const ushort* vrow = vt + ((size_t)b * 512 + (ws * 4) * 64 + li) * 2080 + j0 + 8 * g;
            #pragma unroll
            for (int m = 0; m < 4; ++m) vA[m] = *(const bf16x8*)(vrow + (size_t)m * 16 * 2080);
        }
        // write prefetched K tile to other buffer
        if (hasNext) {
            char* kn = smem + (curbase ^ 32768u);
            #pragma unroll
            for (int t = 0; t < 8; ++t) {
                unsigned L = (unsigned)(tid + t * 256) * 16u;
                *(int4*)(kn + (L ^ ((L >> 1) & 0x40u))) = kreg[t];
            }
        }
        __syncthreads();   // A: att + next-K visible
        // PV: heads ws*4..+3, V JIT-pipelined one head ahead
        #pragma unroll
        for (int hh = 0; hh < 4; ++hh) {
            bf16x8 vB[4];
            if (hh < 3) {
                const ushort* vrow = vt + ((size_t)b * 512 + (ws * 4 + hh + 1) * 64 + li) * 2080 + j0 + 8 * g;
                #pragma unroll
                for (int m = 0; m < 4; ++m) vB[m] = *(const bf16x8*)(vrow + (size_t)m * 16 * 2080);
            }
            unsigned Lr = ((unsigned)((wi * 8 + ws * 4 + hh) * 16 + li)) * 64u + 16u * (unsigned)g;
            bf16x8 af = *(const bf16x8*)(smem + 65536 + (Lr ^ ((Lr >> 3) & 0x70u)));
            #pragma unroll
            for (int m = 0; m < 4; ++m)
                o[hh][m] = __builtin_amdgcn_mfma_f32_16x16x32_bf16(af, vA[m], o[hh][m], 0, 0, 0);
            if (hh < 3) {
                #pragma unroll
                for (int m = 0; m < 4; ++m) vA[m] = vB[m];
            }
        }
        __syncthreads();   // B: att reads done; safe to overwrite next iter
        curbase ^= 32768u;
    }
    // store partial O (bf16)
    {
        int irow0 = blockIdx.x * 32 + wi * 16 + 4 * g;
        #pragma unroll
        for (int hh = 0; hh < 4; ++hh) {
            int d0 = (ws * 4 + hh) * 64;
            #pragma unroll
            for (int m = 0; m < 4; ++m) {
                #pragma unroll
                for (int r = 0; r < 4; ++r) {
                    int irow = irow0 + r;
                    if (irow <= 2048) {
                        Op[(((size_t)(nc * 2 + b)) * 2049 + irow) * 512 + d0 + m * 16 + li] =
                            bf16rnd(o[hh][m][r]);
                    }
                }
            }
        }
    }
}

// ---------------- sum NCJ bf16 partials -> bf16 attno ----------------
__global__ __launch_bounds__(256) void osum_kernel(
    const ushort* __restrict__ Op, ushort* __restrict__ attno)
{
    int idx = blockIdx.x * 256 + threadIdx.x;
    if (idx >= MROWS * 64) return;
    int row = idx >> 6, dq = idx & 63;
    int b = row / NTOK, i = row - b * NTOK;
    float acc[8];
    #pragma unroll
    for (int e = 0; e < 8; ++e) acc[e] = 0.f;
    #pragma unroll
    for (int nc = 0; nc < NCJ; ++nc) {
        const ushort* src = Op + (((size_t)(nc * 2 + b)) * 2049 + i) * 512 + dq * 8;
        int4 v = *(const int4*)src;
        const ushort* up = (const ushort*)&v;
        #pragma unroll
        for (int e = 0; e < 8; ++e) acc[e] += bf16tof(up[e]);
    }
    ushort ov[8];
    #pragma unroll
    for (int e = 0; e < 8; ++e) ov[e] = bf16rnd(acc[e]);
    *(int4*)(attno + (size_t)row * 512 + dq * 8) = *(int4*)ov;
}

// ---------------- head ----------------
__global__ void head_kernel(
    const float* __restrict__ x, const float* __restrict__ g, const float* __restrict__ b,
    const float* __restrict__ w, const float* __restrict__ hb, float* __restrict__ out)
{
    int lane = threadIdx.x & 63;
    for (int bi = 0; bi < 2; ++bi) {
        const float* xr = x + (size_t)bi * NTOK * 128;
        float v0 = xr[lane], v1 = xr[lane + 64];
        float mean = wave_allreduce_sum(v0 + v1) * (1.0f / 128.0f);
        float d0 = v0 - mean, d1 = v1 - mean;
        float var = wave_allreduce_sum(d0 * d0 + d1 * d1) * (1.0f / 128.0f);
        float inv = rsqrtf(var + 1e-5f);
        float y0 = d0 * inv * g[lane] + b[lane];
        float y1 = d1 * inv * g[lane + 64] + b[lane + 64];
        for (int c = 0; c < 4; ++c) {
            float pt = y0 * w[lane * 4 + c] + y1 * w[(lane + 64) * 4 + c];
            pt = wave_allreduce_sum(pt);
            if (lane == 0) out[bi * 4 + c] = pt + hb[c];
        }
    }
}

extern "C" void kernel_launch(void* const* d_in, const int* in_sizes, int n_in,
                              void* d_out, int out_size, void* d_ws, size_t ws_size,
                              hipStream_t stream) {
    const float* eeg   = (const float*)d_in[0];
    const float* est   = (const float*)d_in[1];
    const int*   cvi   = (const int*)d_in[2];
    const float* convw = (const float*)d_in[3];
    const float* convb = (const float*)d_in[4];
    const float* cls   = (const float*)d_in[5];
    const float* clsp  = (const float*)d_in[6];
    const float* bte   = (const float*)d_in[7];
    const float* btr   = (const float*)d_in[8];
    const float* bcr   = (const float*)d_in[9];
    const float* bce   = (const float*)d_in[10];
    const float* ln1g  = (const float*)d_in[11];
    const float* ln1b  = (const float*)d_in[12];
    const float* wqkv  = (const float*)d_in[13];
    const float* wkt   = (const float*)d_in[14];
    const float* wkc   = (const float*)d_in[15];
    const float* wo    = (const float*)d_in[16];
    const float* bo    = (const float*)d_in[17];
    const float* ln2g  = (const float*)d_in[18];
    const float* ln2b  = (const float*)d_in[19];
    const float* w1    = (const float*)d_in[20];
    const float* b1    = (const float*)d_in[21];
    const float* w2    = (const float*)d_in[22];
    const float* b2    = (const float*)d_in[23];
    const float* hlng  = (const float*)d_in[24];
    const float* hlnb  = (const float*)d_in[25];
    const float* hw    = (const float*)d_in[26];
    const float* hb    = (const float*)d_in[27];

    float* ws    = (float*)d_ws;
    float* x_    = ws + OFF_X;
    ushort* xnb  = (ushort*)(ws + OFF_XNB);
    ushort* rtb  = (ushort*)(ws + OFF_RTB);
    ushort* rcb  = (ushort*)(ws + OFF_RCB);
    ushort* qkvb = (ushort*)(ws + OFF_QKVB);
    ushort* ktcb = (ushort*)(ws + OFF_KTCB);
    ushort* qnb  = (ushort*)(ws + OFF_QNB);
    ushort* ksb  = (ushort*)(ws + OFF_KSB);
    ushort* vnb  = (ushort*)(ws + OFF_VNB);
    ushort* vtb  = (ushort*)(ws + OFF_VTB);
    float* colb_ = ws + OFF_COLB;
    ushort* wT   = (ushort*)(ws + OFF_WT);
    ushort* opb  = (ushort*)(ws + OFF_OP);
    ushort* attnob = (ushort*)(ws + OFF_ATTNO);
    ushort* ffnhb  = (ushort*)(ws + OFF_FFNH);

    wprep_kernel<<<dim3(768, 5, 2), 256, 0, stream>>>(wqkv, wkt, wkc, wo, w1, w2, wT);
    embed_kernel<<<4098, 128, 0, stream>>>(eeg, est, cvi, convw, convb, cls, clsp, x_, rtb, rcb);

    for (int l = 0; l < 2; ++l) {
        const ushort* wTl = wT + (size_t)l * 524288;
        ln_kernel<<<1025, 256, 0, stream>>>(x_, ln1g + l * 128, ln1b + l * 128, xnb, MROWS);
        mgemm_kernel<<<dim3(12, 33), 256, 0, stream>>>(xnb, xnb, 128, wTl,
                                                       nullptr, qkvb, nullptr, nullptr,
                                                       MROWS, 128, 1536, 3);
        mgemm_kernel<<<dim3(4, 33), 256, 0, stream>>>(rtb, rcb, 128, wTl + 196608,
                                                      nullptr, ktcb, nullptr, nullptr,
                                                      MROWS, 256, 512, 3);
        remap_kernel<<<MROWS, 512, 0, stream>>>(qkvb, ktcb, bte, btr, bcr, bce,
                                                qnb, ksb, vnb, colb_);
        vtrans_kernel<<<dim3(65, 16, 2), 256, 0, stream>>>(vnb, vtb);
        attn4_kernel<<<dim3(65, NCJ, 2), 256, 0, stream>>>(qnb, ksb, vtb, colb_, opb);
        osum_kernel<<<1025, 256, 0, stream>>>(opb, attnob);
        mgemm_kernel<<<dim3(1, 33), 256, 0, stream>>>(attnob, attnob, 512, wTl + 327680,
                                                      x_, nullptr, bo + l * 128, x_,
                                                      MROWS, 512, 128, 1);
        ln_kernel<<<1025, 256, 0, stream>>>(x_, ln2g + l * 128, ln2b + l * 128, xnb, MROWS);
        mgemm_kernel<<<dim3(4, 33), 256, 0, stream>>>(xnb, xnb, 128, wTl + 393216,
                                                      nullptr, ffnhb, b1 + l * 512, nullptr,
                                                      MROWS, 128, 512, 2);
        mgemm_kernel<<<dim3(1, 33), 256, 0, stream>>>(ffnhb, ffnhb, 512, wTl + 458752,
                                                      x_, nullptr, b2 + l * 128, x_,
                                                      MROWS, 512, 128, 1);
    }
    head_kernel<<<1, 64, 0, stream>>>(x_, hlng, hlnb, hw, hb, (float*)d_out);
}

// Round 6
// 565.312 us; speedup vs baseline: 6.4257x; 1.1266x over previous
//
#include <hip/hip_runtime.h>

#define CH    64
#define NTOK  2049
#define MROWS 4098
#define NCJ   4

typedef __attribute__((ext_vector_type(8))) short bf16x8;
typedef __attribute__((ext_vector_type(4))) float f32x4;

// workspace offsets (float units) — sequential, no overlays
#define OFF_X     0u
#define OFF_XNB   524544u
#define OFF_RTB   786816u
#define OFF_RCB   1049088u
#define OFF_QKVB  1311360u
#define OFF_KTCB  4458624u
#define OFF_QNB   5507712u
#define OFF_KSB   6556800u
#define OFF_VNB   7605888u
#define OFF_VTB   8654976u
#define OFF_COLB  9719936u
#define OFF_WT    9752720u
#define OFF_OP    10277008u
#define OFF_ATTNO 14473360u
#define OFF_FFNH  15522448u

#define GLOAD_LDS16(gp, lp) __builtin_amdgcn_global_load_lds( \
    (const __attribute__((address_space(1))) void*)(gp), \
    (__attribute__((address_space(3))) void*)(lp), 16, 0, 0)

__device__ __forceinline__ float wave_allreduce_sum(float v) {
    #pragma unroll
    for (int m = 1; m < 64; m <<= 1) v += __shfl_xor(v, m);
    return v;
}

__device__ __forceinline__ ushort bf16rnd(float x) {
    unsigned u = __builtin_bit_cast(unsigned, x);
    u += 0x7FFF + ((u >> 16) & 1);
    return (ushort)(u >> 16);
}

__device__ __forceinline__ float bf16tof(ushort u) {
    return __builtin_bit_cast(float, ((unsigned)u) << 16);
}

// ---------------- weight prep: f32 [K][N] -> bf16 Wt [N][K] (ktc concatenated) ----------------
__global__ __launch_bounds__(256) void wprep_kernel(
    const float* __restrict__ wqkv, const float* __restrict__ wkt, const float* __restrict__ wkc,
    const float* __restrict__ wo, const float* __restrict__ w1, const float* __restrict__ w2,
    ushort* __restrict__ wT)
{
    int l = blockIdx.z, mat = blockIdx.y;
    int idx = blockIdx.x * 256 + threadIdx.x;
    float v; int off;
    if (mat == 0) {            // qkv: N=1536 K=128
        if (idx >= 196608) return;
        int n = idx >> 7, k = idx & 127;
        v = wqkv[(size_t)l * 196608 + (size_t)k * 1536 + n]; off = 0;
    } else if (mat == 1) {     // ktc: N=512 K=256 (wkt | wkc)
        if (idx >= 131072) return;
        int n = idx >> 8, k = idx & 255;
        v = (k < 128) ? wkt[(size_t)l * 65536 + (size_t)k * 512 + n]
                      : wkc[(size_t)l * 65536 + (size_t)(k - 128) * 512 + n];
        off = 196608;
    } else if (mat == 2) {     // wo: N=128 K=512
        if (idx >= 65536) return;
        int n = idx >> 9, k = idx & 511;
        v = wo[(size_t)l * 65536 + (size_t)k * 128 + n]; off = 327680;
    } else if (mat == 3) {     // w1: N=512 K=128
        if (idx >= 65536) return;
        int n = idx >> 7, k = idx & 127;
        v = w1[(size_t)l * 65536 + (size_t)k * 512 + n]; off = 393216;
    } else {                   // w2: N=128 K=512
        if (idx >= 65536) return;
        int n = idx >> 9, k = idx & 511;
        v = w2[(size_t)l * 65536 + (size_t)k * 128 + n]; off = 458752;
    }
    wT[(size_t)l * 524288 + off + idx] = bf16rnd(v);
}

// ---------------- embed ----------------
__global__ __launch_bounds__(128) void embed_kernel(
    const float* __restrict__ eeg, const float* __restrict__ est, const int* __restrict__ cvi,
    const float* __restrict__ cw, const float* __restrict__ cb,
    const float* __restrict__ cls, const float* __restrict__ clsp,
    float* __restrict__ x, ushort* __restrict__ rt, ushort* __restrict__ rc)
{
    int id = blockIdx.x;
    int d = threadIdx.x;
    if (id >= 4096) {
        int b = id - 4096;
        size_t base = (size_t)b * NTOK * 128 + d;
        x[base]  = cls[d];
        rt[base] = bf16rnd(clsp[d]);
        rc[base] = bf16rnd(clsp[d]);
        return;
    }
    int b = id >> 11, rem = id & 2047, c = rem >> 5, w = rem & 31;
    __shared__ float xs[25];
    if (d < 25) xs[d] = eeg[((size_t)(b * CH + c)) * 800 + w * 25 + d];
    __syncthreads();
    float acc = cb[d];
    #pragma unroll
    for (int p = 0; p < 25; ++p) acc += xs[p] * cw[d * 25 + p];
    int i = 1 + c * 32 + w;
    size_t base = ((size_t)b * NTOK + i) * 128 + d;
    x[base] = acc;
    int k = d & 63;
    float invk = __expf(-0.14391156831f * (float)k);
    float pt = floorf(est[b] / 0.1f) + (float)w;
    float at = pt * invk;
    rt[base] = bf16rnd((d < 64) ? sinf(at) : cosf(at));
    float pc = (float)cvi[b * CH + c];
    float ac = pc * invk;
    rc[base] = bf16rnd((d < 64) ? sinf(ac) : cosf(ac));
}

// ---------------- layernorm, bf16 out ----------------
__global__ __launch_bounds__(256) void ln_kernel(
    const float* __restrict__ x, const float* __restrict__ g, const float* __restrict__ bb,
    ushort* __restrict__ out, int rows)
{
    int w = threadIdx.x >> 6, lane = threadIdx.x & 63;
    int row = blockIdx.x * 4 + w;
    if (row >= rows) return;
    const float* xr = x + (size_t)row * 128;
    float v0 = xr[lane], v1 = xr[lane + 64];
    float mean = wave_allreduce_sum(v0 + v1) * (1.0f / 128.0f);
    float d0 = v0 - mean, d1 = v1 - mean;
    float var = wave_allreduce_sum(d0 * d0 + d1 * d1) * (1.0f / 128.0f);
    float inv = rsqrtf(var + 1e-5f);
    out[(size_t)row * 128 + lane]      = bf16rnd(d0 * inv * g[lane]      + bb[lane]);
    out[(size_t)row * 128 + lane + 64] = bf16rnd(d1 * inv * g[lane + 64] + bb[lane + 64]);
}

// ---------------- bf16 MFMA GEMM: C = A[MxK] * Wt[NxK]; A may be [A | A2] concat on K ----------------
// mode: 2 -> outB = bf16(gelu(acc+bias)); 3 -> outB = bf16(acc)
__global__ __launch_bounds__(256, 3) void mgemm_kernel(
    const ushort* __restrict__ A, const ushort* __restrict__ A2, int K1,
    const ushort* __restrict__ Wt,
    float* outF, ushort* outB, const float* bias, const float* res,
    int M, int K, int N, int mode)
{
    __shared__ ushort Alds[128 * 72];
    __shared__ ushort Blds[128 * 72];
    int tid = threadIdx.x;
    int lane = tid & 63, wv = tid >> 6;
    int wm = wv >> 1, wn = wv & 1;
    int li = lane & 15, g = lane >> 4;
    int m0 = blockIdx.y * 128, n0 = blockIdx.x * 128;
    int K2s = K - K1;
    f32x4 acc[4][4];
    #pragma unroll
    for (int a = 0; a < 4; ++a)
        #pragma unroll
        for (int c = 0; c < 4; ++c) acc[a][c] = (f32x4){0.f, 0.f, 0.f, 0.f};

    for (int kb = 0; kb < K; kb += 64) {
        #pragma unroll
        for (int it = 0; it < 4; ++it) {
            int gi = tid + it * 256;
            int row = gi >> 3, gc = gi & 7;
            int m = m0 + row; if (m >= M) m = M - 1;
            int acol = kb + gc * 8;
            const ushort* asrc = (acol < K1) ? (A + (size_t)m * K1 + acol)
                                             : (A2 + (size_t)m * K2s + (acol - K1));
            bf16x8 av = *(const bf16x8*)asrc;
            *(bf16x8*)&Alds[row * 72 + ((gc ^ (row & 7)) << 3)] = av;
            int n = n0 + row;
            bf16x8 bv = *(const bf16x8*)(Wt + (size_t)n * K + acol);
            *(bf16x8*)&Blds[row * 72 + ((gc ^ (row & 7)) << 3)] = bv;
        }
        __syncthreads();
        #pragma unroll
        for (int k2 = 0; k2 < 2; ++k2) {
            bf16x8 af[4], bfr[4];
            #pragma unroll
            for (int xx = 0; xx < 4; ++xx) {
                int ra = wm * 64 + xx * 16 + li;
                int rb = wn * 64 + xx * 16 + li;
                af[xx]  = *(const bf16x8*)&Alds[ra * 72 + (((k2 * 4 + g) ^ (ra & 7)) << 3)];
                bfr[xx] = *(const bf16x8*)&Blds[rb * 72 + (((k2 * 4 + g) ^ (rb & 7)) << 3)];
            }
            #pragma unroll
            for (int mi = 0; mi < 4; ++mi)
                #pragma unroll
                for (int ni = 0; ni < 4; ++ni)
                    acc[mi][ni] = __builtin_amdgcn_mfma_f32_16x16x32_bf16(af[mi], bfr[ni], acc[mi][ni], 0, 0, 0);
        }
        __syncthreads();
    }
    #pragma unroll
    for (int mi = 0; mi < 4; ++mi) {
        #pragma unroll
        for (int r = 0; r < 4; ++r) {
            int m = m0 + wm * 64 + mi * 16 + 4 * g + r;
            if (m >= M) continue;
            #pragma unroll
            for (int ni = 0; ni < 4; ++ni) {
                int n = n0 + wn * 64 + ni * 16 + li;
                float v = acc[mi][ni][r];
                if (mode == 2) {
                    v += bias[n];
                    v = 0.5f * v * (1.0f + erff(v * 0.70710678118f));
                    outB[(size_t)m * N + n] = bf16rnd(v);
                } else {
                    outB[(size_t)m * N + n] = bf16rnd(v);
                }
            }
        }
    }
}

// ---------------- thin GEMM (N=128, K=512): one 16x16 tile per wave, no LDS ----------------
// out = acc + bias + res (f32, in-place-safe per element)
__global__ __launch_bounds__(256) void tgemm_kernel(
    const ushort* __restrict__ A, const ushort* __restrict__ Wt,
    float* __restrict__ outF, const float* __restrict__ bias, const float* __restrict__ res,
    int M, int N)
{
    int lane = threadIdx.x & 63, wv = threadIdx.x >> 6;
    int li = lane & 15, g = lane >> 4;
    int mt = blockIdx.y * 4 + wv;
    int m0 = mt * 16, n0 = blockIdx.x * 16;
    int ar = m0 + li; if (ar >= M) ar = M - 1;
    const ushort* arow = A + (size_t)ar * 512 + 8 * g;
    const ushort* brow = Wt + (size_t)(n0 + li) * 512 + 8 * g;
    f32x4 acc = (f32x4){0.f, 0.f, 0.f, 0.f};
    #pragma unroll
    for (int k2 = 0; k2 < 16; ++k2) {
        bf16x8 af = *(const bf16x8*)(arow + k2 * 32);
        bf16x8 bf = *(const bf16x8*)(brow + k2 * 32);
        acc = __builtin_amdgcn_mfma_f32_16x16x32_bf16(af, bf, acc, 0, 0, 0);
    }
    #pragma unroll
    for (int r = 0; r < 4; ++r) {
        int m = m0 + 4 * g + r;
        if (m < M) {
            int n = n0 + li;
            outF[(size_t)m * N + n] = acc[r] + bias[n] + res[(size_t)m * N + n];
        }
    }
}

// ---------------- remap (bf16 inputs) -> qn/ksum/vn (new space) + colb ----------------
__global__ __launch_bounds__(512) void remap_kernel(
    const ushort* __restrict__ qkvb, const ushort* __restrict__ ktcb,
    const float* __restrict__ bte, const float* __restrict__ btr,
    const float* __restrict__ bcr, const float* __restrict__ bce,
    ushort* __restrict__ qn, ushort* __restrict__ ksum, ushort* __restrict__ vn,
    float* __restrict__ colb)
{
    int id = blockIdx.x;            // b2*NTOK + i2
    int b2 = id / NTOK, i2 = id - b2 * NTOK;
    int t = threadIdx.x;
    int h2 = t >> 6, d2 = t & 63;
    int G = i2 * 16 + b2 * 8 + h2;
    int bhA = G / 2049, iA = G - bhA * 2049;
    int bA = bhA >> 3, hA = bhA & 7;
    size_t qbase = ((size_t)(bA * NTOK + iA)) * 1536 + hA * 64 + d2;
    ushort qv = qkvb[qbase], kvu = qkvb[qbase + 512], vvu = qkvb[qbase + 1024];
    int bB = G / 16392, remB = G - bB * 16392;
    int iB = remB >> 3, hB = remB & 7;
    ushort ktcu = ktcb[((size_t)(bB * NTOK + iB)) * 512 + hB * 64 + d2];
    float kv = bf16tof(kvu), ktcv = bf16tof(ktcu);
    size_t ob = (size_t)id * 512 + t;
    qn[ob] = qv;
    ksum[ob] = bf16rnd(kv + ktcv);
    vn[ob] = vvu;
    float cbx = (bte[t] + bce[t]) * kv + (btr[t] + bcr[t]) * ktcv;
    cbx = wave_allreduce_sum(cbx);
    if (d2 == 0) colb[(size_t)id * 8 + h2] = cbx;
}

// ---------------- transpose V: vn[b][j][d] -> vt[b][d][j 2080] ----------------
__global__ __launch_bounds__(256) void vtrans_kernel(
    const ushort* __restrict__ vn, ushort* __restrict__ vt)
{
    __shared__ ushort tile[32][36];
    int jt = blockIdx.x, dt = blockIdx.y, b = blockIdx.z;
    int t = threadIdx.x;
    {
        int jj = t >> 3, dq = t & 7;
        int j = jt * 32 + jj; if (j > 2048) j = 2048;
        const ushort* src = vn + ((size_t)(b * NTOK + j)) * 512 + dt * 32 + dq * 4;
        *(ushort4*)&tile[jj][dq * 4] = *(const ushort4*)src;
    }
    __syncthreads();
    {
        int dd = t >> 3, jq = t & 7;
        ushort4 w;
        w.x = tile[jq * 4 + 0][dd];
        w.y = tile[jq * 4 + 1][dd];
        w.z = tile[jq * 4 + 2][dd];
        w.w = tile[jq * 4 + 3][dd];
        *(ushort4*)(vt + ((size_t)b * 512 + dt * 32 + dd) * 2080 + jt * 32 + jq * 4) = w;
    }
}

// ---------------- fused MFMA attention, spill-free via global_load_lds K staging ----------------
// grid (65, NCJ=4, 2); 4 waves: wi = i-subtile, ws = j-half (QK) / head-half (PV).
// LDS: K dbuf 2x32KB linear [db 64][j 32] @0 | att 16KB @65536 = 80KB -> 2 blocks/CU.
// No reg prefetch (was the round-5 spill): K staged by async global_load_lds, drained by barrier.
__global__ __launch_bounds__(256) void attn5_kernel(
    const ushort* __restrict__ qn, const ushort* __restrict__ ks,
    const ushort* __restrict__ vt, const float* __restrict__ colb,
    ushort* __restrict__ Op)
{
    __shared__ __align__(16) char smem[81920];
    const int tid = threadIdx.x;
    const int lane = tid & 63;
    const int wave = tid >> 6;
    const int wi = wave >> 1, ws = wave & 1;
    const int g = lane >> 4, li = lane & 15;
    const int nc = blockIdx.y, b = blockIdx.z;
    const int jt0 = (nc * 65) / NCJ, jt1 = ((nc + 1) * 65) / NCJ;
    const int jcol = li + 16 * ws;

    // Q fragments in registers (k-slot map d = h*64 + k2*32 + 8g + e)
    bf16x8 qf[8][2];
    {
        int iq = blockIdx.x * 32 + wi * 16 + li; if (iq > 2048) iq = 2048;
        const ushort* qrow = qn + ((size_t)(b * NTOK + iq)) * 512;
        #pragma unroll
        for (int h = 0; h < 8; ++h)
            #pragma unroll
            for (int k2 = 0; k2 < 2; ++k2)
                qf[h][k2] = *(const bf16x8*)(qrow + h * 64 + k2 * 32 + 8 * g);
    }
    f32x4 o[4][4];
    #pragma unroll
    for (int a = 0; a < 4; ++a)
        #pragma unroll
        for (int m = 0; m < 4; ++m) o[a][m] = (f32x4){0.f, 0.f, 0.f, 0.f};

    // async K staging: wave w covers LDS slots [w*512, w*512+512) (16B units), 8 instrs
    // slot n -> (db = n>>5, j = n&31); lane contributes n = w*512 + t*64 + lane
    auto stage = [&](int jt, unsigned base) {
        int j = lane & 31;
        int jg = jt * 32 + j; if (jg > 2048) jg = 2048;
        const ushort* gsrc = ks + ((size_t)(b * NTOK + jg)) * 512 + (wave * 16 + (lane >> 5)) * 8;
        char* ldst = smem + base + wave * 8192;
        #pragma unroll
        for (int t = 0; t < 8; ++t)
            GLOAD_LDS16(gsrc + t * 16, ldst + t * 1024);
    };

    stage(jt0, 0);
    __syncthreads();   // drains global_load_lds (vmcnt 0)
    unsigned cur = 0;

    for (int jt = jt0; jt < jt1; ++jt) {
        const int j0 = jt * 32;
        const bool hasNext = (jt + 1 < jt1);
        if (hasNext) stage(jt + 1, cur ^ 32768u);   // async, lands by next barrier
        // colb for this tile's column
        float cbv[8];
        {
            int jg = j0 + jcol;
            int jc = jg > 2048 ? 2048 : jg;
            const float* cp = colb + ((size_t)(b * NTOK + jc)) * 8;
            float4 c0 = *(const float4*)cp;
            float4 c1 = *(const float4*)(cp + 4);
            cbv[0] = c0.x; cbv[1] = c0.y; cbv[2] = c0.z; cbv[3] = c0.w;
            cbv[4] = c1.x; cbv[5] = c1.y; cbv[6] = c1.z; cbv[7] = c1.w;
            #pragma unroll
            for (int h = 0; h < 8; ++h) cbv[h] = (jg > 2048) ? -1e30f : cbv[h] * 0.125f;
        }
        // QK: all 8 heads, this wave's j-half; K frags from linear LDS
        f32x4 s[8];
        const char* kb = smem + cur;
        #pragma unroll
        for (int h = 0; h < 8; ++h) {
            s[h] = (f32x4){0.f, 0.f, 0.f, 0.f};
            #pragma unroll
            for (int k2 = 0; k2 < 2; ++k2) {
                unsigned db = (unsigned)(h * 8 + k2 * 4 + g);
                bf16x8 kf = *(const bf16x8*)(kb + (size_t)(db * 32 + (unsigned)jcol) * 16);
                s[h] = __builtin_amdgcn_mfma_f32_16x16x32_bf16(qf[h][k2], kf, s[h], 0, 0, 0);
            }
        }
        // softmax over heads (in-lane) -> att LDS (swizzled)
        #pragma unroll
        for (int r = 0; r < 4; ++r) {
            float p[8]; float sum = 0.f;
            #pragma unroll
            for (int h = 0; h < 8; ++h) {
                p[h] = __expf(s[h][r] * 0.125f + cbv[h]);
                sum += p[h];
            }
            float inv = __builtin_amdgcn_rcpf(fmaxf(sum, 1e-20f));  // NORMAL floor (denorm rcp -> inf)
            #pragma unroll
            for (int h = 0; h < 8; ++h) {
                ushort ab = bf16rnd(p[h] * inv);
                unsigned L = ((unsigned)((wi * 8 + h) * 16 + 4 * g + r)) * 64u + (unsigned)jcol * 2u;
                *(ushort*)(smem + 65536 + (L ^ ((L >> 3) & 0x70u))) = ab;
            }
        }
        // V preload for first PV head (hidden under att writes + barrier)
        bf16x8 vA[4];
        {
            const ushort* vrow = vt + ((size_t)b * 512 + (ws * 4) * 64 + li) * 2080 + j0 + 8 * g;
            #pragma unroll
            for (int m = 0; m < 4; ++m) vA[m] = *(const bf16x8*)(vrow + (size_t)m * 16 * 2080);
        }
        __syncthreads();   // A: att visible; next K tile drained into other buffer
        // PV: heads ws*4..+3, V JIT-pipelined one head ahead
        #pragma unroll
        for (int hh = 0; hh < 4; ++hh) {
            bf16x8 vB[4];
            if (hh < 3) {
                const ushort* vrow = vt + ((size_t)b * 512 + (ws * 4 + hh + 1) * 64 + li) * 2080 + j0 + 8 * g;
                #pragma unroll
                for (int m = 0; m < 4; ++m) vB[m] = *(const bf16x8*)(vrow + (size_t)m * 16 * 2080);
            }
            unsigned Lr = ((unsigned)((wi * 8 + ws * 4 + hh) * 16 + li)) * 64u + 16u * (unsigned)g;
            bf16x8 af = *(const bf16x8*)(smem + 65536 + (Lr ^ ((Lr >> 3) & 0x70u)));
            #pragma unroll
            for (int m = 0; m < 4; ++m)
                o[hh][m] = __builtin_amdgcn_mfma_f32_16x16x32_bf16(af, vA[m], o[hh][m], 0, 0, 0);
            if (hh < 3) {
                #pragma unroll
                for (int m = 0; m < 4; ++m) vA[m] = vB[m];
            }
        }
        __syncthreads();   // B: att reads done before next overwrite
        cur ^= 32768u;
    }
    // store partial O (bf16)
    {
        int irow0 = blockIdx.x * 32 + wi * 16 + 4 * g;
        #pragma unroll
        for (int hh = 0; hh < 4; ++hh) {
            int d0 = (ws * 4 + hh) * 64;
            #pragma unroll
            for (int m = 0; m < 4; ++m) {
                #pragma unroll
                for (int r = 0; r < 4; ++r) {
                    int irow = irow0 + r;
                    if (irow <= 2048) {
                        Op[(((size_t)(nc * 2 + b)) * 2049 + irow) * 512 + d0 + m * 16 + li] =
                            bf16rnd(o[hh][m][r]);
                    }
                }
            }
        }
    }
}

// ---------------- sum NCJ bf16 partials -> bf16 attno ----------------
__global__ __launch_bounds__(256) void osum_kernel(
    const ushort* __restrict__ Op, ushort* __restrict__ attno)
{
    int idx = blockIdx.x * 256 + threadIdx.x;
    if (idx >= MROWS * 64) return;
    int row = idx >> 6, dq = idx & 63;
    int b = row / NTOK, i = row - b * NTOK;
    float acc[8];
    #pragma unroll
    for (int e = 0; e < 8; ++e) acc[e] = 0.f;
    #pragma unroll
    for (int nc = 0; nc < NCJ; ++nc) {
        const ushort* src = Op + (((size_t)(nc * 2 + b)) * 2049 + i) * 512 + dq * 8;
        int4 v = *(const int4*)src;
        const ushort* up = (const ushort*)&v;
        #pragma unroll
        for (int e = 0; e < 8; ++e) acc[e] += bf16tof(up[e]);
    }
    ushort ov[8];
    #pragma unroll
    for (int e = 0; e < 8; ++e) ov[e] = bf16rnd(acc[e]);
    *(int4*)(attno + (size_t)row * 512 + dq * 8) = *(int4*)ov;
}

// ---------------- head ----------------
__global__ void head_kernel(
    const float* __restrict__ x, const float* __restrict__ g, const float* __restrict__ b,
    const float* __restrict__ w, const float* __restrict__ hb, float* __restrict__ out)
{
    int lane = threadIdx.x & 63;
    for (int bi = 0; bi < 2; ++bi) {
        const float* xr = x + (size_t)bi * NTOK * 128;
        float v0 = xr[lane], v1 = xr[lane + 64];
        float mean = wave_allreduce_sum(v0 + v1) * (1.0f / 128.0f);
        float d0 = v0 - mean, d1 = v1 - mean;
        float var = wave_allreduce_sum(d0 * d0 + d1 * d1) * (1.0f / 128.0f);
        float inv = rsqrtf(var + 1e-5f);
        float y0 = d0 * inv * g[lane] + b[lane];
        float y1 = d1 * inv * g[lane + 64] + b[lane + 64];
        for (int c = 0; c < 4; ++c) {
            float pt = y0 * w[lane * 4 + c] + y1 * w[(lane + 64) * 4 + c];
            pt = wave_allreduce_sum(pt);
            if (lane == 0) out[bi * 4 + c] = pt + hb[c];
        }
    }
}

extern "C" void kernel_launch(void* const* d_in, const int* in_sizes, int n_in,
                              void* d_out, int out_size, void* d_ws, size_t ws_size,
                              hipStream_t stream) {
    const float* eeg   = (const float*)d_in[0];
    const float* est   = (const float*)d_in[1];
    const int*   cvi   = (const int*)d_in[2];
    const float* convw = (const float*)d_in[3];
    const float* convb = (const float*)d_in[4];
    const float* cls   = (const float*)d_in[5];
    const float* clsp  = (const float*)d_in[6];
    const float* bte   = (const float*)d_in[7];
    const float* btr   = (const float*)d_in[8];
    const float* bcr   = (const float*)d_in[9];
    const float* bce   = (const float*)d_in[10];
    const float* ln1g  = (const float*)d_in[11];
    const float* ln1b  = (const float*)d_in[12];
    const float* wqkv  = (const float*)d_in[13];
    const float* wkt   = (const float*)d_in[14];
    const float* wkc   = (const float*)d_in[15];
    const float* wo    = (const float*)d_in[16];
    const float* bo    = (const float*)d_in[17];
    const float* ln2g  = (const float*)d_in[18];
    const float* ln2b  = (const float*)d_in[19];
    const float* w1    = (const float*)d_in[20];
    const float* b1    = (const float*)d_in[21];
    const float* w2    = (const float*)d_in[22];
    const float* b2    = (const float*)d_in[23];
    const float* hlng  = (const float*)d_in[24];
    const float* hlnb  = (const float*)d_in[25];
    const float* hw    = (const float*)d_in[26];
    const float* hb    = (const float*)d_in[27];

    float* ws    = (float*)d_ws;
    float* x_    = ws + OFF_X;
    ushort* xnb  = (ushort*)(ws + OFF_XNB);
    ushort* rtb  = (ushort*)(ws + OFF_RTB);
    ushort* rcb  = (ushort*)(ws + OFF_RCB);
    ushort* qkvb = (ushort*)(ws + OFF_QKVB);
    ushort* ktcb = (ushort*)(ws + OFF_KTCB);
    ushort* qnb  = (ushort*)(ws + OFF_QNB);
    ushort* ksb  = (ushort*)(ws + OFF_KSB);
    ushort* vnb  = (ushort*)(ws + OFF_VNB);
    ushort* vtb  = (ushort*)(ws + OFF_VTB);
    float* colb_ = ws + OFF_COLB;
    ushort* wT   = (ushort*)(ws + OFF_WT);
    ushort* opb  = (ushort*)(ws + OFF_OP);
    ushort* attnob = (ushort*)(ws + OFF_ATTNO);
    ushort* ffnhb  = (ushort*)(ws + OFF_FFNH);

    wprep_kernel<<<dim3(768, 5, 2), 256, 0, stream>>>(wqkv, wkt, wkc, wo, w1, w2, wT);
    embed_kernel<<<4098, 128, 0, stream>>>(eeg, est, cvi, convw, convb, cls, clsp, x_, rtb, rcb);

    for (int l = 0; l < 2; ++l) {
        const ushort* wTl = wT + (size_t)l * 524288;
        ln_kernel<<<1025, 256, 0, stream>>>(x_, ln1g + l * 128, ln1b + l * 128, xnb, MROWS);
        mgemm_kernel<<<dim3(12, 33), 256, 0, stream>>>(xnb, xnb, 128, wTl,
                                                       nullptr, qkvb, nullptr, nullptr,
                                                       MROWS, 128, 1536, 3);
        mgemm_kernel<<<dim3(4, 33), 256, 0, stream>>>(rtb, rcb, 128, wTl + 196608,
                                                      nullptr, ktcb, nullptr, nullptr,
                                                      MROWS, 256, 512, 3);
        remap_kernel<<<MROWS, 512, 0, stream>>>(qkvb, ktcb, bte, btr, bcr, bce,
                                                qnb, ksb, vnb, colb_);
        vtrans_kernel<<<dim3(65, 16, 2), 256, 0, stream>>>(vnb, vtb);
        attn5_kernel<<<dim3(65, NCJ, 2), 256, 0, stream>>>(qnb, ksb, vtb, colb_, opb);
        osum_kernel<<<1025, 256, 0, stream>>>(opb, attnob);
        tgemm_kernel<<<dim3(8, 65), 256, 0, stream>>>(attnob, wTl + 327680, x_,
                                                      bo + l * 128, x_, MROWS, 128);
        ln_kernel<<<1025, 256, 0, stream>>>(x_, ln2g + l * 128, ln2b + l * 128, xnb, MROWS);
        mgemm_kernel<<<dim3(4, 33), 256, 0, stream>>>(xnb, xnb, 128, wTl + 393216,
                                                      nullptr, ffnhb, b1 + l * 512, nullptr,
                                                      MROWS, 128, 512, 2);
        tgemm_kernel<<<dim3(8, 65), 256, 0, stream>>>(ffnhb, wTl + 458752, x_,
                                                      b2 + l * 128, x_, MROWS, 128);
    }
    head_kernel<<<1, 64, 0, stream>>>(x_, hlng, hlnb, hw, hb, (float*)d_out);
}

// Round 7
// 560.140 us; speedup vs baseline: 6.4850x; 1.0092x over previous
//
#include <hip/hip_runtime.h>

#define CH    64
#define NTOK  2049
#define MROWS 4098
#define NCJ   8

typedef __attribute__((ext_vector_type(8))) short bf16x8;
typedef __attribute__((ext_vector_type(4))) float f32x4;
typedef __attribute__((ext_vector_type(2))) int i32x2;

// workspace offsets (float units) — sequential, no overlays
#define OFF_X     0u
#define OFF_XNB   524544u
#define OFF_RTB   786816u
#define OFF_RCB   1049088u
#define OFF_QKVB  1311360u
#define OFF_KTCB  4458624u
#define OFF_QNB   5507712u
#define OFF_KSB   6556800u
#define OFF_VNB   7605888u
#define OFF_VTB   8654976u
#define OFF_COLB  9719936u
#define OFF_WT    9752720u
#define OFF_OP    10277008u
#define OFF_ATTNO 18669712u
#define OFF_FFNH  19718800u

#define GLOAD_LDS16(gp, lp) __builtin_amdgcn_global_load_lds( \
    (const __attribute__((address_space(1))) void*)(gp), \
    (__attribute__((address_space(3))) void*)(lp), 16, 0, 0)

__device__ __forceinline__ float wave_allreduce_sum(float v) {
    #pragma unroll
    for (int m = 1; m < 64; m <<= 1) v += __shfl_xor(v, m);
    return v;
}

__device__ __forceinline__ ushort bf16rnd(float x) {
    unsigned u = __builtin_bit_cast(unsigned, x);
    u += 0x7FFF + ((u >> 16) & 1);
    return (ushort)(u >> 16);
}

__device__ __forceinline__ float bf16tof(ushort u) {
    return __builtin_bit_cast(float, ((unsigned)u) << 16);
}

// ---------------- weight prep: f32 [K][N] -> bf16 Wt [N][K] (ktc concatenated) ----------------
__global__ __launch_bounds__(256) void wprep_kernel(
    const float* __restrict__ wqkv, const float* __restrict__ wkt, const float* __restrict__ wkc,
    const float* __restrict__ wo, const float* __restrict__ w1, const float* __restrict__ w2,
    ushort* __restrict__ wT)
{
    int l = blockIdx.z, mat = blockIdx.y;
    int idx = blockIdx.x * 256 + threadIdx.x;
    float v; int off;
    if (mat == 0) {            // qkv: N=1536 K=128
        if (idx >= 196608) return;
        int n = idx >> 7, k = idx & 127;
        v = wqkv[(size_t)l * 196608 + (size_t)k * 1536 + n]; off = 0;
    } else if (mat == 1) {     // ktc: N=512 K=256 (wkt | wkc)
        if (idx >= 131072) return;
        int n = idx >> 8, k = idx & 255;
        v = (k < 128) ? wkt[(size_t)l * 65536 + (size_t)k * 512 + n]
                      : wkc[(size_t)l * 65536 + (size_t)(k - 128) * 512 + n];
        off = 196608;
    } else if (mat == 2) {     // wo: N=128 K=512
        if (idx >= 65536) return;
        int n = idx >> 9, k = idx & 511;
        v = wo[(size_t)l * 65536 + (size_t)k * 128 + n]; off = 327680;
    } else if (mat == 3) {     // w1: N=512 K=128
        if (idx >= 65536) return;
        int n = idx >> 7, k = idx & 127;
        v = w1[(size_t)l * 65536 + (size_t)k * 512 + n]; off = 393216;
    } else {                   // w2: N=128 K=512
        if (idx >= 65536) return;
        int n = idx >> 9, k = idx & 511;
        v = w2[(size_t)l * 65536 + (size_t)k * 128 + n]; off = 458752;
    }
    wT[(size_t)l * 524288 + off + idx] = bf16rnd(v);
}

// ---------------- embed ----------------
__global__ __launch_bounds__(128) void embed_kernel(
    const float* __restrict__ eeg, const float* __restrict__ est, const int* __restrict__ cvi,
    const float* __restrict__ cw, const float* __restrict__ cb,
    const float* __restrict__ cls, const float* __restrict__ clsp,
    float* __restrict__ x, ushort* __restrict__ rt, ushort* __restrict__ rc)
{
    int id = blockIdx.x;
    int d = threadIdx.x;
    if (id >= 4096) {
        int b = id - 4096;
        size_t base = (size_t)b * NTOK * 128 + d;
        x[base]  = cls[d];
        rt[base] = bf16rnd(clsp[d]);
        rc[base] = bf16rnd(clsp[d]);
        return;
    }
    int b = id >> 11, rem = id & 2047, c = rem >> 5, w = rem & 31;
    __shared__ float xs[25];
    if (d < 25) xs[d] = eeg[((size_t)(b * CH + c)) * 800 + w * 25 + d];
    __syncthreads();
    float acc = cb[d];
    #pragma unroll
    for (int p = 0; p < 25; ++p) acc += xs[p] * cw[d * 25 + p];
    int i = 1 + c * 32 + w;
    size_t base = ((size_t)b * NTOK + i) * 128 + d;
    x[base] = acc;
    int k = d & 63;
    float invk = __expf(-0.14391156831f * (float)k);
    float pt = floorf(est[b] / 0.1f) + (float)w;
    float at = pt * invk;
    rt[base] = bf16rnd((d < 64) ? sinf(at) : cosf(at));
    float pc = (float)cvi[b * CH + c];
    float ac = pc * invk;
    rc[base] = bf16rnd((d < 64) ? sinf(ac) : cosf(ac));
}

// ---------------- layernorm, bf16 out ----------------
__global__ __launch_bounds__(256) void ln_kernel(
    const float* __restrict__ x, const float* __restrict__ g, const float* __restrict__ bb,
    ushort* __restrict__ out, int rows)
{
    int w = threadIdx.x >> 6, lane = threadIdx.x & 63;
    int row = blockIdx.x * 4 + w;
    if (row >= rows) return;
    const float* xr = x + (size_t)row * 128;
    float v0 = xr[lane], v1 = xr[lane + 64];
    float mean = wave_allreduce_sum(v0 + v1) * (1.0f / 128.0f);
    float d0 = v0 - mean, d1 = v1 - mean;
    float var = wave_allreduce_sum(d0 * d0 + d1 * d1) * (1.0f / 128.0f);
    float inv = rsqrtf(var + 1e-5f);
    out[(size_t)row * 128 + lane]      = bf16rnd(d0 * inv * g[lane]      + bb[lane]);
    out[(size_t)row * 128 + lane + 64] = bf16rnd(d1 * inv * g[lane + 64] + bb[lane + 64]);
}

// ---------------- bf16 MFMA GEMM: C = A[MxK] * Wt[NxK]; A may be [A | A2] concat on K ----------------
// mode: 2 -> outB = bf16(gelu(acc+bias)); 3 -> outB = bf16(acc)
__global__ __launch_bounds__(256, 3) void mgemm_kernel(
    const ushort* __restrict__ A, const ushort* __restrict__ A2, int K1,
    const ushort* __restrict__ Wt,
    float* outF, ushort* outB, const float* bias, const float* res,
    int M, int K, int N, int mode)
{
    __shared__ ushort Alds[128 * 72];
    __shared__ ushort Blds[128 * 72];
    int tid = threadIdx.x;
    int lane = tid & 63, wv = tid >> 6;
    int wm = wv >> 1, wn = wv & 1;
    int li = lane & 15, g = lane >> 4;
    int m0 = blockIdx.y * 128, n0 = blockIdx.x * 128;
    int K2s = K - K1;
    f32x4 acc[4][4];
    #pragma unroll
    for (int a = 0; a < 4; ++a)
        #pragma unroll
        for (int c = 0; c < 4; ++c) acc[a][c] = (f32x4){0.f, 0.f, 0.f, 0.f};

    for (int kb = 0; kb < K; kb += 64) {
        #pragma unroll
        for (int it = 0; it < 4; ++it) {
            int gi = tid + it * 256;
            int row = gi >> 3, gc = gi & 7;
            int m = m0 + row; if (m >= M) m = M - 1;
            int acol = kb + gc * 8;
            const ushort* asrc = (acol < K1) ? (A + (size_t)m * K1 + acol)
                                             : (A2 + (size_t)m * K2s + (acol - K1));
            bf16x8 av = *(const bf16x8*)asrc;
            *(bf16x8*)&Alds[row * 72 + ((gc ^ (row & 7)) << 3)] = av;
            int n = n0 + row;
            bf16x8 bv = *(const bf16x8*)(Wt + (size_t)n * K + acol);
            *(bf16x8*)&Blds[row * 72 + ((gc ^ (row & 7)) << 3)] = bv;
        }
        __syncthreads();
        #pragma unroll
        for (int k2 = 0; k2 < 2; ++k2) {
            bf16x8 af[4], bfr[4];
            #pragma unroll
            for (int xx = 0; xx < 4; ++xx) {
                int ra = wm * 64 + xx * 16 + li;
                int rb = wn * 64 + xx * 16 + li;
                af[xx]  = *(const bf16x8*)&Alds[ra * 72 + (((k2 * 4 + g) ^ (ra & 7)) << 3)];
                bfr[xx] = *(const bf16x8*)&Blds[rb * 72 + (((k2 * 4 + g) ^ (rb & 7)) << 3)];
            }
            #pragma unroll
            for (int mi = 0; mi < 4; ++mi)
                #pragma unroll
                for (int ni = 0; ni < 4; ++ni)
                    acc[mi][ni] = __builtin_amdgcn_mfma_f32_16x16x32_bf16(af[mi], bfr[ni], acc[mi][ni], 0, 0, 0);
        }
        __syncthreads();
    }
    #pragma unroll
    for (int mi = 0; mi < 4; ++mi) {
        #pragma unroll
        for (int r = 0; r < 4; ++r) {
            int m = m0 + wm * 64 + mi * 16 + 4 * g + r;
            if (m >= M) continue;
            #pragma unroll
            for (int ni = 0; ni < 4; ++ni) {
                int n = n0 + wn * 64 + ni * 16 + li;
                float v = acc[mi][ni][r];
                if (mode == 2) {
                    v += bias[n];
                    v = 0.5f * v * (1.0f + erff(v * 0.70710678118f));
                    outB[(size_t)m * N + n] = bf16rnd(v);
                } else {
                    outB[(size_t)m * N + n] = bf16rnd(v);
                }
            }
        }
    }
}

// ---------------- thin GEMM (N=128, K=512): one 16x16 tile per wave, no LDS ----------------
__global__ __launch_bounds__(256) void tgemm_kernel(
    const ushort* __restrict__ A, const ushort* __restrict__ Wt,
    float* __restrict__ outF, const float* __restrict__ bias, const float* __restrict__ res,
    int M, int N)
{
    int lane = threadIdx.x & 63, wv = threadIdx.x >> 6;
    int li = lane & 15, g = lane >> 4;
    int mt = blockIdx.y * 4 + wv;
    int m0 = mt * 16, n0 = blockIdx.x * 16;
    int ar = m0 + li; if (ar >= M) ar = M - 1;
    const ushort* arow = A + (size_t)ar * 512 + 8 * g;
    const ushort* brow = Wt + (size_t)(n0 + li) * 512 + 8 * g;
    f32x4 acc = (f32x4){0.f, 0.f, 0.f, 0.f};
    #pragma unroll
    for (int k2 = 0; k2 < 16; ++k2) {
        bf16x8 af = *(const bf16x8*)(arow + k2 * 32);
        bf16x8 bf = *(const bf16x8*)(brow + k2 * 32);
        acc = __builtin_amdgcn_mfma_f32_16x16x32_bf16(af, bf, acc, 0, 0, 0);
    }
    #pragma unroll
    for (int r = 0; r < 4; ++r) {
        int m = m0 + 4 * g + r;
        if (m < M) {
            int n = n0 + li;
            outF[(size_t)m * N + n] = acc[r] + bias[n] + res[(size_t)m * N + n];
        }
    }
}

// ---------------- remap (bf16 inputs) -> qn/ksum/vn (new space) + colb ----------------
__global__ __launch_bounds__(512) void remap_kernel(
    const ushort* __restrict__ qkvb, const ushort* __restrict__ ktcb,
    const float* __restrict__ bte, const float* __restrict__ btr,
    const float* __restrict__ bcr, const float* __restrict__ bce,
    ushort* __restrict__ qn, ushort* __restrict__ ksum, ushort* __restrict__ vn,
    float* __restrict__ colb)
{
    int id = blockIdx.x;            // b2*NTOK + i2
    int b2 = id / NTOK, i2 = id - b2 * NTOK;
    int t = threadIdx.x;
    int h2 = t >> 6, d2 = t & 63;
    int G = i2 * 16 + b2 * 8 + h2;
    int bhA = G / 2049, iA = G - bhA * 2049;
    int bA = bhA >> 3, hA = bhA & 7;
    size_t qbase = ((size_t)(bA * NTOK + iA)) * 1536 + hA * 64 + d2;
    ushort qv = qkvb[qbase], kvu = qkvb[qbase + 512], vvu = qkvb[qbase + 1024];
    int bB = G / 16392, remB = G - bB * 16392;
    int iB = remB >> 3, hB = remB & 7;
    ushort ktcu = ktcb[((size_t)(bB * NTOK + iB)) * 512 + hB * 64 + d2];
    float kv = bf16tof(kvu), ktcv = bf16tof(ktcu);
    size_t ob = (size_t)id * 512 + t;
    qn[ob] = qv;
    ksum[ob] = bf16rnd(kv + ktcv);
    vn[ob] = vvu;
    float cbx = (bte[t] + bce[t]) * kv + (btr[t] + bcr[t]) * ktcv;
    cbx = wave_allreduce_sum(cbx);
    if (d2 == 0) colb[(size_t)id * 8 + h2] = cbx;
}

// ---------------- transpose V: vn[b][j][d] -> vt[b][d][j 2080] ----------------
__global__ __launch_bounds__(256) void vtrans_kernel(
    const ushort* __restrict__ vn, ushort* __restrict__ vt)
{
    __shared__ ushort tile[32][36];
    int jt = blockIdx.x, dt = blockIdx.y, b = blockIdx.z;
    int t = threadIdx.x;
    {
        int jj = t >> 3, dq = t & 7;
        int j = jt * 32 + jj; if (j > 2048) j = 2048;
        const ushort* src = vn + ((size_t)(b * NTOK + j)) * 512 + dt * 32 + dq * 4;
        *(ushort4*)&tile[jj][dq * 4] = *(const ushort4*)src;
    }
    __syncthreads();
    {
        int dd = t >> 3, jq = t & 7;
        ushort4 w;
        w.x = tile[jq * 4 + 0][dd];
        w.y = tile[jq * 4 + 1][dd];
        w.z = tile[jq * 4 + 2][dd];
        w.w = tile[jq * 4 + 3][dd];
        *(ushort4*)(vt + ((size_t)b * 512 + dt * 32 + dd) * 2080 + jt * 32 + jq * 4) = w;
    }
}

// ---------------- attn6: swapped-QK fused attention, in-register P, 1 barrier/iter ----------------
// grid (33, NCJ=8, 2); 4 waves, each owns a 16-row i-subtile (block i-tile 64), j-tile 16.
// mfma(A=K, B=Q) -> lane holds s(j=4g+r, i=li); softmax over heads in-lane; P is DIRECTLY the
// PV A-operand for mfma_16x16x16 (natural k-map 4g+e). K/V/cb all double-buffered in LDS via
// global_load_lds staged one full iteration ahead -> ONE __syncthreads per iteration.
// LDS: K 2x16KB @0 | V 2x16KB @32768 | cb 2x512B @65536  = 66.6KB -> 2 blocks/CU.
__global__ __launch_bounds__(256, 2) void attn6_kernel(
    const ushort* __restrict__ qn, const ushort* __restrict__ ks,
    const ushort* __restrict__ vt, const float* __restrict__ colb,
    ushort* __restrict__ Op)
{
    __shared__ __align__(16) char smem[66560];
    const int tid = threadIdx.x;
    const int lane = tid & 63, wv = tid >> 6;
    const int g = lane >> 4, li = lane & 15;
    const int nc = blockIdx.y, b = blockIdx.z;
    const int i0 = blockIdx.x * 64;
    const int jt0 = (nc * 129) >> 3, jt1 = ((nc + 1) * 129) >> 3;

    // Q fragments (B-operand): lane holds Q[i = i0+wv*16+li][h*64 + k2*32 + 8g + e]
    bf16x8 qf[8][2];
    {
        int iq = i0 + wv * 16 + li; if (iq > 2048) iq = 2048;
        const ushort* qrow = qn + ((size_t)(b * NTOK + iq)) * 512;
        #pragma unroll
        for (int h = 0; h < 8; ++h)
            #pragma unroll
            for (int k2 = 0; k2 < 2; ++k2)
                qf[h][k2] = *(const bf16x8*)(qrow + h * 64 + k2 * 32 + 8 * g);
    }
    f32x4 o[8][4];
    #pragma unroll
    for (int h = 0; h < 8; ++h)
        #pragma unroll
        for (int dt = 0; dt < 4; ++dt) o[h][dt] = (f32x4){0.f, 0.f, 0.f, 0.f};

    // --- async stagers: one full tile (16 instrs = 4/wave), dest wave-uniform+lane*16 ---
    auto stageK = [&](int jt, int buf) {
        #pragma unroll
        for (int t = 0; t < 4; ++t) {
            unsigned L = (unsigned)(wv * 256 + t * 64 + lane) * 16u;
            unsigned Lp = L ^ (((L >> 10) & 7u) << 4);     // XOR-swizzled K layout
            int j = (int)(Lp >> 10);
            int jg = jt * 16 + j; if (jg > 2048) jg = 2048;
            const ushort* src = ks + ((size_t)(b * NTOK + jg)) * 512 + ((Lp & 1023u) >> 1);
            GLOAD_LDS16(src, smem + buf * 16384 + (wv * 256 + t * 64) * 16);
        }
    };
    auto stageV = [&](int jt, int buf) {                   // linear [d 512][j 16]
        #pragma unroll
        for (int t = 0; t < 4; ++t) {
            int n = wv * 256 + t * 64 + lane;
            int d = n >> 1, half = n & 1;
            const ushort* src = vt + ((size_t)b * 512 + d) * 2080 + jt * 16 + half * 8;
            GLOAD_LDS16(src, smem + 32768 + buf * 16384 + (wv * 256 + t * 64) * 16);
        }
    };
    auto loadcb = [&](int jt) -> float {
        if (tid < 128) {
            int jg = jt * 16 + (tid >> 3);
            bool ok = (jg <= 2048); if (!ok) jg = 2048;
            float v = colb[((size_t)(b * NTOK + jg)) * 8 + (tid & 7)];
            return ok ? v : -1e30f;
        }
        return 0.f;
    };

    // prologue: stage tile jt0 (buf0); pre-write cb(jt0) to cb-buf0; prefetch cbreg = cb(jt0+1)
    stageK(jt0, 0); stageV(jt0, 0);
    {
        float c0 = loadcb(jt0);
        if (tid < 128) ((float*)(smem + 65536))[tid] = c0;
    }
    float cbreg = loadcb(jt0 + 1);

    int cur = 0;
    for (int jt = jt0; jt < jt1; ++jt) {
        __syncthreads();   // drains all global_load_lds (issued a full iter ago) + cb writes
        const bool hn = (jt + 1 < jt1);
        // write cb(jt+1) into other cb-buf; prefetch cb(jt+2); stage K/V(jt+1) into other bufs
        if (hn) {
            if (tid < 128) ((float*)(smem + 65536 + (cur ^ 1) * 512))[tid] = cbreg;
            stageK(jt + 1, cur ^ 1);
            stageV(jt + 1, cur ^ 1);
            cbreg = loadcb(jt + 2);
        }
        // ---- QK (swapped): s = mfma(K, Q) -> lane holds s[h](j = 4g+r, i = li) ----
        const char* kb = smem + cur * 16384;
        f32x4 s[8];
        #pragma unroll
        for (int h = 0; h < 8; ++h) {
            s[h] = (f32x4){0.f, 0.f, 0.f, 0.f};
            #pragma unroll
            for (int k2 = 0; k2 < 2; ++k2) {
                unsigned boff = (unsigned)(li * 1024 + h * 128 + k2 * 64 + g * 16);
                boff ^= (unsigned)((li & 7) << 4);
                bf16x8 kf = *(const bf16x8*)(kb + boff);
                s[h] = __builtin_amdgcn_mfma_f32_16x16x32_bf16(kf, qf[h][k2], s[h], 0, 0, 0);
            }
        }
        // ---- softmax over heads (in-lane) -> pack P (A-operand for PV) ----
        const float* cbl = (const float*)(smem + 65536 + cur * 512);
        unsigned P2[8][2];
        #pragma unroll
        for (int r = 0; r < 4; ++r) {
            int j = 4 * g + r;                     // lane's j-local for this r
            float4 c0 = *(const float4*)(cbl + j * 8);       // broadcast reads
            float4 c1 = *(const float4*)(cbl + j * 8 + 4);
            float cb8[8] = {c0.x, c0.y, c0.z, c0.w, c1.x, c1.y, c1.z, c1.w};
            float p[8]; float sum = 0.f;
            #pragma unroll
            for (int h = 0; h < 8; ++h) {
                p[h] = __expf((s[h][r] + cb8[h]) * 0.125f);
                sum += p[h];
            }
            float inv = __builtin_amdgcn_rcpf(fmaxf(sum, 1e-20f));  // NORMAL floor (denorm rcp->inf)
            #pragma unroll
            for (int h = 0; h < 8; ++h) {
                unsigned u = (unsigned)bf16rnd(p[h] * inv);
                if ((r & 1) == 0) P2[h][r >> 1] = u;
                else              P2[h][r >> 1] |= (u << 16);
            }
        }
        // ---- PV: o[h][dt] += P[h] x V  (16x16x16, K=j16; natural k-map 4g+e both sides) ----
        const char* vb = smem + 32768 + cur * 16384;
        #pragma unroll
        for (int h = 0; h < 8; ++h) {
            i32x2 pa = (i32x2){(int)P2[h][0], (int)P2[h][1]};
            #pragma unroll
            for (int dt = 0; dt < 4; ++dt) {
                int d = h * 64 + dt * 16 + li;
                i32x2 vv = *(const i32x2*)(vb + d * 32 + 8 * g);
                asm("v_mfma_f32_16x16x16_bf16 %0, %1, %2, %0"
                    : "+v"(o[h][dt]) : "v"(pa), "v"(vv));
            }
        }
        cur ^= 1;
    }
    // ---- store partial O (bf16): i = i0 + wv*16 + 4g + r, d = h*64 + dt*16 + li ----
    {
        int irow0 = i0 + wv * 16 + 4 * g;
        #pragma unroll
        for (int h = 0; h < 8; ++h) {
            #pragma unroll
            for (int dt = 0; dt < 4; ++dt) {
                #pragma unroll
                for (int r = 0; r < 4; ++r) {
                    int irow = irow0 + r;
                    if (irow <= 2048) {
                        Op[(((size_t)(nc * 2 + b)) * 2049 + irow) * 512 + h * 64 + dt * 16 + li] =
                            bf16rnd(o[h][dt][r]);
                    }
                }
            }
        }
    }
}

// ---------------- sum NCJ bf16 partials -> bf16 attno ----------------
__global__ __launch_bounds__(256) void osum_kernel(
    const ushort* __restrict__ Op, ushort* __restrict__ attno)
{
    int idx = blockIdx.x * 256 + threadIdx.x;
    if (idx >= MROWS * 64) return;
    int row = idx >> 6, dq = idx & 63;
    int b = row / NTOK, i = row - b * NTOK;
    float acc[8];
    #pragma unroll
    for (int e = 0; e < 8; ++e) acc[e] = 0.f;
    #pragma unroll
    for (int nc = 0; nc < NCJ; ++nc) {
        const ushort* src = Op + (((size_t)(nc * 2 + b)) * 2049 + i) * 512 + dq * 8;
        int4 v = *(const int4*)src;
        const ushort* up = (const ushort*)&v;
        #pragma unroll
        for (int e = 0; e < 8; ++e) acc[e] += bf16tof(up[e]);
    }
    ushort ov[8];
    #pragma unroll
    for (int e = 0; e < 8; ++e) ov[e] = bf16rnd(acc[e]);
    *(int4*)(attno + (size_t)row * 512 + dq * 8) = *(int4*)ov;
}

// ---------------- head ----------------
__global__ void head_kernel(
    const float* __restrict__ x, const float* __restrict__ g, const float* __restrict__ b,
    const float* __restrict__ w, const float* __restrict__ hb, float* __restrict__ out)
{
    int lane = threadIdx.x & 63;
    for (int bi = 0; bi < 2; ++bi) {
        const float* xr = x + (size_t)bi * NTOK * 128;
        float v0 = xr[lane], v1 = xr[lane + 64];
        float mean = wave_allreduce_sum(v0 + v1) * (1.0f / 128.0f);
        float d0 = v0 - mean, d1 = v1 - mean;
        float var = wave_allreduce_sum(d0 * d0 + d1 * d1) * (1.0f / 128.0f);
        float inv = rsqrtf(var + 1e-5f);
        float y0 = d0 * inv * g[lane] + b[lane];
        float y1 = d1 * inv * g[lane + 64] + b[lane + 64];
        for (int c = 0; c < 4; ++c) {
            float pt = y0 * w[lane * 4 + c] + y1 * w[(lane + 64) * 4 + c];
            pt = wave_allreduce_sum(pt);
            if (lane == 0) out[bi * 4 + c] = pt + hb[c];
        }
    }
}

extern "C" void kernel_launch(void* const* d_in, const int* in_sizes, int n_in,
                              void* d_out, int out_size, void* d_ws, size_t ws_size,
                              hipStream_t stream) {
    const float* eeg   = (const float*)d_in[0];
    const float* est   = (const float*)d_in[1];
    const int*   cvi   = (const int*)d_in[2];
    const float* convw = (const float*)d_in[3];
    const float* convb = (const float*)d_in[4];
    const float* cls   = (const float*)d_in[5];
    const float* clsp  = (const float*)d_in[6];
    const float* bte   = (const float*)d_in[7];
    const float* btr   = (const float*)d_in[8];
    const float* bcr   = (const float*)d_in[9];
    const float* bce   = (const float*)d_in[10];
    const float* ln1g  = (const float*)d_in[11];
    const float* ln1b  = (const float*)d_in[12];
    const float* wqkv  = (const float*)d_in[13];
    const float* wkt   = (const float*)d_in[14];
    const float* wkc   = (const float*)d_in[15];
    const float* wo    = (const float*)d_in[16];
    const float* bo    = (const float*)d_in[17];
    const float* ln2g  = (const float*)d_in[18];
    const float* ln2b  = (const float*)d_in[19];
    const float* w1    = (const float*)d_in[20];
    const float* b1    = (const float*)d_in[21];
    const float* w2    = (const float*)d_in[22];
    const float* b2    = (const float*)d_in[23];
    const float* hlng  = (const float*)d_in[24];
    const float* hlnb  = (const float*)d_in[25];
    const float* hw    = (const float*)d_in[26];
    const float* hb    = (const float*)d_in[27];

    float* ws    = (float*)d_ws;
    float* x_    = ws + OFF_X;
    ushort* xnb  = (ushort*)(ws + OFF_XNB);
    ushort* rtb  = (ushort*)(ws + OFF_RTB);
    ushort* rcb  = (ushort*)(ws + OFF_RCB);
    ushort* qkvb = (ushort*)(ws + OFF_QKVB);
    ushort* ktcb = (ushort*)(ws + OFF_KTCB);
    ushort* qnb  = (ushort*)(ws + OFF_QNB);
    ushort* ksb  = (ushort*)(ws + OFF_KSB);
    ushort* vnb  = (ushort*)(ws + OFF_VNB);
    ushort* vtb  = (ushort*)(ws + OFF_VTB);
    float* colb_ = ws + OFF_COLB;
    ushort* wT   = (ushort*)(ws + OFF_WT);
    ushort* opb  = (ushort*)(ws + OFF_OP);
    ushort* attnob = (ushort*)(ws + OFF_ATTNO);
    ushort* ffnhb  = (ushort*)(ws + OFF_FFNH);

    wprep_kernel<<<dim3(768, 5, 2), 256, 0, stream>>>(wqkv, wkt, wkc, wo, w1, w2, wT);
    embed_kernel<<<4098, 128, 0, stream>>>(eeg, est, cvi, convw, convb, cls, clsp, x_, rtb, rcb);

    for (int l = 0; l < 2; ++l) {
        const ushort* wTl = wT + (size_t)l * 524288;
        ln_kernel<<<1025, 256, 0, stream>>>(x_, ln1g + l * 128, ln1b + l * 128, xnb, MROWS);
        mgemm_kernel<<<dim3(12, 33), 256, 0, stream>>>(xnb, xnb, 128, wTl,
                                                       nullptr, qkvb, nullptr, nullptr,
                                                       MROWS, 128, 1536, 3);
        mgemm_kernel<<<dim3(4, 33), 256, 0, stream>>>(rtb, rcb, 128, wTl + 196608,
                                                      nullptr, ktcb, nullptr, nullptr,
                                                      MROWS, 256, 512, 3);
        remap_kernel<<<MROWS, 512, 0, stream>>>(qkvb, ktcb, bte, btr, bcr, bce,
                                                qnb, ksb, vnb, colb_);
        vtrans_kernel<<<dim3(65, 16, 2), 256, 0, stream>>>(vnb, vtb);
        attn6_kernel<<<dim3(33, NCJ, 2), 256, 0, stream>>>(qnb, ksb, vtb, colb_, opb);
        osum_kernel<<<1025, 256, 0, stream>>>(opb, attnob);
        tgemm_kernel<<<dim3(8, 65), 256, 0, stream>>>(attnob, wTl + 327680, x_,
                                                      bo + l * 128, x_, MROWS, 128);
        ln_kernel<<<1025, 256, 0, stream>>>(x_, ln2g + l * 128, ln2b + l * 128, xnb, MROWS);
        mgemm_kernel<<<dim3(4, 33), 256, 0, stream>>>(xnb, xnb, 128, wTl + 393216,
                                                      nullptr, ffnhb, b1 + l * 512, nullptr,
                                                      MROWS, 128, 512, 2);
        tgemm_kernel<<<dim3(8, 65), 256, 0, stream>>>(ffnhb, wTl + 458752, x_,
                                                      b2 + l * 128, x_, MROWS, 128);
    }
    head_kernel<<<1, 64, 0, stream>>>(x_, hlng, hlnb, hw, hb, (float*)d_out);
}

// Round 8
// 496.761 us; speedup vs baseline: 7.3124x; 1.1276x over previous
//
#include <hip/hip_runtime.h>

#define CH    64
#define NTOK  2049
#define MROWS 4098
#define NCJ   4

typedef __attribute__((ext_vector_type(8))) short bf16x8;
typedef __attribute__((ext_vector_type(4))) float f32x4;
typedef __attribute__((ext_vector_type(2))) int i32x2;

// workspace offsets (float units) — sequential, no overlays
#define OFF_X     0u
#define OFF_XNB   524544u
#define OFF_RTB   786816u
#define OFF_RCB   1049088u
#define OFF_QKVB  1311360u
#define OFF_KTCB  4458624u
#define OFF_QNB   5507712u
#define OFF_KSB   6556800u
#define OFF_VNB   7605888u
#define OFF_VTB   8654976u
#define OFF_COLB  9719936u
#define OFF_WT    9752720u
#define OFF_OP    10277008u
#define OFF_ATTNO 18669712u
#define OFF_FFNH  19718800u

#define GLOAD_LDS16(gp, lp) __builtin_amdgcn_global_load_lds( \
    (const __attribute__((address_space(1))) void*)(gp), \
    (__attribute__((address_space(3))) void*)(lp), 16, 0, 0)

__device__ __forceinline__ float wave_allreduce_sum(float v) {
    #pragma unroll
    for (int m = 1; m < 64; m <<= 1) v += __shfl_xor(v, m);
    return v;
}

__device__ __forceinline__ ushort bf16rnd(float x) {
    unsigned u = __builtin_bit_cast(unsigned, x);
    u += 0x7FFF + ((u >> 16) & 1);
    return (ushort)(u >> 16);
}

__device__ __forceinline__ float bf16tof(ushort u) {
    return __builtin_bit_cast(float, ((unsigned)u) << 16);
}

// ---------------- weight prep: f32 [K][N] -> bf16 Wt [N][K] (ktc concatenated) ----------------
__global__ __launch_bounds__(256) void wprep_kernel(
    const float* __restrict__ wqkv, const float* __restrict__ wkt, const float* __restrict__ wkc,
    const float* __restrict__ wo, const float* __restrict__ w1, const float* __restrict__ w2,
    ushort* __restrict__ wT)
{
    int l = blockIdx.z, mat = blockIdx.y;
    int idx = blockIdx.x * 256 + threadIdx.x;
    float v; int off;
    if (mat == 0) {            // qkv: N=1536 K=128
        if (idx >= 196608) return;
        int n = idx >> 7, k = idx & 127;
        v = wqkv[(size_t)l * 196608 + (size_t)k * 1536 + n]; off = 0;
    } else if (mat == 1) {     // ktc: N=512 K=256 (wkt | wkc)
        if (idx >= 131072) return;
        int n = idx >> 8, k = idx & 255;
        v = (k < 128) ? wkt[(size_t)l * 65536 + (size_t)k * 512 + n]
                      : wkc[(size_t)l * 65536 + (size_t)(k - 128) * 512 + n];
        off = 196608;
    } else if (mat == 2) {     // wo: N=128 K=512
        if (idx >= 65536) return;
        int n = idx >> 9, k = idx & 511;
        v = wo[(size_t)l * 65536 + (size_t)k * 128 + n]; off = 327680;
    } else if (mat == 3) {     // w1: N=512 K=128
        if (idx >= 65536) return;
        int n = idx >> 7, k = idx & 127;
        v = w1[(size_t)l * 65536 + (size_t)k * 512 + n]; off = 393216;
    } else {                   // w2: N=128 K=512
        if (idx >= 65536) return;
        int n = idx >> 9, k = idx & 511;
        v = w2[(size_t)l * 65536 + (size_t)k * 128 + n]; off = 458752;
    }
    wT[(size_t)l * 524288 + off + idx] = bf16rnd(v);
}

// ---------------- embed ----------------
__global__ __launch_bounds__(128) void embed_kernel(
    const float* __restrict__ eeg, const float* __restrict__ est, const int* __restrict__ cvi,
    const float* __restrict__ cw, const float* __restrict__ cb,
    const float* __restrict__ cls, const float* __restrict__ clsp,
    float* __restrict__ x, ushort* __restrict__ rt, ushort* __restrict__ rc)
{
    int id = blockIdx.x;
    int d = threadIdx.x;
    if (id >= 4096) {
        int b = id - 4096;
        size_t base = (size_t)b * NTOK * 128 + d;
        x[base]  = cls[d];
        rt[base] = bf16rnd(clsp[d]);
        rc[base] = bf16rnd(clsp[d]);
        return;
    }
    int b = id >> 11, rem = id & 2047, c = rem >> 5, w = rem & 31;
    __shared__ float xs[25];
    if (d < 25) xs[d] = eeg[((size_t)(b * CH + c)) * 800 + w * 25 + d];
    __syncthreads();
    float acc = cb[d];
    #pragma unroll
    for (int p = 0; p < 25; ++p) acc += xs[p] * cw[d * 25 + p];
    int i = 1 + c * 32 + w;
    size_t base = ((size_t)b * NTOK + i) * 128 + d;
    x[base] = acc;
    int k = d & 63;
    float invk = __expf(-0.14391156831f * (float)k);
    float pt = floorf(est[b] / 0.1f) + (float)w;
    float at = pt * invk;
    rt[base] = bf16rnd((d < 64) ? sinf(at) : cosf(at));
    float pc = (float)cvi[b * CH + c];
    float ac = pc * invk;
    rc[base] = bf16rnd((d < 64) ? sinf(ac) : cosf(ac));
}

// ---------------- layernorm, bf16 out ----------------
__global__ __launch_bounds__(256) void ln_kernel(
    const float* __restrict__ x, const float* __restrict__ g, const float* __restrict__ bb,
    ushort* __restrict__ out, int rows)
{
    int w = threadIdx.x >> 6, lane = threadIdx.x & 63;
    int row = blockIdx.x * 4 + w;
    if (row >= rows) return;
    const float* xr = x + (size_t)row * 128;
    float v0 = xr[lane], v1 = xr[lane + 64];
    float mean = wave_allreduce_sum(v0 + v1) * (1.0f / 128.0f);
    float d0 = v0 - mean, d1 = v1 - mean;
    float var = wave_allreduce_sum(d0 * d0 + d1 * d1) * (1.0f / 128.0f);
    float inv = rsqrtf(var + 1e-5f);
    out[(size_t)row * 128 + lane]      = bf16rnd(d0 * inv * g[lane]      + bb[lane]);
    out[(size_t)row * 128 + lane + 64] = bf16rnd(d1 * inv * g[lane + 64] + bb[lane + 64]);
}

// ---------------- bf16 MFMA GEMM: C = A[MxK] * Wt[NxK]; A may be [A | A2] concat on K ----------------
// mode: 2 -> outB = bf16(gelu(acc+bias)); 3 -> outB = bf16(acc)
__global__ __launch_bounds__(256, 3) void mgemm_kernel(
    const ushort* __restrict__ A, const ushort* __restrict__ A2, int K1,
    const ushort* __restrict__ Wt,
    float* outF, ushort* outB, const float* bias, const float* res,
    int M, int K, int N, int mode)
{
    __shared__ ushort Alds[128 * 72];
    __shared__ ushort Blds[128 * 72];
    int tid = threadIdx.x;
    int lane = tid & 63, wv = tid >> 6;
    int wm = wv >> 1, wn = wv & 1;
    int li = lane & 15, g = lane >> 4;
    int m0 = blockIdx.y * 128, n0 = blockIdx.x * 128;
    int K2s = K - K1;
    f32x4 acc[4][4];
    #pragma unroll
    for (int a = 0; a < 4; ++a)
        #pragma unroll
        for (int c = 0; c < 4; ++c) acc[a][c] = (f32x4){0.f, 0.f, 0.f, 0.f};

    for (int kb = 0; kb < K; kb += 64) {
        #pragma unroll
        for (int it = 0; it < 4; ++it) {
            int gi = tid + it * 256;
            int row = gi >> 3, gc = gi & 7;
            int m = m0 + row; if (m >= M) m = M - 1;
            int acol = kb + gc * 8;
            const ushort* asrc = (acol < K1) ? (A + (size_t)m * K1 + acol)
                                             : (A2 + (size_t)m * K2s + (acol - K1));
            bf16x8 av = *(const bf16x8*)asrc;
            *(bf16x8*)&Alds[row * 72 + ((gc ^ (row & 7)) << 3)] = av;
            int n = n0 + row;
            bf16x8 bv = *(const bf16x8*)(Wt + (size_t)n * K + acol);
            *(bf16x8*)&Blds[row * 72 + ((gc ^ (row & 7)) << 3)] = bv;
        }
        __syncthreads();
        #pragma unroll
        for (int k2 = 0; k2 < 2; ++k2) {
            bf16x8 af[4], bfr[4];
            #pragma unroll
            for (int xx = 0; xx < 4; ++xx) {
                int ra = wm * 64 + xx * 16 + li;
                int rb = wn * 64 + xx * 16 + li;
                af[xx]  = *(const bf16x8*)&Alds[ra * 72 + (((k2 * 4 + g) ^ (ra & 7)) << 3)];
                bfr[xx] = *(const bf16x8*)&Blds[rb * 72 + (((k2 * 4 + g) ^ (rb & 7)) << 3)];
            }
            #pragma unroll
            for (int mi = 0; mi < 4; ++mi)
                #pragma unroll
                for (int ni = 0; ni < 4; ++ni)
                    acc[mi][ni] = __builtin_amdgcn_mfma_f32_16x16x32_bf16(af[mi], bfr[ni], acc[mi][ni], 0, 0, 0);
        }
        __syncthreads();
    }
    #pragma unroll
    for (int mi = 0; mi < 4; ++mi) {
        #pragma unroll
        for (int r = 0; r < 4; ++r) {
            int m = m0 + wm * 64 + mi * 16 + 4 * g + r;
            if (m >= M) continue;
            #pragma unroll
            for (int ni = 0; ni < 4; ++ni) {
                int n = n0 + wn * 64 + ni * 16 + li;
                float v = acc[mi][ni][r];
                if (mode == 2) {
                    v += bias[n];
                    v = 0.5f * v * (1.0f + erff(v * 0.70710678118f));
                    outB[(size_t)m * N + n] = bf16rnd(v);
                } else {
                    outB[(size_t)m * N + n] = bf16rnd(v);
                }
            }
        }
    }
}

// ---------------- thin GEMM (N=128, K=512): one 16x16 tile per wave, no LDS ----------------
__global__ __launch_bounds__(256) void tgemm_kernel(
    const ushort* __restrict__ A, const ushort* __restrict__ Wt,
    float* __restrict__ outF, const float* __restrict__ bias, const float* __restrict__ res,
    int M, int N)
{
    int lane = threadIdx.x & 63, wv = threadIdx.x >> 6;
    int li = lane & 15, g = lane >> 4;
    int mt = blockIdx.y * 4 + wv;
    int m0 = mt * 16, n0 = blockIdx.x * 16;
    int ar = m0 + li; if (ar >= M) ar = M - 1;
    const ushort* arow = A + (size_t)ar * 512 + 8 * g;
    const ushort* brow = Wt + (size_t)(n0 + li) * 512 + 8 * g;
    f32x4 acc = (f32x4){0.f, 0.f, 0.f, 0.f};
    #pragma unroll
    for (int k2 = 0; k2 < 16; ++k2) {
        bf16x8 af = *(const bf16x8*)(arow + k2 * 32);
        bf16x8 bf = *(const bf16x8*)(brow + k2 * 32);
        acc = __builtin_amdgcn_mfma_f32_16x16x32_bf16(af, bf, acc, 0, 0, 0);
    }
    #pragma unroll
    for (int r = 0; r < 4; ++r) {
        int m = m0 + 4 * g + r;
        if (m < M) {
            int n = n0 + li;
            outF[(size_t)m * N + n] = acc[r] + bias[n] + res[(size_t)m * N + n];
        }
    }
}

// ---------------- remap (bf16 inputs) -> qn(x0.125)/ksum/vn + colb ----------------
__global__ __launch_bounds__(512) void remap_kernel(
    const ushort* __restrict__ qkvb, const ushort* __restrict__ ktcb,
    const float* __restrict__ bte, const float* __restrict__ btr,
    const float* __restrict__ bcr, const float* __restrict__ bce,
    ushort* __restrict__ qn, ushort* __restrict__ ksum, ushort* __restrict__ vn,
    float* __restrict__ colb)
{
    int id = blockIdx.x;            // b2*NTOK + i2
    int b2 = id / NTOK, i2 = id - b2 * NTOK;
    int t = threadIdx.x;
    int h2 = t >> 6, d2 = t & 63;
    int G = i2 * 16 + b2 * 8 + h2;
    int bhA = G / 2049, iA = G - bhA * 2049;
    int bA = bhA >> 3, hA = bhA & 7;
    size_t qbase = ((size_t)(bA * NTOK + iA)) * 1536 + hA * 64 + d2;
    ushort qv = qkvb[qbase], kvu = qkvb[qbase + 512], vvu = qkvb[qbase + 1024];
    int bB = G / 16392, remB = G - bB * 16392;
    int iB = remB >> 3, hB = remB & 7;
    ushort ktcu = ktcb[((size_t)(bB * NTOK + iB)) * 512 + hB * 64 + d2];
    float kv = bf16tof(kvu), ktcv = bf16tof(ktcu);
    size_t ob = (size_t)id * 512 + t;
    qn[ob] = bf16rnd(bf16tof(qv) * 0.125f);   // exact (exponent shift) — folds SCALE into QK
    ksum[ob] = bf16rnd(kv + ktcv);
    vn[ob] = vvu;
    float cbx = (bte[t] + bce[t]) * kv + (btr[t] + bcr[t]) * ktcv;
    cbx = wave_allreduce_sum(cbx);
    if (d2 == 0) colb[(size_t)id * 8 + h2] = cbx;
}

// ---------------- transpose V: vn[b][j][d] -> vt[b][d][j 2080] ----------------
__global__ __launch_bounds__(256) void vtrans_kernel(
    const ushort* __restrict__ vn, ushort* __restrict__ vt)
{
    __shared__ ushort tile[32][36];
    int jt = blockIdx.x, dt = blockIdx.y, b = blockIdx.z;
    int t = threadIdx.x;
    {
        int jj = t >> 3, dq = t & 7;
        int j = jt * 32 + jj; if (j > 2048) j = 2048;
        const ushort* src = vn + ((size_t)(b * NTOK + j)) * 512 + dt * 32 + dq * 4;
        *(ushort4*)&tile[jj][dq * 4] = *(const ushort4*)src;
    }
    __syncthreads();
    {
        int dd = t >> 3, jq = t & 7;
        ushort4 w;
        w.x = tile[jq * 4 + 0][dd];
        w.y = tile[jq * 4 + 1][dd];
        w.z = tile[jq * 4 + 2][dd];
        w.w = tile[jq * 4 + 3][dd];
        *(ushort4*)(vt + ((size_t)b * 512 + dt * 32 + dd) * 2080 + jt * 32 + jq * 4) = w;
    }
}

// ---------------- attn7: swapped-QK, in-register P, spill-free register budget ----------------
// grid (65, NCJ=4, 2); 4 waves = (wi i-16-subtile, hs head-half). i-tile 32, j-tile 16.
// QK duplicated across hs (all 8 heads per wave, builtin MFMA); softmax in-lane; P packed
// (cvt_pk) is directly the 16x16x16 PV A-operand. o[4][4] forced to AGPR ("+a") -> arch VGPR
// fits (~160), total ~224 <= 256, NO scratch. K swizzled as attn6; V 16B-granule XOR-swizzled
// (source-permuted for global_load_lds). LDS: K 2x16K | V 2x16K | cb 2x512 = 65.5KB.
__global__ __launch_bounds__(256, 2) void attn7_kernel(
    const ushort* __restrict__ qn, const ushort* __restrict__ ks,
    const ushort* __restrict__ vt, const float* __restrict__ colb,
    ushort* __restrict__ Op)
{
    __shared__ __align__(16) char smem[66560];
    const int tid = threadIdx.x;
    const int lane = tid & 63, wv = tid >> 6;
    const int wi = wv >> 1, hs = wv & 1;
    const int g = lane >> 4, li = lane & 15;
    const int nc = blockIdx.y, b = blockIdx.z;
    const int i0 = blockIdx.x * 32;
    const int jt0 = (nc * 129) / NCJ, jt1 = ((nc + 1) * 129) / NCJ;

    // Q fragments (B-operand), pre-scaled by 0.125 in remap
    bf16x8 qf[8][2];
    {
        int iq = i0 + wi * 16 + li; if (iq > 2048) iq = 2048;
        const ushort* qrow = qn + ((size_t)(b * NTOK + iq)) * 512;
        #pragma unroll
        for (int h = 0; h < 8; ++h)
            #pragma unroll
            for (int k2 = 0; k2 < 2; ++k2)
                qf[h][k2] = *(const bf16x8*)(qrow + h * 64 + k2 * 32 + 8 * g);
    }
    f32x4 o[4][4];   // 4 heads (hs half) x 4 d-subtiles -> AGPR via "+a"
    #pragma unroll
    for (int a = 0; a < 4; ++a)
        #pragma unroll
        for (int m = 0; m < 4; ++m) o[a][m] = (f32x4){0.f, 0.f, 0.f, 0.f};

    // hoisted per-lane LDS read bases (compile-time imm offsets inside loops)
    const unsigned koff0 = (unsigned)(li * 1024) + (unsigned)((g * 16) ^ ((li & 7) << 4));
    const unsigned koff1 = (unsigned)(li * 1024) + (unsigned)((64 + g * 16) ^ ((li & 7) << 4));
    const unsigned vboff = (unsigned)((((2 * li + (g >> 1)) ^ ((li >> 2) & 3)) << 4) + (g & 1) * 8)
                         + (unsigned)(hs * 8192);

    auto stageK = [&](int jt, int buf) {
        #pragma unroll
        for (int t = 0; t < 4; ++t) {
            unsigned L = (unsigned)((wv * 256 + t * 64 + lane) * 16);
            unsigned Lp = L ^ (((L >> 10) & 7u) << 4);
            int j = (int)(Lp >> 10);
            int jg = jt * 16 + j; if (jg > 2048) jg = 2048;
            const ushort* src = ks + ((size_t)(b * NTOK + jg)) * 512 + ((Lp & 1023u) >> 1);
            GLOAD_LDS16(src, smem + buf * 16384 + (wv * 256 + t * 64) * 16);
        }
    };
    auto stageV = [&](int jt, int buf) {   // [d 512][j 16], 16B-granule swizzle via source perm
        #pragma unroll
        for (int t = 0; t < 4; ++t) {
            int n = wv * 256 + t * 64 + lane;
            int m = n ^ ((n >> 3) & 3);
            int d = m >> 1, half = m & 1;
            const ushort* src = vt + ((size_t)b * 512 + d) * 2080 + jt * 16 + half * 8;
            GLOAD_LDS16(src, smem + 32768 + buf * 16384 + (wv * 256 + t * 64) * 16);
        }
    };
    auto loadcb = [&](int jt) -> float {   // pre-scaled by 0.125; -1e30 mask
        if (tid < 128) {
            int jg = jt * 16 + (tid >> 3);
            bool ok = (jg <= 2048); if (!ok) jg = 2048;
            float v = colb[((size_t)(b * NTOK + jg)) * 8 + (tid & 7)] * 0.125f;
            return ok ? v : -1e30f;
        }
        return 0.f;
    };

    stageK(jt0, 0); stageV(jt0, 0);
    {
        float c0 = loadcb(jt0);
        if (tid < 128) ((float*)(smem + 65536))[tid] = c0;
    }
    float cbreg = loadcb(jt0 + 1);

    int cur = 0;
    for (int jt = jt0; jt < jt1; ++jt) {
        __syncthreads();   // drains prior-iter global_load_lds + cb writes
        const bool hn = (jt + 1 < jt1);
        if (hn) {
            if (tid < 128) ((float*)(smem + 65536 + (cur ^ 1) * 512))[tid] = cbreg;
            stageK(jt + 1, cur ^ 1);
            stageV(jt + 1, cur ^ 1);
            cbreg = loadcb(jt + 2);
        }
        // ---- QK (swapped): s[h](j=4g+r, i=li), all 8 heads ----
        const char* kb = smem + cur * 16384;
        f32x4 s[8];
        #pragma unroll
        for (int h = 0; h < 8; ++h) {
            s[h] = (f32x4){0.f, 0.f, 0.f, 0.f};
            bf16x8 kf0 = *(const bf16x8*)(kb + koff0 + h * 128);
            s[h] = __builtin_amdgcn_mfma_f32_16x16x32_bf16(kf0, qf[h][0], s[h], 0, 0, 0);
            bf16x8 kf1 = *(const bf16x8*)(kb + koff1 + h * 128);
            s[h] = __builtin_amdgcn_mfma_f32_16x16x32_bf16(kf1, qf[h][1], s[h], 0, 0, 0);
        }
        // ---- softmax over heads (in-lane); pack this wave's 4 heads via cvt_pk ----
        const float* cbl = (const float*)(smem + 65536 + cur * 512);
        unsigned P2[4][2];
        #pragma unroll
        for (int rp = 0; rp < 2; ++rp) {
            f32x4 ca0 = *(const f32x4*)(cbl + (4 * g + 2 * rp) * 8);
            f32x4 ca1 = *(const f32x4*)(cbl + (4 * g + 2 * rp) * 8 + 4);
            f32x4 cb0 = *(const f32x4*)(cbl + (4 * g + 2 * rp + 1) * 8);
            f32x4 cb1 = *(const f32x4*)(cbl + (4 * g + 2 * rp + 1) * 8 + 4);
            float pa_[8], pb_[8]; float sa = 0.f, sb = 0.f;
            #pragma unroll
            for (int h = 0; h < 8; ++h) {
                float cav = (h < 4) ? ca0[h & 3] : ca1[h & 3];
                float cbv = (h < 4) ? cb0[h & 3] : cb1[h & 3];
                pa_[h] = __expf(s[h][2 * rp]     + cav); sa += pa_[h];
                pb_[h] = __expf(s[h][2 * rp + 1] + cbv); sb += pb_[h];
            }
            float ia = __builtin_amdgcn_rcpf(fmaxf(sa, 1e-20f));  // NORMAL floor (denorm rcp->inf)
            float ib = __builtin_amdgcn_rcpf(fmaxf(sb, 1e-20f));
            #pragma unroll
            for (int hh = 0; hh < 4; ++hh) {
                int h = hs * 4 + hh;
                float lo = pa_[h] * ia, hi = pb_[h] * ib;
                asm("v_cvt_pk_bf16_f32 %0, %1, %2" : "=v"(P2[hh][rp]) : "v"(lo), "v"(hi));
            }
        }
        // ---- PV: heads hs*4..+3, 16x16x16, o in AGPR ----
        const char* vb = smem + 32768 + cur * 16384 + vboff;
        #pragma unroll
        for (int hh = 0; hh < 4; ++hh) {
            i32x2 pa = (i32x2){(int)P2[hh][0], (int)P2[hh][1]};
            #pragma unroll
            for (int dt = 0; dt < 4; ++dt) {
                i32x2 vv = *(const i32x2*)(vb + hh * 2048 + dt * 512);
                asm("v_mfma_f32_16x16x16_bf16 %0, %1, %2, %0"
                    : "+a"(o[hh][dt]) : "v"(pa), "v"(vv));
            }
        }
        cur ^= 1;
    }
    // ---- store partial O (bf16): i = i0+wi*16+4g+r, d = (hs*4+hh)*64 + dt*16 + li ----
    {
        int irow0 = i0 + wi * 16 + 4 * g;
        #pragma unroll
        for (int hh = 0; hh < 4; ++hh) {
            int d0 = (hs * 4 + hh) * 64;
            #pragma unroll
            for (int dt = 0; dt < 4; ++dt) {
                #pragma unroll
                for (int r = 0; r < 4; ++r) {
                    int irow = irow0 + r;
                    if (irow <= 2048) {
                        Op[(((size_t)(nc * 2 + b)) * 2049 + irow) * 512 + d0 + dt * 16 + li] =
                            bf16rnd(o[hh][dt][r]);
                    }
                }
            }
        }
    }
}

// ---------------- sum NCJ bf16 partials -> bf16 attno ----------------
__global__ __launch_bounds__(256) void osum_kernel(
    const ushort* __restrict__ Op, ushort* __restrict__ attno)
{
    int idx = blockIdx.x * 256 + threadIdx.x;
    if (idx >= MROWS * 64) return;
    int row = idx >> 6, dq = idx & 63;
    int b = row / NTOK, i = row - b * NTOK;
    float acc[8];
    #pragma unroll
    for (int e = 0; e < 8; ++e) acc[e] = 0.f;
    #pragma unroll
    for (int nc = 0; nc < NCJ; ++nc) {
        const ushort* src = Op + (((size_t)(nc * 2 + b)) * 2049 + i) * 512 + dq * 8;
        int4 v = *(const int4*)src;
        const ushort* up = (const ushort*)&v;
        #pragma unroll
        for (int e = 0; e < 8; ++e) acc[e] += bf16tof(up[e]);
    }
    ushort ov[8];
    #pragma unroll
    for (int e = 0; e < 8; ++e) ov[e] = bf16rnd(acc[e]);
    *(int4*)(attno + (size_t)row * 512 + dq * 8) = *(int4*)ov;
}

// ---------------- head ----------------
__global__ void head_kernel(
    const float* __restrict__ x, const float* __restrict__ g, const float* __restrict__ b,
    const float* __restrict__ w, const float* __restrict__ hb, float* __restrict__ out)
{
    int lane = threadIdx.x & 63;
    for (int bi = 0; bi < 2; ++bi) {
        const float* xr = x + (size_t)bi * NTOK * 128;
        float v0 = xr[lane], v1 = xr[lane + 64];
        float mean = wave_allreduce_sum(v0 + v1) * (1.0f / 128.0f);
        float d0 = v0 - mean, d1 = v1 - mean;
        float var = wave_allreduce_sum(d0 * d0 + d1 * d1) * (1.0f / 128.0f);
        float inv = rsqrtf(var + 1e-5f);
        float y0 = d0 * inv * g[lane] + b[lane];
        float y1 = d1 * inv * g[lane + 64] + b[lane + 64];
        for (int c = 0; c < 4; ++c) {
            float pt = y0 * w[lane * 4 + c] + y1 * w[(lane + 64) * 4 + c];
            pt = wave_allreduce_sum(pt);
            if (lane == 0) out[bi * 4 + c] = pt + hb[c];
        }
    }
}

extern "C" void kernel_launch(void* const* d_in, const int* in_sizes, int n_in,
                              void* d_out, int out_size, void* d_ws, size_t ws_size,
                              hipStream_t stream) {
    const float* eeg   = (const float*)d_in[0];
    const float* est   = (const float*)d_in[1];
    const int*   cvi   = (const int*)d_in[2];
    const float* convw = (const float*)d_in[3];
    const float* convb = (const float*)d_in[4];
    const float* cls   = (const float*)d_in[5];
    const float* clsp  = (const float*)d_in[6];
    const float* bte   = (const float*)d_in[7];
    const float* btr   = (const float*)d_in[8];
    const float* bcr   = (const float*)d_in[9];
    const float* bce   = (const float*)d_in[10];
    const float* ln1g  = (const float*)d_in[11];
    const float* ln1b  = (const float*)d_in[12];
    const float* wqkv  = (const float*)d_in[13];
    const float* wkt   = (const float*)d_in[14];
    const float* wkc   = (const float*)d_in[15];
    const float* wo    = (const float*)d_in[16];
    const float* bo    = (const float*)d_in[17];
    const float* ln2g  = (const float*)d_in[18];
    const float* ln2b  = (const float*)d_in[19];
    const float* w1    = (const float*)d_in[20];
    const float* b1    = (const float*)d_in[21];
    const float* w2    = (const float*)d_in[22];
    const float* b2    = (const float*)d_in[23];
    const float* hlng  = (const float*)d_in[24];
    const float* hlnb  = (const float*)d_in[25];
    const float* hw    = (const float*)d_in[26];
    const float* hb    = (const float*)d_in[27];

    float* ws    = (float*)d_ws;
    float* x_    = ws + OFF_X;
    ushort* xnb  = (ushort*)(ws + OFF_XNB);
    ushort* rtb  = (ushort*)(ws + OFF_RTB);
    ushort* rcb  = (ushort*)(ws + OFF_RCB);
    ushort* qkvb = (ushort*)(ws + OFF_QKVB);
    ushort* ktcb = (ushort*)(ws + OFF_KTCB);
    ushort* qnb  = (ushort*)(ws + OFF_QNB);
    ushort* ksb  = (ushort*)(ws + OFF_KSB);
    ushort* vnb  = (ushort*)(ws + OFF_VNB);
    ushort* vtb  = (ushort*)(ws + OFF_VTB);
    float* colb_ = ws + OFF_COLB;
    ushort* wT   = (ushort*)(ws + OFF_WT);
    ushort* opb  = (ushort*)(ws + OFF_OP);
    ushort* attnob = (ushort*)(ws + OFF_ATTNO);
    ushort* ffnhb  = (ushort*)(ws + OFF_FFNH);

    wprep_kernel<<<dim3(768, 5, 2), 256, 0, stream>>>(wqkv, wkt, wkc, wo, w1, w2, wT);
    embed_kernel<<<4098, 128, 0, stream>>>(eeg, est, cvi, convw, convb, cls, clsp, x_, rtb, rcb);

    for (int l = 0; l < 2; ++l) {
        const ushort* wTl = wT + (size_t)l * 524288;
        ln_kernel<<<1025, 256, 0, stream>>>(x_, ln1g + l * 128, ln1b + l * 128, xnb, MROWS);
        mgemm_kernel<<<dim3(12, 33), 256, 0, stream>>>(xnb, xnb, 128, wTl,
                                                       nullptr, qkvb, nullptr, nullptr,
                                                       MROWS, 128, 1536, 3);
        mgemm_kernel<<<dim3(4, 33), 256, 0, stream>>>(rtb, rcb, 128, wTl + 196608,
                                                      nullptr, ktcb, nullptr, nullptr,
                                                      MROWS, 256, 512, 3);
        remap_kernel<<<MROWS, 512, 0, stream>>>(qkvb, ktcb, bte, btr, bcr, bce,
                                                qnb, ksb, vnb, colb_);
        vtrans_kernel<<<dim3(65, 16, 2), 256, 0, stream>>>(vnb, vtb);
        attn7_kernel<<<dim3(65, NCJ, 2), 256, 0, stream>>>(qnb, ksb, vtb, colb_, opb);
        osum_kernel<<<1025, 256, 0, stream>>>(opb, attnob);
        tgemm_kernel<<<dim3(8, 65), 256, 0, stream>>>(attnob, wTl + 327680, x_,
                                                      bo + l * 128, x_, MROWS, 128);
        ln_kernel<<<1025, 256, 0, stream>>>(x_, ln2g + l * 128, ln2b + l * 128, xnb, MROWS);
        mgemm_kernel<<<dim3(4, 33), 256, 0, stream>>>(xnb, xnb, 128, wTl + 393216,
                                                      nullptr, ffnhb, b1 + l * 512, nullptr,
                                                      MROWS, 128, 512, 2);
        tgemm_kernel<<<dim3(8, 65), 256, 0, stream>>>(ffnhb, wTl + 458752, x_,
                                                      b2 + l * 128, x_, MROWS, 128);
    }
    head_kernel<<<1, 64, 0, stream>>>(x_, hlng, hlnb, hw, hb, (float*)d_out);
}

// Round 9
// 421.234 us; speedup vs baseline: 8.6235x; 1.1793x over previous
//
#include <hip/hip_runtime.h>

#define CH    64
#define NTOK  2049
#define MROWS 4098
#define NCJ   3

typedef __attribute__((ext_vector_type(8))) short bf16x8;
typedef __attribute__((ext_vector_type(4))) float f32x4;
typedef __attribute__((ext_vector_type(2))) int i32x2;

// workspace offsets (float units) — sequential, no overlays
#define OFF_X     0u
#define OFF_XNB   524544u
#define OFF_RTB   786816u
#define OFF_RCB   1049088u
#define OFF_QKVB  1311360u
#define OFF_KTCB  4458624u
#define OFF_QNB   5507712u
#define OFF_KSB   6556800u
#define OFF_VNB   7605888u
#define OFF_VTB   8654976u
#define OFF_COLB  9719936u
#define OFF_WT    9752720u
#define OFF_OP    10277008u
#define OFF_ATTNO 18669712u
#define OFF_FFNH  19718800u

// 0.125 * log2(e): folds SCALE and exp->exp2 conversion into q/colb pre-scale
#define QSCALE 0.1803368801111204f

#define GLOAD_LDS16(gp, lp) __builtin_amdgcn_global_load_lds( \
    (const __attribute__((address_space(1))) void*)(gp), \
    (__attribute__((address_space(3))) void*)(lp), 16, 0, 0)

__device__ __forceinline__ float wave_allreduce_sum(float v) {
    #pragma unroll
    for (int m = 1; m < 64; m <<= 1) v += __shfl_xor(v, m);
    return v;
}

__device__ __forceinline__ ushort bf16rnd(float x) {
    unsigned u = __builtin_bit_cast(unsigned, x);
    u += 0x7FFF + ((u >> 16) & 1);
    return (ushort)(u >> 16);
}

__device__ __forceinline__ float bf16tof(ushort u) {
    return __builtin_bit_cast(float, ((unsigned)u) << 16);
}

// ---------------- weight prep: f32 [K][N] -> bf16 Wt [N][K] (ktc concatenated) ----------------
__global__ __launch_bounds__(256) void wprep_kernel(
    const float* __restrict__ wqkv, const float* __restrict__ wkt, const float* __restrict__ wkc,
    const float* __restrict__ wo, const float* __restrict__ w1, const float* __restrict__ w2,
    ushort* __restrict__ wT)
{
    int l = blockIdx.z, mat = blockIdx.y;
    int idx = blockIdx.x * 256 + threadIdx.x;
    float v; int off;
    if (mat == 0) {            // qkv: N=1536 K=128
        if (idx >= 196608) return;
        int n = idx >> 7, k = idx & 127;
        v = wqkv[(size_t)l * 196608 + (size_t)k * 1536 + n]; off = 0;
    } else if (mat == 1) {     // ktc: N=512 K=256 (wkt | wkc)
        if (idx >= 131072) return;
        int n = idx >> 8, k = idx & 255;
        v = (k < 128) ? wkt[(size_t)l * 65536 + (size_t)k * 512 + n]
                      : wkc[(size_t)l * 65536 + (size_t)(k - 128) * 512 + n];
        off = 196608;
    } else if (mat == 2) {     // wo: N=128 K=512
        if (idx >= 65536) return;
        int n = idx >> 9, k = idx & 511;
        v = wo[(size_t)l * 65536 + (size_t)k * 128 + n]; off = 327680;
    } else if (mat == 3) {     // w1: N=512 K=128
        if (idx >= 65536) return;
        int n = idx >> 7, k = idx & 127;
        v = w1[(size_t)l * 65536 + (size_t)k * 512 + n]; off = 393216;
    } else {                   // w2: N=128 K=512
        if (idx >= 65536) return;
        int n = idx >> 9, k = idx & 511;
        v = w2[(size_t)l * 65536 + (size_t)k * 128 + n]; off = 458752;
    }
    wT[(size_t)l * 524288 + off + idx] = bf16rnd(v);
}

// ---------------- embed ----------------
__global__ __launch_bounds__(128) void embed_kernel(
    const float* __restrict__ eeg, const float* __restrict__ est, const int* __restrict__ cvi,
    const float* __restrict__ cw, const float* __restrict__ cb,
    const float* __restrict__ cls, const float* __restrict__ clsp,
    float* __restrict__ x, ushort* __restrict__ rt, ushort* __restrict__ rc)
{
    int id = blockIdx.x;
    int d = threadIdx.x;
    if (id >= 4096) {
        int b = id - 4096;
        size_t base = (size_t)b * NTOK * 128 + d;
        x[base]  = cls[d];
        rt[base] = bf16rnd(clsp[d]);
        rc[base] = bf16rnd(clsp[d]);
        return;
    }
    int b = id >> 11, rem = id & 2047, c = rem >> 5, w = rem & 31;
    __shared__ float xs[25];
    if (d < 25) xs[d] = eeg[((size_t)(b * CH + c)) * 800 + w * 25 + d];
    __syncthreads();
    float acc = cb[d];
    #pragma unroll
    for (int p = 0; p < 25; ++p) acc += xs[p] * cw[d * 25 + p];
    int i = 1 + c * 32 + w;
    size_t base = ((size_t)b * NTOK + i) * 128 + d;
    x[base] = acc;
    int k = d & 63;
    float invk = __expf(-0.14391156831f * (float)k);
    float pt = floorf(est[b] / 0.1f) + (float)w;
    float at = pt * invk;
    rt[base] = bf16rnd((d < 64) ? sinf(at) : cosf(at));
    float pc = (float)cvi[b * CH + c];
    float ac = pc * invk;
    rc[base] = bf16rnd((d < 64) ? sinf(ac) : cosf(ac));
}

// ---------------- layernorm, bf16 out ----------------
__global__ __launch_bounds__(256) void ln_kernel(
    const float* __restrict__ x, const float* __restrict__ g, const float* __restrict__ bb,
    ushort* __restrict__ out, int rows)
{
    int w = threadIdx.x >> 6, lane = threadIdx.x & 63;
    int row = blockIdx.x * 4 + w;
    if (row >= rows) return;
    const float* xr = x + (size_t)row * 128;
    float v0 = xr[lane], v1 = xr[lane + 64];
    float mean = wave_allreduce_sum(v0 + v1) * (1.0f / 128.0f);
    float d0 = v0 - mean, d1 = v1 - mean;
    float var = wave_allreduce_sum(d0 * d0 + d1 * d1) * (1.0f / 128.0f);
    float inv = rsqrtf(var + 1e-5f);
    out[(size_t)row * 128 + lane]      = bf16rnd(d0 * inv * g[lane]      + bb[lane]);
    out[(size_t)row * 128 + lane + 64] = bf16rnd(d1 * inv * g[lane + 64] + bb[lane + 64]);
}

// ---------------- bf16 MFMA GEMM: C = A[MxK] * Wt[NxK]; A may be [A | A2] concat on K ----------------
// mode: 2 -> outB = bf16(gelu(acc+bias)); 3 -> outB = bf16(acc)
__global__ __launch_bounds__(256, 3) void mgemm_kernel(
    const ushort* __restrict__ A, const ushort* __restrict__ A2, int K1,
    const ushort* __restrict__ Wt,
    float* outF, ushort* outB, const float* bias, const float* res,
    int M, int K, int N, int mode)
{
    __shared__ ushort Alds[128 * 72];
    __shared__ ushort Blds[128 * 72];
    int tid = threadIdx.x;
    int lane = tid & 63, wv = tid >> 6;
    int wm = wv >> 1, wn = wv & 1;
    int li = lane & 15, g = lane >> 4;
    int m0 = blockIdx.y * 128, n0 = blockIdx.x * 128;
    int K2s = K - K1;
    f32x4 acc[4][4];
    #pragma unroll
    for (int a = 0; a < 4; ++a)
        #pragma unroll
        for (int c = 0; c < 4; ++c) acc[a][c] = (f32x4){0.f, 0.f, 0.f, 0.f};

    for (int kb = 0; kb < K; kb += 64) {
        #pragma unroll
        for (int it = 0; it < 4; ++it) {
            int gi = tid + it * 256;
            int row = gi >> 3, gc = gi & 7;
            int m = m0 + row; if (m >= M) m = M - 1;
            int acol = kb + gc * 8;
            const ushort* asrc = (acol < K1) ? (A + (size_t)m * K1 + acol)
                                             : (A2 + (size_t)m * K2s + (acol - K1));
            bf16x8 av = *(const bf16x8*)asrc;
            *(bf16x8*)&Alds[row * 72 + ((gc ^ (row & 7)) << 3)] = av;
            int n = n0 + row;
            bf16x8 bv = *(const bf16x8*)(Wt + (size_t)n * K + acol);
            *(bf16x8*)&Blds[row * 72 + ((gc ^ (row & 7)) << 3)] = bv;
        }
        __syncthreads();
        #pragma unroll
        for (int k2 = 0; k2 < 2; ++k2) {
            bf16x8 af[4], bfr[4];
            #pragma unroll
            for (int xx = 0; xx < 4; ++xx) {
                int ra = wm * 64 + xx * 16 + li;
                int rb = wn * 64 + xx * 16 + li;
                af[xx]  = *(const bf16x8*)&Alds[ra * 72 + (((k2 * 4 + g) ^ (ra & 7)) << 3)];
                bfr[xx] = *(const bf16x8*)&Blds[rb * 72 + (((k2 * 4 + g) ^ (rb & 7)) << 3)];
            }
            #pragma unroll
            for (int mi = 0; mi < 4; ++mi)
                #pragma unroll
                for (int ni = 0; ni < 4; ++ni)
                    acc[mi][ni] = __builtin_amdgcn_mfma_f32_16x16x32_bf16(af[mi], bfr[ni], acc[mi][ni], 0, 0, 0);
        }
        __syncthreads();
    }
    #pragma unroll
    for (int mi = 0; mi < 4; ++mi) {
        #pragma unroll
        for (int r = 0; r < 4; ++r) {
            int m = m0 + wm * 64 + mi * 16 + 4 * g + r;
            if (m >= M) continue;
            #pragma unroll
            for (int ni = 0; ni < 4; ++ni) {
                int n = n0 + wn * 64 + ni * 16 + li;
                float v = acc[mi][ni][r];
                if (mode == 2) {
                    v += bias[n];
                    v = 0.5f * v * (1.0f + erff(v * 0.70710678118f));
                    outB[(size_t)m * N + n] = bf16rnd(v);
                } else {
                    outB[(size_t)m * N + n] = bf16rnd(v);
                }
            }
        }
    }
}

// ---------------- thin GEMM (N=128, K=512): one 16x16 tile per wave, no LDS ----------------
__global__ __launch_bounds__(256) void tgemm_kernel(
    const ushort* __restrict__ A, const ushort* __restrict__ Wt,
    float* __restrict__ outF, const float* __restrict__ bias, const float* __restrict__ res,
    int M, int N)
{
    int lane = threadIdx.x & 63, wv = threadIdx.x >> 6;
    int li = lane & 15, g = lane >> 4;
    int mt = blockIdx.y * 4 + wv;
    int m0 = mt * 16, n0 = blockIdx.x * 16;
    int ar = m0 + li; if (ar >= M) ar = M - 1;
    const ushort* arow = A + (size_t)ar * 512 + 8 * g;
    const ushort* brow = Wt + (size_t)(n0 + li) * 512 + 8 * g;
    f32x4 acc = (f32x4){0.f, 0.f, 0.f, 0.f};
    #pragma unroll
    for (int k2 = 0; k2 < 16; ++k2) {
        bf16x8 af = *(const bf16x8*)(arow + k2 * 32);
        bf16x8 bf = *(const bf16x8*)(brow + k2 * 32);
        acc = __builtin_amdgcn_mfma_f32_16x16x32_bf16(af, bf, acc, 0, 0, 0);
    }
    #pragma unroll
    for (int r = 0; r < 4; ++r) {
        int m = m0 + 4 * g + r;
        if (m < M) {
            int n = n0 + li;
            outF[(size_t)m * N + n] = acc[r] + bias[n] + res[(size_t)m * N + n];
        }
    }
}

// ---------------- remap (bf16 inputs) -> qn(xQSCALE)/ksum/vn + colb ----------------
__global__ __launch_bounds__(512) void remap_kernel(
    const ushort* __restrict__ qkvb, const ushort* __restrict__ ktcb,
    const float* __restrict__ bte, const float* __restrict__ btr,
    const float* __restrict__ bcr, const float* __restrict__ bce,
    ushort* __restrict__ qn, ushort* __restrict__ ksum, ushort* __restrict__ vn,
    float* __restrict__ colb)
{
    int id = blockIdx.x;            // b2*NTOK + i2
    int b2 = id / NTOK, i2 = id - b2 * NTOK;
    int t = threadIdx.x;
    int h2 = t >> 6, d2 = t & 63;
    int G = i2 * 16 + b2 * 8 + h2;
    int bhA = G / 2049, iA = G - bhA * 2049;
    int bA = bhA >> 3, hA = bhA & 7;
    size_t qbase = ((size_t)(bA * NTOK + iA)) * 1536 + hA * 64 + d2;
    ushort qv = qkvb[qbase], kvu = qkvb[qbase + 512], vvu = qkvb[qbase + 1024];
    int bB = G / 16392, remB = G - bB * 16392;
    int iB = remB >> 3, hB = remB & 7;
    ushort ktcu = ktcb[((size_t)(bB * NTOK + iB)) * 512 + hB * 64 + d2];
    float kv = bf16tof(kvu), ktcv = bf16tof(ktcu);
    size_t ob = (size_t)id * 512 + t;
    qn[ob] = bf16rnd(bf16tof(qv) * QSCALE);   // folds SCALE + log2e (exp -> exp2)
    ksum[ob] = bf16rnd(kv + ktcv);
    vn[ob] = vvu;
    float cbx = (bte[t] + bce[t]) * kv + (btr[t] + bcr[t]) * ktcv;
    cbx = wave_allreduce_sum(cbx);
    if (d2 == 0) colb[(size_t)id * 8 + h2] = cbx;
}

// ---------------- transpose V: vn[b][j][d] -> vt[b][d][j 2080] ----------------
__global__ __launch_bounds__(256) void vtrans_kernel(
    const ushort* __restrict__ vn, ushort* __restrict__ vt)
{
    __shared__ ushort tile[32][36];
    int jt = blockIdx.x, dt = blockIdx.y, b = blockIdx.z;
    int t = threadIdx.x;
    {
        int jj = t >> 3, dq = t & 7;
        int j = jt * 32 + jj; if (j > 2048) j = 2048;
        const ushort* src = vn + ((size_t)(b * NTOK + j)) * 512 + dt * 32 + dq * 4;
        *(ushort4*)&tile[jj][dq * 4] = *(const ushort4*)src;
    }
    __syncthreads();
    {
        int dd = t >> 3, jq = t & 7;
        ushort4 w;
        w.x = tile[jq * 4 + 0][dd];
        w.y = tile[jq * 4 + 1][dd];
        w.z = tile[jq * 4 + 2][dd];
        w.w = tile[jq * 4 + 3][dd];
        *(ushort4*)(vt + ((size_t)b * 512 + dt * 32 + dd) * 2080 + jt * 32 + jq * 4) = w;
    }
}

// ---------------- attn8: swapped-QK, in-register P; single-round grid + exp2 + 2-way V swz ----
// grid (65, NCJ=3, 2) = 390 blocks <= 512 residency slots (2 blocks/CU at 66.5KB LDS) -> no
// 2-round tail (round-8 lesson: 520 blocks = 512+8 cost a full extra round).
// 4 waves = (wi i-16-subtile, hs head-half). i-tile 32, j-tile 16; 43 tiles per nc (129=3*43).
// Softmax uses v_exp_f32 directly (scales pre-folded with log2e). V LDS granule swizzle key
// reduced to (d>>2)&1 on the h16 bit -> 2-way bank aliasing (free) instead of 4-way.
__global__ __launch_bounds__(256, 2) void attn8_kernel(
    const ushort* __restrict__ qn, const ushort* __restrict__ ks,
    const ushort* __restrict__ vt, const float* __restrict__ colb,
    ushort* __restrict__ Op)
{
    __shared__ __align__(16) char smem[66560];
    const int tid = threadIdx.x;
    const int lane = tid & 63, wv = tid >> 6;
    const int wi = wv >> 1, hs = wv & 1;
    const int g = lane >> 4, li = lane & 15;
    const int nc = blockIdx.y, b = blockIdx.z;
    const int i0 = blockIdx.x * 32;
    const int jt0 = nc * 43, jt1 = (nc + 1) * 43;

    // Q fragments (B-operand), pre-scaled by QSCALE in remap
    bf16x8 qf[8][2];
    {
        int iq = i0 + wi * 16 + li; if (iq > 2048) iq = 2048;
        const ushort* qrow = qn + ((size_t)(b * NTOK + iq)) * 512;
        #pragma unroll
        for (int h = 0; h < 8; ++h)
            #pragma unroll
            for (int k2 = 0; k2 < 2; ++k2)
                qf[h][k2] = *(const bf16x8*)(qrow + h * 64 + k2 * 32 + 8 * g);
    }
    f32x4 o[4][4];   // 4 heads (hs half) x 4 d-subtiles -> AGPR via "+a"
    #pragma unroll
    for (int a = 0; a < 4; ++a)
        #pragma unroll
        for (int m = 0; m < 4; ++m) o[a][m] = (f32x4){0.f, 0.f, 0.f, 0.f};

    // hoisted per-lane LDS read bases (compile-time imm offsets inside loops)
    const unsigned koff0 = (unsigned)(li * 1024) + (unsigned)((g * 16) ^ ((li & 7) << 4));
    const unsigned koff1 = (unsigned)(li * 1024) + (unsigned)((64 + g * 16) ^ ((li & 7) << 4));
    // V read: logical 8B unit g of row d' -> phys = d'*32 + ((g>>1)^((li>>2)&1))*16 + (g&1)*8
    const unsigned vboff = (unsigned)(li * 32)
                         + (unsigned)((((g >> 1) ^ ((li >> 2) & 1)) << 4) + (g & 1) * 8)
                         + (unsigned)(hs * 8192);

    auto stageK = [&](int jt, int buf) {
        #pragma unroll
        for (int t = 0; t < 4; ++t) {
            unsigned L = (unsigned)((wv * 256 + t * 64 + lane) * 16);
            unsigned Lp = L ^ (((L >> 10) & 7u) << 4);
            int j = (int)(Lp >> 10);
            int jg = jt * 16 + j; if (jg > 2048) jg = 2048;
            const ushort* src = ks + ((size_t)(b * NTOK + jg)) * 512 + ((Lp & 1023u) >> 1);
            GLOAD_LDS16(src, smem + buf * 16384 + (wv * 256 + t * 64) * 16);
        }
    };
    auto stageV = [&](int jt, int buf) {   // [d 512][j 16], h16 bit XOR'd by (d>>2)&1 (src perm)
        #pragma unroll
        for (int t = 0; t < 4; ++t) {
            int n = wv * 256 + t * 64 + lane;
            int d = n >> 1;
            int h16 = (n & 1) ^ ((n >> 3) & 1);
            const ushort* src = vt + ((size_t)b * 512 + d) * 2080 + jt * 16 + h16 * 8;
            GLOAD_LDS16(src, smem + 32768 + buf * 16384 + (wv * 256 + t * 64) * 16);
        }
    };
    auto loadcb = [&](int jt) -> float {   // pre-scaled by QSCALE; -1e30 mask
        if (tid < 128) {
            int jg = jt * 16 + (tid >> 3);
            bool ok = (jg <= 2048); if (!ok) jg = 2048;
            float v = colb[((size_t)(b * NTOK + jg)) * 8 + (tid & 7)] * QSCALE;
            return ok ? v : -1e30f;
        }
        return 0.f;
    };

    stageK(jt0, 0); stageV(jt0, 0);
    {
        float c0 = loadcb(jt0);
        if (tid < 128) ((float*)(smem + 65536))[tid] = c0;
    }
    float cbreg = loadcb(jt0 + 1);

    int cur = 0;
    for (int jt = jt0; jt < jt1; ++jt) {
        __syncthreads();   // drains prior-iter global_load_lds + cb writes
        const bool hn = (jt + 1 < jt1);
        if (hn) {
            if (tid < 128) ((float*)(smem + 65536 + (cur ^ 1) * 512))[tid] = cbreg;
            stageK(jt + 1, cur ^ 1);
            stageV(jt + 1, cur ^ 1);
            cbreg = loadcb(jt + 2);
        }
        // ---- QK (swapped): s[h](j=4g+r, i=li), all 8 heads ----
        const char* kb = smem + cur * 16384;
        f32x4 s[8];
        #pragma unroll
        for (int h = 0; h < 8; ++h) {
            s[h] = (f32x4){0.f, 0.f, 0.f, 0.f};
            bf16x8 kf0 = *(const bf16x8*)(kb + koff0 + h * 128);
            s[h] = __builtin_amdgcn_mfma_f32_16x16x32_bf16(kf0, qf[h][0], s[h], 0, 0, 0);
            bf16x8 kf1 = *(const bf16x8*)(kb + koff1 + h * 128);
            s[h] = __builtin_amdgcn_mfma_f32_16x16x32_bf16(kf1, qf[h][1], s[h], 0, 0, 0);
        }
        // ---- softmax over heads (in-lane, exp2); pack this wave's 4 heads via cvt_pk ----
        const float* cbl = (const float*)(smem + 65536 + cur * 512);
        unsigned P2[4][2];
        #pragma unroll
        for (int rp = 0; rp < 2; ++rp) {
            f32x4 ca0 = *(const f32x4*)(cbl + (4 * g + 2 * rp) * 8);
            f32x4 ca1 = *(const f32x4*)(cbl + (4 * g + 2 * rp) * 8 + 4);
            f32x4 cb0 = *(const f32x4*)(cbl + (4 * g + 2 * rp + 1) * 8);
            f32x4 cb1 = *(const f32x4*)(cbl + (4 * g + 2 * rp + 1) * 8 + 4);
            float pa_[8], pb_[8]; float sa = 0.f, sb = 0.f;
            #pragma unroll
            for (int h = 0; h < 8; ++h) {
                float cav = (h < 4) ? ca0[h & 3] : ca1[h & 3];
                float cbv = (h < 4) ? cb0[h & 3] : cb1[h & 3];
                pa_[h] = __builtin_amdgcn_exp2f(s[h][2 * rp]     + cav); sa += pa_[h];
                pb_[h] = __builtin_amdgcn_exp2f(s[h][2 * rp + 1] + cbv); sb += pb_[h];
            }
            float ia = __builtin_amdgcn_rcpf(fmaxf(sa, 1e-20f));  // NORMAL floor (denorm rcp->inf)
            float ib = __builtin_amdgcn_rcpf(fmaxf(sb, 1e-20f));
            #pragma unroll
            for (int hh = 0; hh < 4; ++hh) {
                int h = hs * 4 + hh;
                float lo = pa_[h] * ia, hi = pb_[h] * ib;
                asm("v_cvt_pk_bf16_f32 %0, %1, %2" : "=v"(P2[hh][rp]) : "v"(lo), "v"(hi));
            }
        }
        // ---- PV: heads hs*4..+3, 16x16x16, o in AGPR ----
        const char* vb = smem + 32768 + cur * 16384 + vboff;
        #pragma unroll
        for (int hh = 0; hh < 4; ++hh) {
            i32x2 pa = (i32x2){(int)P2[hh][0], (int)P2[hh][1]};
            #pragma unroll
            for (int dt = 0; dt < 4; ++dt) {
                i32x2 vv = *(const i32x2*)(vb + hh * 2048 + dt * 512);
                asm("v_mfma_f32_16x16x16_bf16 %0, %1, %2, %0"
                    : "+a"(o[hh][dt]) : "v"(pa), "v"(vv));
            }
        }
        cur ^= 1;
    }
    // ---- store partial O (bf16): i = i0+wi*16+4g+r, d = (hs*4+hh)*64 + dt*16 + li ----
    {
        int irow0 = i0 + wi * 16 + 4 * g;
        #pragma unroll
        for (int hh = 0; hh < 4; ++hh) {
            int d0 = (hs * 4 + hh) * 64;
            #pragma unroll
            for (int dt = 0; dt < 4; ++dt) {
                #pragma unroll
                for (int r = 0; r < 4; ++r) {
                    int irow = irow0 + r;
                    if (irow <= 2048) {
                        Op[(((size_t)(nc * 2 + b)) * 2049 + irow) * 512 + d0 + dt * 16 + li] =
                            bf16rnd(o[hh][dt][r]);
                    }
                }
            }
        }
    }
}

// ---------------- sum NCJ bf16 partials -> bf16 attno ----------------
__global__ __launch_bounds__(256) void osum_kernel(
    const ushort* __restrict__ Op, ushort* __restrict__ attno)
{
    int idx = blockIdx.x * 256 + threadIdx.x;
    if (idx >= MROWS * 64) return;
    int row = idx >> 6, dq = idx & 63;
    int b = row / NTOK, i = row - b * NTOK;
    float acc[8];
    #pragma unroll
    for (int e = 0; e < 8; ++e) acc[e] = 0.f;
    #pragma unroll
    for (int nc = 0; nc < NCJ; ++nc) {
        const ushort* src = Op + (((size_t)(nc * 2 + b)) * 2049 + i) * 512 + dq * 8;
        int4 v = *(const int4*)src;
        const ushort* up = (const ushort*)&v;
        #pragma unroll
        for (int e = 0; e < 8; ++e) acc[e] += bf16tof(up[e]);
    }
    ushort ov[8];
    #pragma unroll
    for (int e = 0; e < 8; ++e) ov[e] = bf16rnd(acc[e]);
    *(int4*)(attno + (size_t)row * 512 + dq * 8) = *(int4*)ov;
}

// ---------------- head ----------------
__global__ void head_kernel(
    const float* __restrict__ x, const float* __restrict__ g, const float* __restrict__ b,
    const float* __restrict__ w, const float* __restrict__ hb, float* __restrict__ out)
{
    int lane = threadIdx.x & 63;
    for (int bi = 0; bi < 2; ++bi) {
        const float* xr = x + (size_t)bi * NTOK * 128;
        float v0 = xr[lane], v1 = xr[lane + 64];
        float mean = wave_allreduce_sum(v0 + v1) * (1.0f / 128.0f);
        float d0 = v0 - mean, d1 = v1 - mean;
        float var = wave_allreduce_sum(d0 * d0 + d1 * d1) * (1.0f / 128.0f);
        float inv = rsqrtf(var + 1e-5f);
        float y0 = d0 * inv * g[lane] + b[lane];
        float y1 = d1 * inv * g[lane + 64] + b[lane + 64];
        for (int c = 0; c < 4; ++c) {
            float pt = y0 * w[lane * 4 + c] + y1 * w[(lane + 64) * 4 + c];
            pt = wave_allreduce_sum(pt);
            if (lane == 0) out[bi * 4 + c] = pt + hb[c];
        }
    }
}

extern "C" void kernel_launch(void* const* d_in, const int* in_sizes, int n_in,
                              void* d_out, int out_size, void* d_ws, size_t ws_size,
                              hipStream_t stream) {
    const float* eeg   = (const float*)d_in[0];
    const float* est   = (const float*)d_in[1];
    const int*   cvi   = (const int*)d_in[2];
    const float* convw = (const float*)d_in[3];
    const float* convb = (const float*)d_in[4];
    const float* cls   = (const float*)d_in[5];
    const float* clsp  = (const float*)d_in[6];
    const float* bte   = (const float*)d_in[7];
    const float* btr   = (const float*)d_in[8];
    const float* bcr   = (const float*)d_in[9];
    const float* bce   = (const float*)d_in[10];
    const float* ln1g  = (const float*)d_in[11];
    const float* ln1b  = (const float*)d_in[12];
    const float* wqkv  = (const float*)d_in[13];
    const float* wkt   = (const float*)d_in[14];
    const float* wkc   = (const float*)d_in[15];
    const float* wo    = (const float*)d_in[16];
    const float* bo    = (const float*)d_in[17];
    const float* ln2g  = (const float*)d_in[18];
    const float* ln2b  = (const float*)d_in[19];
    const float* w1    = (const float*)d_in[20];
    const float* b1    = (const float*)d_in[21];
    const float* w2    = (const float*)d_in[22];
    const float* b2    = (const float*)d_in[23];
    const float* hlng  = (const float*)d_in[24];
    const float* hlnb  = (const float*)d_in[25];
    const float* hw    = (const float*)d_in[26];
    const float* hb    = (const float*)d_in[27];

    float* ws    = (float*)d_ws;
    float* x_    = ws + OFF_X;
    ushort* xnb  = (ushort*)(ws + OFF_XNB);
    ushort* rtb  = (ushort*)(ws + OFF_RTB);
    ushort* rcb  = (ushort*)(ws + OFF_RCB);
    ushort* qkvb = (ushort*)(ws + OFF_QKVB);
    ushort* ktcb = (ushort*)(ws + OFF_KTCB);
    ushort* qnb  = (ushort*)(ws + OFF_QNB);
    ushort* ksb  = (ushort*)(ws + OFF_KSB);
    ushort* vnb  = (ushort*)(ws + OFF_VNB);
    ushort* vtb  = (ushort*)(ws + OFF_VTB);
    float* colb_ = ws + OFF_COLB;
    ushort* wT   = (ushort*)(ws + OFF_WT);
    ushort* opb  = (ushort*)(ws + OFF_OP);
    ushort* attnob = (ushort*)(ws + OFF_ATTNO);
    ushort* ffnhb  = (ushort*)(ws + OFF_FFNH);

    wprep_kernel<<<dim3(768, 5, 2), 256, 0, stream>>>(wqkv, wkt, wkc, wo, w1, w2, wT);
    embed_kernel<<<4098, 128, 0, stream>>>(eeg, est, cvi, convw, convb, cls, clsp, x_, rtb, rcb);

    for (int l = 0; l < 2; ++l) {
        const ushort* wTl = wT + (size_t)l * 524288;
        ln_kernel<<<1025, 256, 0, stream>>>(x_, ln1g + l * 128, ln1b + l * 128, xnb, MROWS);
        mgemm_kernel<<<dim3(12, 33), 256, 0, stream>>>(xnb, xnb, 128, wTl,
                                                       nullptr, qkvb, nullptr, nullptr,
                                                       MROWS, 128, 1536, 3);
        mgemm_kernel<<<dim3(4, 33), 256, 0, stream>>>(rtb, rcb, 128, wTl + 196608,
                                                      nullptr, ktcb, nullptr, nullptr,
                                                      MROWS, 256, 512, 3);
        remap_kernel<<<MROWS, 512, 0, stream>>>(qkvb, ktcb, bte, btr, bcr, bce,
                                                qnb, ksb, vnb, colb_);
        vtrans_kernel<<<dim3(65, 16, 2), 256, 0, stream>>>(vnb, vtb);
        attn8_kernel<<<dim3(65, NCJ, 2), 256, 0, stream>>>(qnb, ksb, vtb, colb_, opb);
        osum_kernel<<<1025, 256, 0, stream>>>(opb, attnob);
        tgemm_kernel<<<dim3(8, 65), 256, 0, stream>>>(attnob, wTl + 327680, x_,
                                                      bo + l * 128, x_, MROWS, 128);
        ln_kernel<<<1025, 256, 0, stream>>>(x_, ln2g + l * 128, ln2b + l * 128, xnb, MROWS);
        mgemm_kernel<<<dim3(4, 33), 256, 0, stream>>>(xnb, xnb, 128, wTl + 393216,
                                                      nullptr, ffnhb, b1 + l * 512, nullptr,
                                                      MROWS, 128, 512, 2);
        tgemm_kernel<<<dim3(8, 65), 256, 0, stream>>>(ffnhb, wTl + 458752, x_,
                                                      b2 + l * 128, x_, MROWS, 128);
    }
    head_kernel<<<1, 64, 0, stream>>>(x_, hlng, hlnb, hw, hb, (float*)d_out);
}

// Round 10
// 355.104 us; speedup vs baseline: 10.2295x; 1.1862x over previous
//
#include <hip/hip_runtime.h>

#define CH    64
#define NTOK  2049
#define NTOKP 2064
#define MROWS 4098
#define NCJ   3

typedef __attribute__((ext_vector_type(8))) short bf16x8;
typedef __attribute__((ext_vector_type(4))) float f32x4;
typedef __attribute__((ext_vector_type(2))) int i32x2;

// workspace offsets (float units) — sequential, no overlays
#define OFF_X     0u
#define OFF_XNB   524544u
#define OFF_RTB   786816u
#define OFF_RCB   1049088u
#define OFF_QKVB  1311360u
#define OFF_KTCB  4458624u
#define OFF_QNB   5507712u
#define OFF_KSB   6556800u
#define OFF_VNB   7613568u
#define OFF_VTB   8662656u
#define OFF_COLB  9727616u
#define OFF_WT    9760640u
#define OFF_OP    10284928u
#define OFF_ATTNO 13432192u
#define OFF_FFNH  14481280u

// 0.125 * log2(e): folds SCALE and exp->exp2 conversion into q/colb pre-scale
#define QSCALE 0.1803368801111204f

#define GLOAD_LDS16(gp, lp) __builtin_amdgcn_global_load_lds( \
    (const __attribute__((address_space(1))) void*)(gp), \
    (__attribute__((address_space(3))) void*)(lp), 16, 0, 0)

__device__ __forceinline__ float wave_allreduce_sum(float v) {
    #pragma unroll
    for (int m = 1; m < 64; m <<= 1) v += __shfl_xor(v, m);
    return v;
}

__device__ __forceinline__ ushort bf16rnd(float x) {
    unsigned u = __builtin_bit_cast(unsigned, x);
    u += 0x7FFF + ((u >> 16) & 1);
    return (ushort)(u >> 16);
}

__device__ __forceinline__ float bf16tof(ushort u) {
    return __builtin_bit_cast(float, ((unsigned)u) << 16);
}

// ---------------- weight prep: f32 [K][N] -> bf16 Wt [N][K] (ktc concatenated) ----------------
__global__ __launch_bounds__(256) void wprep_kernel(
    const float* __restrict__ wqkv, const float* __restrict__ wkt, const float* __restrict__ wkc,
    const float* __restrict__ wo, const float* __restrict__ w1, const float* __restrict__ w2,
    ushort* __restrict__ wT)
{
    int l = blockIdx.z, mat = blockIdx.y;
    int idx = blockIdx.x * 256 + threadIdx.x;
    float v; int off;
    if (mat == 0) {            // qkv: N=1536 K=128
        if (idx >= 196608) return;
        int n = idx >> 7, k = idx & 127;
        v = wqkv[(size_t)l * 196608 + (size_t)k * 1536 + n]; off = 0;
    } else if (mat == 1) {     // ktc: N=512 K=256 (wkt | wkc)
        if (idx >= 131072) return;
        int n = idx >> 8, k = idx & 255;
        v = (k < 128) ? wkt[(size_t)l * 65536 + (size_t)k * 512 + n]
                      : wkc[(size_t)l * 65536 + (size_t)(k - 128) * 512 + n];
        off = 196608;
    } else if (mat == 2) {     // wo: N=128 K=512
        if (idx >= 65536) return;
        int n = idx >> 9, k = idx & 511;
        v = wo[(size_t)l * 65536 + (size_t)k * 128 + n]; off = 327680;
    } else if (mat == 3) {     // w1: N=512 K=128
        if (idx >= 65536) return;
        int n = idx >> 7, k = idx & 127;
        v = w1[(size_t)l * 65536 + (size_t)k * 512 + n]; off = 393216;
    } else {                   // w2: N=128 K=512
        if (idx >= 65536) return;
        int n = idx >> 9, k = idx & 511;
        v = w2[(size_t)l * 65536 + (size_t)k * 128 + n]; off = 458752;
    }
    wT[(size_t)l * 524288 + off + idx] = bf16rnd(v);
}

// ---------------- embed ----------------
__global__ __launch_bounds__(128) void embed_kernel(
    const float* __restrict__ eeg, const float* __restrict__ est, const int* __restrict__ cvi,
    const float* __restrict__ cw, const float* __restrict__ cb,
    const float* __restrict__ cls, const float* __restrict__ clsp,
    float* __restrict__ x, ushort* __restrict__ rt, ushort* __restrict__ rc)
{
    int id = blockIdx.x;
    int d = threadIdx.x;
    if (id >= 4096) {
        int b = id - 4096;
        size_t base = (size_t)b * NTOK * 128 + d;
        x[base]  = cls[d];
        rt[base] = bf16rnd(clsp[d]);
        rc[base] = bf16rnd(clsp[d]);
        return;
    }
    int b = id >> 11, rem = id & 2047, c = rem >> 5, w = rem & 31;
    __shared__ float xs[25];
    if (d < 25) xs[d] = eeg[((size_t)(b * CH + c)) * 800 + w * 25 + d];
    __syncthreads();
    float acc = cb[d];
    #pragma unroll
    for (int p = 0; p < 25; ++p) acc += xs[p] * cw[d * 25 + p];
    int i = 1 + c * 32 + w;
    size_t base = ((size_t)b * NTOK + i) * 128 + d;
    x[base] = acc;
    int k = d & 63;
    float invk = __expf(-0.14391156831f * (float)k);
    float pt = floorf(est[b] / 0.1f) + (float)w;
    float at = pt * invk;
    rt[base] = bf16rnd((d < 64) ? sinf(at) : cosf(at));
    float pc = (float)cvi[b * CH + c];
    float ac = pc * invk;
    rc[base] = bf16rnd((d < 64) ? sinf(ac) : cosf(ac));
}

// ---------------- layernorm, bf16 out ----------------
__global__ __launch_bounds__(256) void ln_kernel(
    const float* __restrict__ x, const float* __restrict__ g, const float* __restrict__ bb,
    ushort* __restrict__ out, int rows)
{
    int w = threadIdx.x >> 6, lane = threadIdx.x & 63;
    int row = blockIdx.x * 4 + w;
    if (row >= rows) return;
    const float* xr = x + (size_t)row * 128;
    float v0 = xr[lane], v1 = xr[lane + 64];
    float mean = wave_allreduce_sum(v0 + v1) * (1.0f / 128.0f);
    float d0 = v0 - mean, d1 = v1 - mean;
    float var = wave_allreduce_sum(d0 * d0 + d1 * d1) * (1.0f / 128.0f);
    float inv = rsqrtf(var + 1e-5f);
    out[(size_t)row * 128 + lane]      = bf16rnd(d0 * inv * g[lane]      + bb[lane]);
    out[(size_t)row * 128 + lane + 64] = bf16rnd(d1 * inv * g[lane + 64] + bb[lane + 64]);
}

// ---------------- bf16 MFMA GEMM: C = A[MxK] * Wt[NxK]; A may be [A | A2] concat on K ----------------
// mode: 2 -> outB = bf16(gelu(acc+bias)); 3 -> outB = bf16(acc)
__global__ __launch_bounds__(256, 3) void mgemm_kernel(
    const ushort* __restrict__ A, const ushort* __restrict__ A2, int K1,
    const ushort* __restrict__ Wt,
    float* outF, ushort* outB, const float* bias, const float* res,
    int M, int K, int N, int mode)
{
    __shared__ ushort Alds[128 * 72];
    __shared__ ushort Blds[128 * 72];
    int tid = threadIdx.x;
    int lane = tid & 63, wv = tid >> 6;
    int wm = wv >> 1, wn = wv & 1;
    int li = lane & 15, g = lane >> 4;
    int m0 = blockIdx.y * 128, n0 = blockIdx.x * 128;
    int K2s = K - K1;
    f32x4 acc[4][4];
    #pragma unroll
    for (int a = 0; a < 4; ++a)
        #pragma unroll
        for (int c = 0; c < 4; ++c) acc[a][c] = (f32x4){0.f, 0.f, 0.f, 0.f};

    for (int kb = 0; kb < K; kb += 64) {
        #pragma unroll
        for (int it = 0; it < 4; ++it) {
            int gi = tid + it * 256;
            int row = gi >> 3, gc = gi & 7;
            int m = m0 + row; if (m >= M) m = M - 1;
            int acol = kb + gc * 8;
            const ushort* asrc = (acol < K1) ? (A + (size_t)m * K1 + acol)
                                             : (A2 + (size_t)m * K2s + (acol - K1));
            bf16x8 av = *(const bf16x8*)asrc;
            *(bf16x8*)&Alds[row * 72 + ((gc ^ (row & 7)) << 3)] = av;
            int n = n0 + row;
            bf16x8 bv = *(const bf16x8*)(Wt + (size_t)n * K + acol);
            *(bf16x8*)&Blds[row * 72 + ((gc ^ (row & 7)) << 3)] = bv;
        }
        __syncthreads();
        #pragma unroll
        for (int k2 = 0; k2 < 2; ++k2) {
            bf16x8 af[4], bfr[4];
            #pragma unroll
            for (int xx = 0; xx < 4; ++xx) {
                int ra = wm * 64 + xx * 16 + li;
                int rb = wn * 64 + xx * 16 + li;
                af[xx]  = *(const bf16x8*)&Alds[ra * 72 + (((k2 * 4 + g) ^ (ra & 7)) << 3)];
                bfr[xx] = *(const bf16x8*)&Blds[rb * 72 + (((k2 * 4 + g) ^ (rb & 7)) << 3)];
            }
            #pragma unroll
            for (int mi = 0; mi < 4; ++mi)
                #pragma unroll
                for (int ni = 0; ni < 4; ++ni)
                    acc[mi][ni] = __builtin_amdgcn_mfma_f32_16x16x32_bf16(af[mi], bfr[ni], acc[mi][ni], 0, 0, 0);
        }
        __syncthreads();
    }
    #pragma unroll
    for (int mi = 0; mi < 4; ++mi) {
        #pragma unroll
        for (int r = 0; r < 4; ++r) {
            int m = m0 + wm * 64 + mi * 16 + 4 * g + r;
            if (m >= M) continue;
            #pragma unroll
            for (int ni = 0; ni < 4; ++ni) {
                int n = n0 + wn * 64 + ni * 16 + li;
                float v = acc[mi][ni][r];
                if (mode == 2) {
                    v += bias[n];
                    v = 0.5f * v * (1.0f + erff(v * 0.70710678118f));
                    outB[(size_t)m * N + n] = bf16rnd(v);
                } else {
                    outB[(size_t)m * N + n] = bf16rnd(v);
                }
            }
        }
    }
}

// ---------------- thin GEMM (N=128, K=512): one 16x16 tile per wave, no LDS ----------------
__global__ __launch_bounds__(256) void tgemm_kernel(
    const ushort* __restrict__ A, const ushort* __restrict__ Wt,
    float* __restrict__ outF, const float* __restrict__ bias, const float* __restrict__ res,
    int M, int N)
{
    int lane = threadIdx.x & 63, wv = threadIdx.x >> 6;
    int li = lane & 15, g = lane >> 4;
    int mt = blockIdx.y * 4 + wv;
    int m0 = mt * 16, n0 = blockIdx.x * 16;
    int ar = m0 + li; if (ar >= M) ar = M - 1;
    const ushort* arow = A + (size_t)ar * 512 + 8 * g;
    const ushort* brow = Wt + (size_t)(n0 + li) * 512 + 8 * g;
    f32x4 acc = (f32x4){0.f, 0.f, 0.f, 0.f};
    #pragma unroll
    for (int k2 = 0; k2 < 16; ++k2) {
        bf16x8 af = *(const bf16x8*)(arow + k2 * 32);
        bf16x8 bf = *(const bf16x8*)(brow + k2 * 32);
        acc = __builtin_amdgcn_mfma_f32_16x16x32_bf16(af, bf, acc, 0, 0, 0);
    }
    #pragma unroll
    for (int r = 0; r < 4; ++r) {
        int m = m0 + 4 * g + r;
        if (m < M) {
            int n = n0 + li;
            outF[(size_t)m * N + n] = acc[r] + bias[n] + res[(size_t)m * N + n];
        }
    }
}

// ---------------- remap (bf16 inputs) -> qn(xQSCALE)/ksum(padded)/vn + colb(padded) ----------------
__global__ __launch_bounds__(512) void remap_kernel(
    const ushort* __restrict__ qkvb, const ushort* __restrict__ ktcb,
    const float* __restrict__ bte, const float* __restrict__ btr,
    const float* __restrict__ bcr, const float* __restrict__ bce,
    ushort* __restrict__ qn, ushort* __restrict__ ksum, ushort* __restrict__ vn,
    float* __restrict__ colb)
{
    int id = blockIdx.x;            // b2*NTOK + i2
    int b2 = id / NTOK, i2 = id - b2 * NTOK;
    int t = threadIdx.x;
    int h2 = t >> 6, d2 = t & 63;
    int G = i2 * 16 + b2 * 8 + h2;
    int bhA = G / 2049, iA = G - bhA * 2049;
    int bA = bhA >> 3, hA = bhA & 7;
    size_t qbase = ((size_t)(bA * NTOK + iA)) * 1536 + hA * 64 + d2;
    ushort qv = qkvb[qbase], kvu = qkvb[qbase + 512], vvu = qkvb[qbase + 1024];
    int bB = G / 16392, remB = G - bB * 16392;
    int iB = remB >> 3, hB = remB & 7;
    ushort ktcu = ktcb[((size_t)(bB * NTOK + iB)) * 512 + hB * 64 + d2];
    float kv = bf16tof(kvu), ktcv = bf16tof(ktcu);
    qn[(size_t)id * 512 + t] = bf16rnd(bf16tof(qv) * QSCALE);   // SCALE+log2e folded
    ksum[((size_t)(b2 * NTOKP + i2)) * 512 + t] = bf16rnd(kv + ktcv);
    vn[(size_t)id * 512 + t] = vvu;
    float cbx = (bte[t] + bce[t]) * kv + (btr[t] + bcr[t]) * ktcv;
    cbx = wave_allreduce_sum(cbx);
    if (d2 == 0) colb[((size_t)(b2 * NTOKP + i2)) * 8 + h2] = cbx;
}

// ---------------- transpose V: vn[b][j][d] -> vt[b][d][j 2080], zero-fill j>2048 ----------------
__global__ __launch_bounds__(256) void vtrans_kernel(
    const ushort* __restrict__ vn, ushort* __restrict__ vt)
{
    __shared__ ushort tile[32][36];
    int jt = blockIdx.x, dt = blockIdx.y, b = blockIdx.z;
    int t = threadIdx.x;
    {
        int jj = t >> 3, dq = t & 7;
        int j = jt * 32 + jj;
        ushort4 v = make_ushort4(0, 0, 0, 0);
        if (j <= 2048)
            v = *(const ushort4*)(vn + ((size_t)(b * NTOK + j)) * 512 + dt * 32 + dq * 4);
        *(ushort4*)&tile[jj][dq * 4] = v;
    }
    __syncthreads();
    {
        int dd = t >> 3, jq = t & 7;
        ushort4 w;
        w.x = tile[jq * 4 + 0][dd];
        w.y = tile[jq * 4 + 1][dd];
        w.z = tile[jq * 4 + 2][dd];
        w.w = tile[jq * 4 + 3][dd];
        *(ushort4*)(vt + ((size_t)b * 512 + dt * 32 + dd) * 2080 + jt * 32 + jq * 4) = w;
    }
}

// ---------------- attn9: swapped-QK, heads SPLIT across wave pair + LDS sum-exchange ----------------
// grid (65, NCJ=3, 2) = 390 blocks (single residency round). 4 waves = (wi i-16-sub, hg head-group-4).
// Each wave: QK for ITS 4 heads only (8 MFMA, no duplication), exp2 its 4 heads, partial head-sum
// exchanged with partner wave (wi, 1-hg) through LDS (f32x4/lane) -> full softmax denominator.
// Buffers padded to 2064 rows (zeros) -> NO clamps, affine staging addresses. Staging issued
// post-B2 so the exchange barrier's vmcnt drain doesn't kill the one-iteration prefetch.
// LDS: K dbuf 2x16K @0 | V dbuf 2x16K @32768 | cb dbuf 2x768 @65536 | ex 4K @67072 = 69.4KB.
__global__ __launch_bounds__(256, 2) void attn9_kernel(
    const ushort* __restrict__ qn, const ushort* __restrict__ ks,
    const ushort* __restrict__ vt, const float* __restrict__ colb,
    ushort* __restrict__ Op)
{
    __shared__ __align__(16) char smem[71168];
    const int tid = threadIdx.x;
    const int lane = tid & 63, wv = tid >> 6;
    const int wi = wv >> 1, hg = wv & 1;
    const int g = lane >> 4, li = lane & 15;
    const int nc = blockIdx.y, b = blockIdx.z;
    const int i0 = blockIdx.x * 32;
    const int jt0 = nc * 43, jt1 = (nc + 1) * 43;

    // Q fragments: own 4 heads x 2 k2 (pre-scaled by QSCALE in remap)
    bf16x8 qf[4][2];
    {
        int iq = i0 + wi * 16 + li; if (iq > 2048) iq = 2048;
        const ushort* qrow = qn + ((size_t)(b * NTOK + iq)) * 512 + hg * 256;
        #pragma unroll
        for (int hh = 0; hh < 4; ++hh)
            #pragma unroll
            for (int k2 = 0; k2 < 2; ++k2)
                qf[hh][k2] = *(const bf16x8*)(qrow + hh * 64 + k2 * 32 + 8 * g);
    }
    f32x4 o[4][4];   // own 4 heads x 4 d-subtiles -> AGPR
    #pragma unroll
    for (int a = 0; a < 4; ++a)
        #pragma unroll
        for (int m = 0; m < 4; ++m) o[a][m] = (f32x4){0.f, 0.f, 0.f, 0.f};

    // hoisted per-lane LDS read bases
    const unsigned koff0 = (unsigned)(li * 1024) + (unsigned)((g * 16) ^ ((li & 7) << 4))
                         + (unsigned)(hg * 512);
    const unsigned koff1 = (unsigned)(li * 1024) + (unsigned)((64 + g * 16) ^ ((li & 7) << 4))
                         + (unsigned)(hg * 512);
    const unsigned vboff = (unsigned)(li * 32)
                         + (unsigned)((((g >> 1) ^ ((li >> 2) & 1)) << 4) + (g & 1) * 8)
                         + (unsigned)(hg * 8192);
    const unsigned exoff = 67072u + (unsigned)(wv * 1024 + lane * 16);
    const unsigned exoffp = 67072u + (unsigned)((wv ^ 1) * 1024 + lane * 16);

    // staging (padded buffers: NO clamps, affine in jt)
    const ushort* ksb_b = ks + ((size_t)b * NTOKP) * 512;
    auto stageK = [&](int jt, int buf) {
        #pragma unroll
        for (int t = 0; t < 4; ++t) {
            unsigned L = (unsigned)((wv * 256 + t * 64 + lane) * 16);
            unsigned Lp = L ^ (((L >> 10) & 7u) << 4);
            const ushort* src = ksb_b + (size_t)(jt * 16 + (int)(Lp >> 10)) * 512 + ((Lp & 1023u) >> 1);
            GLOAD_LDS16(src, smem + buf * 16384 + (wv * 256 + t * 64) * 16);
        }
    };
    const ushort* vtb_b = vt + (size_t)b * 512 * 2080;
    auto stageV = [&](int jt, int buf) {
        #pragma unroll
        for (int t = 0; t < 4; ++t) {
            int n = wv * 256 + t * 64 + lane;
            int d = n >> 1;
            int h16 = (n & 1) ^ ((n >> 3) & 1);
            const ushort* src = vtb_b + (size_t)d * 2080 + jt * 16 + h16 * 8;
            GLOAD_LDS16(src, smem + 32768 + buf * 16384 + (wv * 256 + t * 64) * 16);
        }
    };
    auto loadcb = [&](int jt) -> float {
        if (tid < 128) {
            int jg = jt * 16 + (tid >> 3);
            if (jg > 2063) jg = 2063;      // pad rows are zero; just keep in-bounds
            return colb[((size_t)(b * NTOKP + jg)) * 8 + (tid & 7)] * QSCALE;
        }
        return 0.f;
    };

    stageK(jt0, 0); stageV(jt0, 0);
    {
        float c0 = loadcb(jt0);
        if (tid < 128) ((float*)(smem + 65536))[(tid >> 3) * 12 + (tid & 7)] = c0;
    }
    float cbreg = loadcb(jt0 + 1);

    int cur = 0;
    for (int jt = jt0; jt < jt1; ++jt) {
        __syncthreads();   // B1: staging(jt)+cb(jt) visible; prev ex reads done
        // ---- QK (swapped): s[hh](j=4g+r, i=li), own 4 heads only ----
        const char* kb = smem + cur * 16384;
        f32x4 s[4];
        #pragma unroll
        for (int hh = 0; hh < 4; ++hh) {
            s[hh] = (f32x4){0.f, 0.f, 0.f, 0.f};
            bf16x8 kf0 = *(const bf16x8*)(kb + koff0 + hh * 128);
            s[hh] = __builtin_amdgcn_mfma_f32_16x16x32_bf16(kf0, qf[hh][0], s[hh], 0, 0, 0);
            bf16x8 kf1 = *(const bf16x8*)(kb + koff1 + hh * 128);
            s[hh] = __builtin_amdgcn_mfma_f32_16x16x32_bf16(kf1, qf[hh][1], s[hh], 0, 0, 0);
        }
        // ---- exp2 own heads + partial head-sum -> LDS exchange ----
        const float* cbl = (const float*)(smem + 65536 + cur * 768);
        float p[4][4];
        #pragma unroll
        for (int rp = 0; rp < 2; ++rp) {
            f32x4 ce = *(const f32x4*)(cbl + (4 * g + 2 * rp) * 12 + hg * 4);
            f32x4 co = *(const f32x4*)(cbl + (4 * g + 2 * rp) * 12 + 12 + hg * 4);
            #pragma unroll
            for (int hh = 0; hh < 4; ++hh) {
                p[hh][2 * rp]     = __builtin_amdgcn_exp2f(s[hh][2 * rp]     + ce[hh]);
                p[hh][2 * rp + 1] = __builtin_amdgcn_exp2f(s[hh][2 * rp + 1] + co[hh]);
            }
        }
        f32x4 e;
        #pragma unroll
        for (int r = 0; r < 4; ++r)
            e[r] = (p[0][r] + p[1][r]) + (p[2][r] + p[3][r]);
        *(f32x4*)(smem + exoff) = e;
        __syncthreads();   // B2: exchange visible (staging(jt) long drained)
        f32x4 eo = *(const f32x4*)(smem + exoffp);
        // ---- issue next-tile staging + cb write NOW (post-B2: latency spans PV + next QK) ----
        const bool hn = (jt + 1 < jt1);
        if (hn) {
            if (tid < 128) ((float*)(smem + 65536 + (cur ^ 1) * 768))[(tid >> 3) * 12 + (tid & 7)] = cbreg;
            stageK(jt + 1, cur ^ 1);
            stageV(jt + 1, cur ^ 1);
            cbreg = loadcb(jt + 2);
        }
        // ---- full softmax denominator, pack P (PV A-operand) ----
        float inv[4];
        #pragma unroll
        for (int r = 0; r < 4; ++r)
            inv[r] = __builtin_amdgcn_rcpf(fmaxf(e[r] + eo[r], 1e-20f));  // NORMAL floor
        unsigned P2[4][2];
        #pragma unroll
        for (int hh = 0; hh < 4; ++hh)
            #pragma unroll
            for (int rp = 0; rp < 2; ++rp) {
                float lo = p[hh][2 * rp] * inv[2 * rp];
                float hi = p[hh][2 * rp + 1] * inv[2 * rp + 1];
                asm("v_cvt_pk_bf16_f32 %0, %1, %2" : "=v"(P2[hh][rp]) : "v"(lo), "v"(hi));
            }
        // ---- PV: own 4 heads, 16x16x16, o in AGPR ----
        const char* vb = smem + 32768 + cur * 16384 + vboff;
        #pragma unroll
        for (int hh = 0; hh < 4; ++hh) {
            i32x2 pa = (i32x2){(int)P2[hh][0], (int)P2[hh][1]};
            #pragma unroll
            for (int dt = 0; dt < 4; ++dt) {
                i32x2 vv = *(const i32x2*)(vb + hh * 2048 + dt * 512);
                asm("v_mfma_f32_16x16x16_bf16 %0, %1, %2, %0"
                    : "+a"(o[hh][dt]) : "v"(pa), "v"(vv));
            }
        }
        cur ^= 1;
    }
    // ---- store partial O (bf16): i = i0+wi*16+4g+r, d = (hg*4+hh)*64 + dt*16 + li ----
    {
        int irow0 = i0 + wi * 16 + 4 * g;
        #pragma unroll
        for (int hh = 0; hh < 4; ++hh) {
            int d0 = (hg * 4 + hh) * 64;
            #pragma unroll
            for (int dt = 0; dt < 4; ++dt) {
                #pragma unroll
                for (int r = 0; r < 4; ++r) {
                    int irow = irow0 + r;
                    if (irow <= 2048) {
                        Op[(((size_t)(nc * 2 + b)) * 2049 + irow) * 512 + d0 + dt * 16 + li] =
                            bf16rnd(o[hh][dt][r]);
                    }
                }
            }
        }
    }
}

// ---------------- sum NCJ bf16 partials -> bf16 attno ----------------
__global__ __launch_bounds__(256) void osum_kernel(
    const ushort* __restrict__ Op, ushort* __restrict__ attno)
{
    int idx = blockIdx.x * 256 + threadIdx.x;
    if (idx >= MROWS * 64) return;
    int row = idx >> 6, dq = idx & 63;
    int b = row / NTOK, i = row - b * NTOK;
    float acc[8];
    #pragma unroll
    for (int e = 0; e < 8; ++e) acc[e] = 0.f;
    #pragma unroll
    for (int nc = 0; nc < NCJ; ++nc) {
        const ushort* src = Op + (((size_t)(nc * 2 + b)) * 2049 + i) * 512 + dq * 8;
        int4 v = *(const int4*)src;
        const ushort* up = (const ushort*)&v;
        #pragma unroll
        for (int e = 0; e < 8; ++e) acc[e] += bf16tof(up[e]);
    }
    ushort ov[8];
    #pragma unroll
    for (int e = 0; e < 8; ++e) ov[e] = bf16rnd(acc[e]);
    *(int4*)(attno + (size_t)row * 512 + dq * 8) = *(int4*)ov;
}

// ---------------- head ----------------
__global__ void head_kernel(
    const float* __restrict__ x, const float* __restrict__ g, const float* __restrict__ b,
    const float* __restrict__ w, const float* __restrict__ hb, float* __restrict__ out)
{
    int lane = threadIdx.x & 63;
    for (int bi = 0; bi < 2; ++bi) {
        const float* xr = x + (size_t)bi * NTOK * 128;
        float v0 = xr[lane], v1 = xr[lane + 64];
        float mean = wave_allreduce_sum(v0 + v1) * (1.0f / 128.0f);
        float d0 = v0 - mean, d1 = v1 - mean;
        float var = wave_allreduce_sum(d0 * d0 + d1 * d1) * (1.0f / 128.0f);
        float inv = rsqrtf(var + 1e-5f);
        float y0 = d0 * inv * g[lane] + b[lane];
        float y1 = d1 * inv * g[lane + 64] + b[lane + 64];
        for (int c = 0; c < 4; ++c) {
            float pt = y0 * w[lane * 4 + c] + y1 * w[(lane + 64) * 4 + c];
            pt = wave_allreduce_sum(pt);
            if (lane == 0) out[bi * 4 + c] = pt + hb[c];
        }
    }
}

extern "C" void kernel_launch(void* const* d_in, const int* in_sizes, int n_in,
                              void* d_out, int out_size, void* d_ws, size_t ws_size,
                              hipStream_t stream) {
    const float* eeg   = (const float*)d_in[0];
    const float* est   = (const float*)d_in[1];
    const int*   cvi   = (const int*)d_in[2];
    const float* convw = (const float*)d_in[3];
    const float* convb = (const float*)d_in[4];
    const float* cls   = (const float*)d_in[5];
    const float* clsp  = (const float*)d_in[6];
    const float* bte   = (const float*)d_in[7];
    const float* btr   = (const float*)d_in[8];
    const float* bcr   = (const float*)d_in[9];
    const float* bce   = (const float*)d_in[10];
    const float* ln1g  = (const float*)d_in[11];
    const float* ln1b  = (const float*)d_in[12];
    const float* wqkv  = (const float*)d_in[13];
    const float* wkt   = (const float*)d_in[14];
    const float* wkc   = (const float*)d_in[15];
    const float* wo    = (const float*)d_in[16];
    const float* bo    = (const float*)d_in[17];
    const float* ln2g  = (const float*)d_in[18];
    const float* ln2b  = (const float*)d_in[19];
    const float* w1    = (const float*)d_in[20];
    const float* b1    = (const float*)d_in[21];
    const float* w2    = (const float*)d_in[22];
    const float* b2    = (const float*)d_in[23];
    const float* hlng  = (const float*)d_in[24];
    const float* hlnb  = (const float*)d_in[25];
    const float* hw    = (const float*)d_in[26];
    const float* hb    = (const float*)d_in[27];

    float* ws    = (float*)d_ws;
    float* x_    = ws + OFF_X;
    ushort* xnb  = (ushort*)(ws + OFF_XNB);
    ushort* rtb  = (ushort*)(ws + OFF_RTB);
    ushort* rcb  = (ushort*)(ws + OFF_RCB);
    ushort* qkvb = (ushort*)(ws + OFF_QKVB);
    ushort* ktcb = (ushort*)(ws + OFF_KTCB);
    ushort* qnb  = (ushort*)(ws + OFF_QNB);
    ushort* ksb  = (ushort*)(ws + OFF_KSB);
    ushort* vnb  = (ushort*)(ws + OFF_VNB);
    ushort* vtb  = (ushort*)(ws + OFF_VTB);
    float* colb_ = ws + OFF_COLB;
    ushort* wT   = (ushort*)(ws + OFF_WT);
    ushort* opb  = (ushort*)(ws + OFF_OP);
    ushort* attnob = (ushort*)(ws + OFF_ATTNO);
    ushort* ffnhb  = (ushort*)(ws + OFF_FFNH);

    // zero the pad rows (j in [2049, 2064)) of ksum and colb once per launch
    for (int b = 0; b < 2; ++b) {
        hipMemsetAsync(ksb + ((size_t)(b * NTOKP + 2049)) * 512, 0,
                       (NTOKP - 2049) * 512 * sizeof(ushort), stream);
        hipMemsetAsync(colb_ + ((size_t)(b * NTOKP + 2049)) * 8, 0,
                       (NTOKP - 2049) * 8 * sizeof(float), stream);
    }

    wprep_kernel<<<dim3(768, 5, 2), 256, 0, stream>>>(wqkv, wkt, wkc, wo, w1, w2, wT);
    embed_kernel<<<4098, 128, 0, stream>>>(eeg, est, cvi, convw, convb, cls, clsp, x_, rtb, rcb);

    for (int l = 0; l < 2; ++l) {
        const ushort* wTl = wT + (size_t)l * 524288;
        ln_kernel<<<1025, 256, 0, stream>>>(x_, ln1g + l * 128, ln1b + l * 128, xnb, MROWS);
        mgemm_kernel<<<dim3(12, 33), 256, 0, stream>>>(xnb, xnb, 128, wTl,
                                                       nullptr, qkvb, nullptr, nullptr,
                                                       MROWS, 128, 1536, 3);
        mgemm_kernel<<<dim3(4, 33), 256, 0, stream>>>(rtb, rcb, 128, wTl + 196608,
                                                      nullptr, ktcb, nullptr, nullptr,
                                                      MROWS, 256, 512, 3);
        remap_kernel<<<MROWS, 512, 0, stream>>>(qkvb, ktcb, bte, btr, bcr, bce,
                                                qnb, ksb, vnb, colb_);
        vtrans_kernel<<<dim3(65, 16, 2), 256, 0, stream>>>(vnb, vtb);
        attn9_kernel<<<dim3(65, NCJ, 2), 256, 0, stream>>>(qnb, ksb, vtb, colb_, opb);
        osum_kernel<<<1025, 256, 0, stream>>>(opb, attnob);
        tgemm_kernel<<<dim3(8, 65), 256, 0, stream>>>(attnob, wTl + 327680, x_,
                                                      bo + l * 128, x_, MROWS, 128);
        ln_kernel<<<1025, 256, 0, stream>>>(x_, ln2g + l * 128, ln2b + l * 128, xnb, MROWS);
        mgemm_kernel<<<dim3(4, 33), 256, 0, stream>>>(xnb, xnb, 128, wTl + 393216,
                                                      nullptr, ffnhb, b1 + l * 512, nullptr,
                                                      MROWS, 128, 512, 2);
        tgemm_kernel<<<dim3(8, 65), 256, 0, stream>>>(ffnhb, wTl + 458752, x_,
                                                      b2 + l * 128, x_, MROWS, 128);
    }
    head_kernel<<<1, 64, 0, stream>>>(x_, hlng, hlnb, hw, hb, (float*)d_out);
}